// Round 6
// baseline (450.328 us; speedup 1.0000x reference)
//
#include <hip/hip_runtime.h>
#include <math.h>

#define DEV __device__ __forceinline__

constexpr int Bb   = 2;
constexpr int Seq  = 1024;
constexpr int Dim  = 1024;
constexpr int Hh   = 8;
constexpr int Dh   = 64;
constexpr int Di   = 512;
constexpr int BN   = Bb * Seq;       // 2048
constexpr int NSEQ = Bb * Hh;        // 16
constexpr int CHUNK = 32;            // chunks per sequence
constexpr int CLEN  = Seq / CHUNK;   // 32
constexpr float EPSV = 1.1920929e-07f;

typedef _Float16 half8 __attribute__((ext_vector_type(8)));
typedef float    f32x4 __attribute__((ext_vector_type(4)));

DEV float bf2f(unsigned short u) {
  union { unsigned int i; float f; } x; x.i = ((unsigned int)u) << 16; return x.f;
}
DEV unsigned short f2bf(float f) {
  union { float f; unsigned int i; } x; x.f = f;
  unsigned int r = x.i + 0x7fffu + ((x.i >> 16) & 1u);
  return (unsigned short)(r >> 16);
}
// flag: 1 -> fp32, 0 -> bf16
DEV float ldin(const void* p, int f32, size_t i) {
  if (f32) return ((const float*)p)[i];
  return bf2f(((const unsigned short*)p)[i]);
}

struct InPtrs { const void* p[17]; int n[17]; };

// ---------------------------------------------------------------------------
// K0: dtype sniffer. Block b samples even-indexed 16-bit halves of input b.
// fp32 data -> even halves are mantissa garbage (mostly outside [1e-12,1e4]
// or exactly 0 for constant arrays). bf16 data -> real samples, inside band.
// ---------------------------------------------------------------------------
__global__ __launch_bounds__(64) void k_sniff(InPtrs ip, int* __restrict__ flags) {
  int b = blockIdx.x, tid = threadIdx.x;
  const unsigned short* u = (const unsigned short*)ip.p[b];
  int count = ip.n[b];
  int j = 2 * tid;
  int valid = 0, bad = 0;
  if (j < count) {
    valid = 1;
    float v = bf2f(u[j]);
    float a = fabsf(v);
    if (!(a >= 1e-12f && a <= 1e4f)) bad = 1;  // NaN/Inf/huge/tiny/zero -> bad
  }
#pragma unroll
  for (int m = 1; m < 64; m <<= 1) { valid += __shfl_xor(valid, m); bad += __shfl_xor(bad, m); }
  if (tid == 0) flags[b] = (2 * bad > valid) ? 1 : 0;   // 1 = fp32
}

// ---------------------------------------------------------------------------
// K1: RMSNorm(x) -> xa (f16), fused gate projections sigmoid(xa@W+b)
// ---------------------------------------------------------------------------
__global__ __launch_bounds__(256) void k_rms_gates(
    const void* __restrict__ x, const void* __restrict__ w_rms,
    const void* __restrict__ lr_w, const void* __restrict__ decay_w,
    const void* __restrict__ mom_w,
    const void* __restrict__ lr_b, const void* __restrict__ decay_b,
    const void* __restrict__ mom_b,
    const int* __restrict__ flags,
    _Float16* __restrict__ xaf,
    float* __restrict__ lr, float* __restrict__ decay, float* __restrict__ mom)
{
  __shared__ float xrow[Dim];
  __shared__ float red[4];
  int r = blockIdx.x, b = r >> 10, t = r & (Seq - 1);
  int tid = threadIdx.x, lane = tid & 63, wid = tid >> 6;
  int fx = flags[0], fw = flags[1];
  int f11 = flags[11], f12 = flags[12], f13 = flags[13], f14 = flags[14];
  int f15 = flags[15], f16_ = flags[16];

  size_t rb = (size_t)r * Dim + tid * 4;
  float v0 = ldin(x, fx, rb + 0), v1 = ldin(x, fx, rb + 1);
  float v2 = ldin(x, fx, rb + 2), v3 = ldin(x, fx, rb + 3);
  float ss = v0 * v0 + v1 * v1 + v2 * v2 + v3 * v3;
#pragma unroll
  for (int m = 1; m < 64; m <<= 1) ss += __shfl_xor(ss, m);
  if (lane == 0) red[wid] = ss;
  __syncthreads();
  float scale = rsqrtf((red[0] + red[1] + red[2] + red[3]) * (1.0f / Dim) + EPSV);

  float a0 = v0 * scale * ldin(w_rms, fw, tid * 4 + 0);
  float a1 = v1 * scale * ldin(w_rms, fw, tid * 4 + 1);
  float a2 = v2 * scale * ldin(w_rms, fw, tid * 4 + 2);
  float a3 = v3 * scale * ldin(w_rms, fw, tid * 4 + 3);
  _Float16 t4[4] = {(_Float16)a0, (_Float16)a1, (_Float16)a2, (_Float16)a3};
  *(ushort4*)&xaf[rb] = *(ushort4*)t4;
  xrow[tid * 4 + 0] = a0; xrow[tid * 4 + 1] = a1;
  xrow[tid * 4 + 2] = a2; xrow[tid * 4 + 3] = a3;
  __syncthreads();

#pragma unroll
  for (int oo = 0; oo < 6; ++oo) {
    int o = wid * 6 + oo;
    int g = o >> 3, h = o & 7;
    const void* W = (g == 0) ? lr_w : ((g == 1) ? decay_w : mom_w);
    int fW = (g == 0) ? f11 : ((g == 1) ? f13 : f15);
    float acc = 0.f;
#pragma unroll
    for (int ii = 0; ii < 16; ++ii) {
      int d = lane + ii * 64;
      acc = fmaf(xrow[d], ldin(W, fW, (size_t)d * Hh + h), acc);
    }
#pragma unroll
    for (int m = 1; m < 64; m <<= 1) acc += __shfl_xor(acc, m);
    if (lane == 0) {
      const void* Bp = (g == 0) ? lr_b : ((g == 1) ? decay_b : mom_b);
      int fB = (g == 0) ? f12 : ((g == 1) ? f14 : f16_);
      float z = acc + ldin(Bp, fB, h);
      float s = 1.f / (1.f + expf(-z));
      float* Op = (g == 0) ? lr : ((g == 1) ? decay : mom);
      Op[(b * Hh + h) * Seq + t] = s;
    }
  }
}

// ---------------------------------------------------------------------------
// K2: depthwise conv, out[t] = sum_k xa[t-2+k]*w[k], zero padded, per batch.
// ---------------------------------------------------------------------------
__global__ __launch_bounds__(256) void k_conv(
    const _Float16* __restrict__ xaf,
    const void* __restrict__ cq, const void* __restrict__ ck,
    const void* __restrict__ cv, const int* __restrict__ flags,
    _Float16* __restrict__ qc, _Float16* __restrict__ kc,
    _Float16* __restrict__ vc)
{
  int r = blockIdx.x, b = r >> 10, t = r & (Seq - 1);
  int c0 = threadIdx.x * 4;
  int f6 = flags[6], f7 = flags[7], f8 = flags[8];

  float lwq[16], lwk[16], lwv[16];
#pragma unroll
  for (int e = 0; e < 16; ++e) {
    lwq[e] = ldin(cq, f6, (size_t)c0 * 4 + e);
    lwk[e] = ldin(ck, f7, (size_t)c0 * 4 + e);
    lwv[e] = ldin(cv, f8, (size_t)c0 * 4 + e);
  }

  float aq[4] = {0.f, 0.f, 0.f, 0.f};
  float ak[4] = {0.f, 0.f, 0.f, 0.f};
  float av[4] = {0.f, 0.f, 0.f, 0.f};
#pragma unroll
  for (int kk = 0; kk < 4; ++kk) {
    int ts = t - 2 + kk;
    float xv[4] = {0.f, 0.f, 0.f, 0.f};
    if (ts >= 0 && ts < Seq) {
      ushort4 u = *(const ushort4*)&xaf[((size_t)(b * Seq + ts)) * Dim + c0];
      _Float16 hx[4]; *(ushort4*)hx = u;
      xv[0] = (float)hx[0]; xv[1] = (float)hx[1];
      xv[2] = (float)hx[2]; xv[3] = (float)hx[3];
    }
#pragma unroll
    for (int j = 0; j < 4; ++j) {
      aq[j] = fmaf(xv[j], lwq[j * 4 + kk], aq[j]);
      ak[j] = fmaf(xv[j], lwk[j * 4 + kk], ak[j]);
      av[j] = fmaf(xv[j], lwv[j * 4 + kk], av[j]);
    }
  }
  _Float16 tq[4], tk[4], tv[4];
#pragma unroll
  for (int j = 0; j < 4; ++j) {
    tq[j] = (_Float16)aq[j]; tk[j] = (_Float16)ak[j]; tv[j] = (_Float16)av[j];
  }
  *(ushort4*)&qc[(size_t)r * Dim + c0] = *(ushort4*)tq;
  *(ushort4*)&kc[(size_t)r * Dim + c0] = *(ushort4*)tk;
  *(ushort4*)&vc[(size_t)r * Dim + c0] = *(ushort4*)tv;
}

// ---------------------------------------------------------------------------
// K3: MFMA GEMM  C[MxN] = A[MxK](f16 ws) * B[KxN](input; flag INDEX passed,
// resolved via flags[]). 64x64 tile, BK=32, batched via blockIdx.z.
// ---------------------------------------------------------------------------
__global__ __launch_bounds__(256) void k_gemm(
    const _Float16* __restrict__ A0, const _Float16* __restrict__ A1,
    const _Float16* __restrict__ A2,
    const void* __restrict__ B0, const void* __restrict__ B1,
    const void* __restrict__ B2,
    int iB0, int iB1, int iB2,
    void* __restrict__ C0, void* __restrict__ C1, void* __restrict__ C2,
    const int* __restrict__ flags,
    int Nn, int Kd, int is_final)
{
  int z = blockIdx.z;
  const _Float16* A = (z == 0) ? A0 : ((z == 1) ? A1 : A2);
  const void* Bm    = (z == 0) ? B0 : ((z == 1) ? B1 : B2);
  int iB            = (z == 0) ? iB0 : ((z == 1) ? iB1 : iB2);
  int fB = flags[iB];                       // 1 = fp32, 0 = bf16
  void* C = (z == 0) ? C0 : ((z == 1) ? C1 : C2);

  __shared__ __align__(16) _Float16 As[64][40];
  __shared__ __align__(16) _Float16 Bs[64][40];

  int tid = threadIdx.x, lane = tid & 63, wvid = tid >> 6;
  int n0 = blockIdx.x * 64, m0 = blockIdx.y * 64;
  int arow = tid >> 2, acol = (tid & 3) * 8;
  int bkk = tid >> 3, bnn = (tid & 7) * 8;
  int mrow = lane & 15, quad = lane >> 4;

  f32x4 acc[4];
#pragma unroll
  for (int mi = 0; mi < 4; ++mi) acc[mi] = (f32x4){0.f, 0.f, 0.f, 0.f};

  for (int kt = 0; kt < Kd; kt += 32) {
    __syncthreads();
    {
      *(uint4*)&As[arow][acol] = *(const uint4*)&A[(size_t)(m0 + arow) * Kd + kt + acol];
#pragma unroll
      for (int j = 0; j < 8; ++j)
        Bs[bnn + j][bkk] = (_Float16)ldin(Bm, fB, (size_t)(kt + bkk) * Nn + n0 + bnn + j);
    }
    __syncthreads();
    half8 bfr = *(const half8*)&Bs[wvid * 16 + mrow][quad * 8];
#pragma unroll
    for (int mi = 0; mi < 4; ++mi) {
      half8 afr = *(const half8*)&As[mi * 16 + mrow][quad * 8];
      acc[mi] = __builtin_amdgcn_mfma_f32_16x16x32_f16(afr, bfr, acc[mi], 0, 0, 0);
    }
  }

  int any_bf16 = 0;
  if (is_final) {
#pragma unroll
    for (int i2 = 0; i2 < 17; ++i2) any_bf16 |= (flags[i2] == 0);
  }

  int col = n0 + wvid * 16 + mrow;
#pragma unroll
  for (int mi = 0; mi < 4; ++mi) {
#pragma unroll
    for (int r2 = 0; r2 < 4; ++r2) {
      int row = m0 + mi * 16 + quad * 4 + r2;
      float v = acc[mi][r2];
      size_t idx = (size_t)row * Nn + col;
      if (!is_final)        ((_Float16*)C)[idx] = (_Float16)v;
      else if (any_bf16)    ((unsigned short*)C)[idx] = f2bf(v);
      else                  ((float*)C)[idx] = v;
    }
  }
}

// ---------------------------------------------------------------------------
// Recurrence. State 64x64/seq, thread owns (i = tid>>2, j0 = (tid&3)*16).
// Z_t = m_t Z_{t-1} - v_i k_j ; S_t = d_t S_{t-1} - l_t Z_t ; y_t = S_{t-1} q_t
// Chunked: Z_t = Mcum Z_in + Zloc ; S_t = Dcum S_in + w Z_in + Sloc
// ---------------------------------------------------------------------------
__global__ __launch_bounds__(256) void k_phaseA(
    const _Float16* __restrict__ kpre, const _Float16* __restrict__ vpre,
    const void* __restrict__ gamma_k, const int* __restrict__ flags,
    const float* __restrict__ lr, const float* __restrict__ decay,
    const float* __restrict__ mom,
    _Float16* __restrict__ ZS_Z, _Float16* __restrict__ ZS_S,
    float* __restrict__ Mc, float* __restrict__ Dc, float* __restrict__ Wc)
{
  int c = blockIdx.x, s = blockIdx.y;
  int b = s >> 3, h = s & 7;
  int tid = threadIdx.x, lane = tid & 63, wid = tid >> 6;
  int i = tid >> 2, j0 = (tid & 3) * 16;
  __shared__ float kls[64], vls[64], gls[3];
  float Zl[16], Sl[16];
#pragma unroll
  for (int jj = 0; jj < 16; ++jj) { Zl[jj] = 0.f; Sl[jj] = 0.f; }
  float Mcum = 1.f, Dcum = 1.f, wacc = 0.f;
  float gk = ldin(gamma_k, flags[10], (size_t)h * 64 + lane);

  for (int t = 0; t < CLEN; ++t) {
    int T = c * CLEN + t;
    __syncthreads();
    if (wid == 0) {
      float kv = (float)kpre[((size_t)(b * Seq + T)) * Di + h * 64 + lane];
      float ss = kv * kv;
#pragma unroll
      for (int m = 1; m < 64; m <<= 1) ss += __shfl_xor(ss, m);
      kls[lane] = kv * (1.f / fmaxf(sqrtf(ss) * 0.125f, 1e-8f)) * gk;
    } else if (wid == 1) {
      vls[lane] = (float)vpre[((size_t)(b * Seq + T)) * Di + h * 64 + lane];
    } else if (wid == 2) {
      if (lane < 3) {
        const float* gp = (lane == 0) ? lr : ((lane == 1) ? decay : mom);
        gls[lane] = gp[s * Seq + T];
      }
    }
    __syncthreads();
    float l = gls[0], dd = gls[1], mm = gls[2];
    float vi = vls[i];
    Mcum *= mm;
#pragma unroll
    for (int jj = 0; jj < 16; ++jj) {
      Zl[jj] = fmaf(mm, Zl[jj], -vi * kls[j0 + jj]);
      Sl[jj] = fmaf(dd, Sl[jj], -l * Zl[jj]);
    }
    wacc = fmaf(dd, wacc, -l * Mcum);
    Dcum *= dd;
  }
  size_t base = ((size_t)(s * CHUNK + c)) * 4096 + (size_t)i * 64 + j0;
#pragma unroll
  for (int jj = 0; jj < 16; ++jj) {
    ZS_Z[base + jj] = (_Float16)Zl[jj];
    ZS_S[base + jj] = (_Float16)Sl[jj];
  }
  if (tid == 0) {
    Mc[s * CHUNK + c] = Mcum; Dc[s * CHUNK + c] = Dcum; Wc[s * CHUNK + c] = wacc;
  }
}

__global__ __launch_bounds__(256) void k_phaseB(
    _Float16* __restrict__ ZS_Z, _Float16* __restrict__ ZS_S,
    const float* __restrict__ Mc, const float* __restrict__ Dc,
    const float* __restrict__ Wc)
{
  int s = blockIdx.x;
  int e = blockIdx.y * 256 + threadIdx.x;
  float Z = 0.f, S = 0.f;
  for (int c = 0; c < CHUNK; ++c) {
    size_t base = ((size_t)(s * CHUNK + c)) * 4096 + e;
    float mc = Mc[s * CHUNK + c], dc = Dc[s * CHUNK + c], wc = Wc[s * CHUNK + c];
    float zl = (float)ZS_Z[base], sl = (float)ZS_S[base];
    ZS_Z[base] = (_Float16)Z; ZS_S[base] = (_Float16)S;   // chunk inputs
    S = fmaf(dc, S, fmaf(wc, Z, sl));  // uses OLD Z (= chunk input)
    Z = fmaf(mc, Z, zl);
  }
}

__global__ __launch_bounds__(256) void k_phaseC(
    const _Float16* __restrict__ qpre, const _Float16* __restrict__ kpre,
    const _Float16* __restrict__ vpre,
    const void* __restrict__ gamma_q, const void* __restrict__ gamma_k,
    const int* __restrict__ flags,
    const float* __restrict__ lr, const float* __restrict__ decay,
    const float* __restrict__ mom,
    const _Float16* __restrict__ ZS_Z, const _Float16* __restrict__ ZS_S,
    _Float16* __restrict__ yb)
{
  int c = blockIdx.x, s = blockIdx.y;
  int b = s >> 3, h = s & 7;
  int tid = threadIdx.x, lane = tid & 63, wid = tid >> 6;
  int i = tid >> 2, j0 = (tid & 3) * 16;
  __shared__ float kls[64], vls[64], qls[64], gls[3];

  float Zi_[16], Si_[16], Zl[16], Sl[16];
  size_t base = ((size_t)(s * CHUNK + c)) * 4096 + (size_t)i * 64 + j0;
#pragma unroll
  for (int jj = 0; jj < 16; ++jj) {
    Zi_[jj] = (float)ZS_Z[base + jj]; Si_[jj] = (float)ZS_S[base + jj];
    Zl[jj] = 0.f; Sl[jj] = 0.f;
  }
  float Mcum = 1.f, Dcum = 1.f, wacc = 0.f;
  float Dprev = 1.f, wprev = 0.f;
  float gk = ldin(gamma_k, flags[10], (size_t)h * 64 + lane);
  float gq = ldin(gamma_q, flags[9],  (size_t)h * 64 + lane);

  for (int t = 0; t < CLEN; ++t) {
    int T = c * CLEN + t;
    __syncthreads();
    if (wid == 0) {
      float kv = (float)kpre[((size_t)(b * Seq + T)) * Di + h * 64 + lane];
      float ss = kv * kv;
#pragma unroll
      for (int m = 1; m < 64; m <<= 1) ss += __shfl_xor(ss, m);
      kls[lane] = kv * (1.f / fmaxf(sqrtf(ss) * 0.125f, 1e-8f)) * gk;
    } else if (wid == 1) {
      vls[lane] = (float)vpre[((size_t)(b * Seq + T)) * Di + h * 64 + lane];
    } else if (wid == 2) {
      float qv = (float)qpre[((size_t)(b * Seq + T)) * Di + h * 64 + lane];
      float ss = qv * qv;
#pragma unroll
      for (int m = 1; m < 64; m <<= 1) ss += __shfl_xor(ss, m);
      qls[lane] = qv * (1.f / fmaxf(sqrtf(ss) * 0.125f, 1e-8f)) * gq;
    } else {
      if (lane < 3) {
        const float* gp = (lane == 0) ? lr : ((lane == 1) ? decay : mom);
        gls[lane] = gp[s * Seq + T];
      }
    }
    __syncthreads();
    float l = gls[0], dd = gls[1], mm = gls[2];

    float yp = 0.f;
#pragma unroll
    for (int jj = 0; jj < 16; ++jj) {
      float tmp = fmaf(Dprev, Si_[jj], fmaf(wprev, Zi_[jj], Sl[jj]));
      yp = fmaf(tmp, qls[j0 + jj], yp);
    }
    yp += __shfl_xor(yp, 1);
    yp += __shfl_xor(yp, 2);
    if ((tid & 3) == 0)
      yb[((size_t)(b * Seq + T)) * Di + h * 64 + i] = (_Float16)yp;

    float vi = vls[i];
    Mcum *= mm;
#pragma unroll
    for (int jj = 0; jj < 16; ++jj) {
      Zl[jj] = fmaf(mm, Zl[jj], -vi * kls[j0 + jj]);
      Sl[jj] = fmaf(dd, Sl[jj], -l * Zl[jj]);
    }
    wacc = fmaf(dd, wacc, -l * Mcum);
    Dcum *= dd;
    Dprev = Dcum; wprev = wacc;
  }
}

// ---------------------------------------------------------------------------
extern "C" void kernel_launch(void* const* d_in, const int* in_sizes, int n_in,
                              void* d_out, int out_size, void* d_ws, size_t ws_size,
                              hipStream_t stream) {
  InPtrs ip;
  for (int i = 0; i < 17; ++i) { ip.p[i] = d_in[i]; ip.n[i] = in_sizes[i]; }

  char* p = (char*)d_ws;
  auto take = [&](size_t bytes) -> char* {
    char* q = p; p += (bytes + 255) & ~(size_t)255; return q;
  };
  int* flags           = (int*)take(32 * 4);
  _Float16* xaf        = (_Float16*)take((size_t)BN * Dim * 2);
  _Float16* qc         = (_Float16*)take((size_t)BN * Dim * 2);
  _Float16* kc         = (_Float16*)take((size_t)BN * Dim * 2);
  _Float16* vc         = (_Float16*)take((size_t)BN * Dim * 2);
  _Float16* qpre       = (_Float16*)take((size_t)BN * Di * 2);
  _Float16* kpre       = (_Float16*)take((size_t)BN * Di * 2);
  _Float16* vpre       = (_Float16*)take((size_t)BN * Di * 2);
  float* lrA           = (float*)take((size_t)NSEQ * Seq * 4);
  float* decayA        = (float*)take((size_t)NSEQ * Seq * 4);
  float* momA          = (float*)take((size_t)NSEQ * Seq * 4);
  _Float16* ZS_Z       = (_Float16*)take((size_t)NSEQ * CHUNK * 4096 * 2);
  _Float16* ZS_S       = (_Float16*)take((size_t)NSEQ * CHUNK * 4096 * 2);
  float* Mc            = (float*)take((size_t)NSEQ * CHUNK * 4);
  float* Dc            = (float*)take((size_t)NSEQ * CHUNK * 4);
  float* Wc            = (float*)take((size_t)NSEQ * CHUNK * 4);
  _Float16* yb         = (_Float16*)take((size_t)BN * Di * 2);

  k_sniff<<<17, 64, 0, stream>>>(ip, flags);

  k_rms_gates<<<BN, 256, 0, stream>>>(d_in[0], d_in[1], d_in[11], d_in[13], d_in[15],
                                      d_in[12], d_in[14], d_in[16], flags,
                                      xaf, lrA, decayA, momA);
  k_conv<<<BN, 256, 0, stream>>>(xaf, d_in[6], d_in[7], d_in[8], flags, qc, kc, vc);

  dim3 g1(Di / 64, BN / 64, 3);
  k_gemm<<<g1, 256, 0, stream>>>(qc, kc, vc, d_in[2], d_in[3], d_in[4],
                                 2, 3, 4,
                                 qpre, kpre, vpre, flags, Di, Dim, 0);

  k_phaseA<<<dim3(CHUNK, NSEQ), 256, 0, stream>>>(kpre, vpre, d_in[10], flags,
                                                  lrA, decayA, momA,
                                                  ZS_Z, ZS_S, Mc, Dc, Wc);
  k_phaseB<<<dim3(NSEQ, 16), 256, 0, stream>>>(ZS_Z, ZS_S, Mc, Dc, Wc);
  k_phaseC<<<dim3(CHUNK, NSEQ), 256, 0, stream>>>(qpre, kpre, vpre, d_in[9], d_in[10],
                                                  flags, lrA, decayA, momA,
                                                  ZS_Z, ZS_S, yb);

  dim3 g2(Dim / 64, BN / 64, 1);
  k_gemm<<<g2, 256, 0, stream>>>(yb, yb, yb, d_in[5], d_in[5], d_in[5],
                                 5, 5, 5,
                                 d_out, d_out, d_out, flags, Dim, Di, 1);
}

// Round 7
// 311.821 us; speedup vs baseline: 1.4442x; 1.4442x over previous
//
#include <hip/hip_runtime.h>
#include <math.h>

#define DEV __device__ __forceinline__

constexpr int Bb   = 2;
constexpr int Seq  = 1024;
constexpr int Dim  = 1024;
constexpr int Hh   = 8;
constexpr int Dh   = 64;
constexpr int Di   = 512;
constexpr int BN   = Bb * Seq;       // 2048
constexpr int NSEQ = Bb * Hh;        // 16
constexpr int CHUNK = 32;            // chunks per sequence
constexpr int CLEN  = Seq / CHUNK;   // 32
constexpr float EPSV = 1.1920929e-07f;

typedef _Float16 half8 __attribute__((ext_vector_type(8)));
typedef float    f32x4 __attribute__((ext_vector_type(4)));

DEV float bf2f(unsigned short u) {
  union { unsigned int i; float f; } x; x.i = ((unsigned int)u) << 16; return x.f;
}
DEV unsigned short f2bf(float f) {
  union { float f; unsigned int i; } x; x.f = f;
  unsigned int r = x.i + 0x7fffu + ((x.i >> 16) & 1u);
  return (unsigned short)(r >> 16);
}
// flag: 1 -> fp32, 0 -> bf16
DEV float ldin(const void* p, int f32, size_t i) {
  if (f32) return ((const float*)p)[i];
  return bf2f(((const unsigned short*)p)[i]);
}

struct InPtrs { const void* p[17]; int n[17]; };

// ---------------------------------------------------------------------------
// K0: dtype sniffer (proven round 6). flags[b]: 1 = fp32, 0 = bf16.
// ---------------------------------------------------------------------------
__global__ __launch_bounds__(64) void k_sniff(InPtrs ip, int* __restrict__ flags) {
  int b = blockIdx.x, tid = threadIdx.x;
  const unsigned short* u = (const unsigned short*)ip.p[b];
  int count = ip.n[b];
  int j = 2 * tid;
  int valid = 0, bad = 0;
  if (j < count) {
    valid = 1;
    float v = bf2f(u[j]);
    float a = fabsf(v);
    if (!(a >= 1e-12f && a <= 1e4f)) bad = 1;
  }
#pragma unroll
  for (int m = 1; m < 64; m <<= 1) { valid += __shfl_xor(valid, m); bad += __shfl_xor(bad, m); }
  if (tid == 0) flags[b] = (2 * bad > valid) ? 1 : 0;
}

// ---------------------------------------------------------------------------
// K0b: weight prep — convert + transpose wq/wk/wv (1024x512) and wo (512x1024)
// into f16 [N][K] layout. One-time cost; removes all dtype branches from GEMM.
// ---------------------------------------------------------------------------
__global__ __launch_bounds__(256) void k_prep_w(
    const void* __restrict__ wq, const void* __restrict__ wk,
    const void* __restrict__ wv, const void* __restrict__ wo,
    const int* __restrict__ flags,
    _Float16* __restrict__ wqT, _Float16* __restrict__ wkT,
    _Float16* __restrict__ wvT, _Float16* __restrict__ woT)
{
  int z = blockIdx.z;
  const void* src = (z == 0) ? wq : ((z == 1) ? wk : ((z == 2) ? wv : wo));
  _Float16* dst   = (z == 0) ? wqT : ((z == 1) ? wkT : ((z == 2) ? wvT : woT));
  int f = flags[(z == 0) ? 2 : ((z == 1) ? 3 : ((z == 2) ? 4 : 5))];
  int Kd = (z < 3) ? Dim : Di;   // rows of src
  int Nn = (z < 3) ? Di : Dim;   // cols of src
  int n0 = blockIdx.x * 64, k0 = blockIdx.y * 64;
  if (n0 >= Nn || k0 >= Kd) return;

  __shared__ float tile[64][65];
  int tid = threadIdx.x;
  int r = tid >> 4, c4 = (tid & 15) * 4;
#pragma unroll
  for (int rr = 0; rr < 4; ++rr) {
    int k = rr * 16 + r;
#pragma unroll
    for (int j = 0; j < 4; ++j)
      tile[k][c4 + j] = ldin(src, f, (size_t)(k0 + k) * Nn + n0 + c4 + j);
  }
  __syncthreads();
#pragma unroll
  for (int rr = 0; rr < 4; ++rr) {
    int n = rr * 16 + r;
    _Float16 o4[4];
#pragma unroll
    for (int j = 0; j < 4; ++j) o4[j] = (_Float16)tile[c4 + j][n];
    *(ushort4*)&dst[(size_t)(n0 + n) * Kd + k0 + c4] = *(ushort4*)o4;
  }
}

// K0c: decode gamma_q/gamma_k to f32
__global__ __launch_bounds__(256) void k_prep_gamma(
    const void* __restrict__ gq, const void* __restrict__ gk,
    const int* __restrict__ flags, float* __restrict__ gqf, float* __restrict__ gkf)
{
  int tid = threadIdx.x;
  int f9 = flags[9], f10 = flags[10];
  for (int i = tid; i < Di; i += 256) {
    gqf[i] = ldin(gq, f9, i);
    gkf[i] = ldin(gk, f10, i);
  }
}

// ---------------------------------------------------------------------------
// K1: RMSNorm(x) -> xa (f16), fused gate projections sigmoid(xa@W+b)
// ---------------------------------------------------------------------------
__global__ __launch_bounds__(256) void k_rms_gates(
    const void* __restrict__ x, const void* __restrict__ w_rms,
    const void* __restrict__ lr_w, const void* __restrict__ decay_w,
    const void* __restrict__ mom_w,
    const void* __restrict__ lr_b, const void* __restrict__ decay_b,
    const void* __restrict__ mom_b,
    const int* __restrict__ flags,
    _Float16* __restrict__ xaf,
    float* __restrict__ lr, float* __restrict__ decay, float* __restrict__ mom)
{
  __shared__ float xrow[Dim];
  __shared__ float red[4];
  int r = blockIdx.x, b = r >> 10, t = r & (Seq - 1);
  int tid = threadIdx.x, lane = tid & 63, wid = tid >> 6;
  int fx = flags[0], fw = flags[1];
  int f11 = flags[11], f12 = flags[12], f13 = flags[13], f14 = flags[14];
  int f15 = flags[15], f16_ = flags[16];

  size_t rb = (size_t)r * Dim + tid * 4;
  float v0, v1, v2, v3;
  if (fx) {
    float4 u = *(const float4*)((const float*)x + rb);
    v0 = u.x; v1 = u.y; v2 = u.z; v3 = u.w;
  } else {
    ushort4 u = *(const ushort4*)((const unsigned short*)x + rb);
    v0 = bf2f(u.x); v1 = bf2f(u.y); v2 = bf2f(u.z); v3 = bf2f(u.w);
  }
  float ss = v0 * v0 + v1 * v1 + v2 * v2 + v3 * v3;
#pragma unroll
  for (int m = 1; m < 64; m <<= 1) ss += __shfl_xor(ss, m);
  if (lane == 0) red[wid] = ss;
  __syncthreads();
  float scale = rsqrtf((red[0] + red[1] + red[2] + red[3]) * (1.0f / Dim) + EPSV);

  float w0, w1, w2, w3;
  if (fw) {
    float4 u = *(const float4*)((const float*)w_rms + tid * 4);
    w0 = u.x; w1 = u.y; w2 = u.z; w3 = u.w;
  } else {
    ushort4 u = *(const ushort4*)((const unsigned short*)w_rms + tid * 4);
    w0 = bf2f(u.x); w1 = bf2f(u.y); w2 = bf2f(u.z); w3 = bf2f(u.w);
  }
  float a0 = v0 * scale * w0, a1 = v1 * scale * w1;
  float a2 = v2 * scale * w2, a3 = v3 * scale * w3;
  _Float16 t4[4] = {(_Float16)a0, (_Float16)a1, (_Float16)a2, (_Float16)a3};
  *(ushort4*)&xaf[rb] = *(ushort4*)t4;
  xrow[tid * 4 + 0] = a0; xrow[tid * 4 + 1] = a1;
  xrow[tid * 4 + 2] = a2; xrow[tid * 4 + 3] = a3;
  __syncthreads();

#pragma unroll
  for (int oo = 0; oo < 6; ++oo) {
    int o = wid * 6 + oo;
    int g = o >> 3, h = o & 7;
    const void* W = (g == 0) ? lr_w : ((g == 1) ? decay_w : mom_w);
    int fW = (g == 0) ? f11 : ((g == 1) ? f13 : f15);
    float acc = 0.f;
#pragma unroll
    for (int ii = 0; ii < 16; ++ii) {
      int d = lane + ii * 64;
      acc = fmaf(xrow[d], ldin(W, fW, (size_t)d * Hh + h), acc);
    }
#pragma unroll
    for (int m = 1; m < 64; m <<= 1) acc += __shfl_xor(acc, m);
    if (lane == 0) {
      const void* Bp = (g == 0) ? lr_b : ((g == 1) ? decay_b : mom_b);
      int fB = (g == 0) ? f12 : ((g == 1) ? f14 : f16_);
      float z = acc + ldin(Bp, fB, h);
      float s = 1.f / (1.f + expf(-z));
      float* Op = (g == 0) ? lr : ((g == 1) ? decay : mom);
      Op[(b * Hh + h) * Seq + t] = s;
    }
  }
}

// ---------------------------------------------------------------------------
// K2: depthwise conv (unchanged; weights cached)
// ---------------------------------------------------------------------------
__global__ __launch_bounds__(256) void k_conv(
    const _Float16* __restrict__ xaf,
    const void* __restrict__ cq, const void* __restrict__ ck,
    const void* __restrict__ cv, const int* __restrict__ flags,
    _Float16* __restrict__ qc, _Float16* __restrict__ kc,
    _Float16* __restrict__ vc)
{
  int r = blockIdx.x, b = r >> 10, t = r & (Seq - 1);
  int c0 = threadIdx.x * 4;
  int f6 = flags[6], f7 = flags[7], f8 = flags[8];

  float lwq[16], lwk[16], lwv[16];
#pragma unroll
  for (int e = 0; e < 16; ++e) {
    lwq[e] = ldin(cq, f6, (size_t)c0 * 4 + e);
    lwk[e] = ldin(ck, f7, (size_t)c0 * 4 + e);
    lwv[e] = ldin(cv, f8, (size_t)c0 * 4 + e);
  }

  float aq[4] = {0.f, 0.f, 0.f, 0.f};
  float ak[4] = {0.f, 0.f, 0.f, 0.f};
  float av[4] = {0.f, 0.f, 0.f, 0.f};
#pragma unroll
  for (int kk = 0; kk < 4; ++kk) {
    int ts = t - 2 + kk;
    float xv[4] = {0.f, 0.f, 0.f, 0.f};
    if (ts >= 0 && ts < Seq) {
      ushort4 u = *(const ushort4*)&xaf[((size_t)(b * Seq + ts)) * Dim + c0];
      _Float16 hx[4]; *(ushort4*)hx = u;
      xv[0] = (float)hx[0]; xv[1] = (float)hx[1];
      xv[2] = (float)hx[2]; xv[3] = (float)hx[3];
    }
#pragma unroll
    for (int j = 0; j < 4; ++j) {
      aq[j] = fmaf(xv[j], lwq[j * 4 + kk], aq[j]);
      ak[j] = fmaf(xv[j], lwk[j * 4 + kk], ak[j]);
      av[j] = fmaf(xv[j], lwv[j * 4 + kk], av[j]);
    }
  }
  _Float16 tq[4], tk[4], tv[4];
#pragma unroll
  for (int j = 0; j < 4; ++j) {
    tq[j] = (_Float16)aq[j]; tk[j] = (_Float16)ak[j]; tv[j] = (_Float16)av[j];
  }
  *(ushort4*)&qc[(size_t)r * Dim + c0] = *(ushort4*)tq;
  *(ushort4*)&kc[(size_t)r * Dim + c0] = *(ushort4*)tk;
  *(ushort4*)&vc[(size_t)r * Dim + c0] = *(ushort4*)tv;
}

// ---------------------------------------------------------------------------
// K3: MFMA GEMM with pre-transposed f16 B [N][K]. Both stagings are one
// uint4 global load + one uint4 LDS store. 64x64 tile, BK=32.
// ---------------------------------------------------------------------------
__global__ __launch_bounds__(256) void k_gemm_bt(
    const _Float16* __restrict__ A0, const _Float16* __restrict__ A1,
    const _Float16* __restrict__ A2,
    const _Float16* __restrict__ B0, const _Float16* __restrict__ B1,
    const _Float16* __restrict__ B2,
    void* __restrict__ C0, void* __restrict__ C1, void* __restrict__ C2,
    const int* __restrict__ flags,
    int Nn, int Kd, int is_final)
{
  int z = blockIdx.z;
  const _Float16* A  = (z == 0) ? A0 : ((z == 1) ? A1 : A2);
  const _Float16* Bt = (z == 0) ? B0 : ((z == 1) ? B1 : B2);
  void* C = (z == 0) ? C0 : ((z == 1) ? C1 : C2);

  __shared__ __align__(16) _Float16 As[64][40];
  __shared__ __align__(16) _Float16 Bs[64][40];

  int tid = threadIdx.x, lane = tid & 63, wvid = tid >> 6;
  int n0 = blockIdx.x * 64, m0 = blockIdx.y * 64;
  int srow = tid >> 2, scol = (tid & 3) * 8;
  int mrow = lane & 15, quad = lane >> 4;

  f32x4 acc[4];
#pragma unroll
  for (int mi = 0; mi < 4; ++mi) acc[mi] = (f32x4){0.f, 0.f, 0.f, 0.f};

  for (int kt = 0; kt < Kd; kt += 32) {
    __syncthreads();
    *(uint4*)&As[srow][scol] = *(const uint4*)&A[(size_t)(m0 + srow) * Kd + kt + scol];
    *(uint4*)&Bs[srow][scol] = *(const uint4*)&Bt[(size_t)(n0 + srow) * Kd + kt + scol];
    __syncthreads();
    half8 bfr = *(const half8*)&Bs[wvid * 16 + mrow][quad * 8];
#pragma unroll
    for (int mi = 0; mi < 4; ++mi) {
      half8 afr = *(const half8*)&As[mi * 16 + mrow][quad * 8];
      acc[mi] = __builtin_amdgcn_mfma_f32_16x16x32_f16(afr, bfr, acc[mi], 0, 0, 0);
    }
  }

  int any_bf16 = 0;
  if (is_final) {
#pragma unroll
    for (int i2 = 0; i2 < 17; ++i2) any_bf16 |= (flags[i2] == 0);
  }

  int col = n0 + wvid * 16 + mrow;
#pragma unroll
  for (int mi = 0; mi < 4; ++mi) {
#pragma unroll
    for (int r2 = 0; r2 < 4; ++r2) {
      int row = m0 + mi * 16 + quad * 4 + r2;
      float v = acc[mi][r2];
      size_t idx = (size_t)row * Nn + col;
      if (!is_final)        ((_Float16*)C)[idx] = (_Float16)v;
      else if (any_bf16)    ((unsigned short*)C)[idx] = f2bf(v);
      else                  ((float*)C)[idx] = v;
    }
  }
}

// ---------------------------------------------------------------------------
// Recurrence phases. LDS-preloaded chunk, barrier-free serial loop.
// Z_t = m_t Z_{t-1} - v_i k_j ; S_t = d_t S_{t-1} - l_t Z_t ; y_t = S_{t-1} q_t
// ---------------------------------------------------------------------------
__global__ __launch_bounds__(256) void k_phaseA(
    const _Float16* __restrict__ kpre, const _Float16* __restrict__ vpre,
    const float* __restrict__ gkf,
    const float* __restrict__ lr, const float* __restrict__ decay,
    const float* __restrict__ mom,
    _Float16* __restrict__ ZS_Z, _Float16* __restrict__ ZS_S,
    float* __restrict__ Mc, float* __restrict__ Dc, float* __restrict__ Wc)
{
  int c = blockIdx.x, s = blockIdx.y;
  int b = s >> 3, h = s & 7;
  int tid = threadIdx.x, lane = tid & 63, wv = tid >> 6;
  int i = tid >> 2, j0 = (tid & 3) * 16;
  __shared__ float kn[CLEN][64], vv[CLEN][64];
  __shared__ float gl[CLEN], gd[CLEN], gm[CLEN];

  {
    int t = tid >> 3, col = (tid & 7) * 8;
    size_t g = ((size_t)(b * Seq + c * CLEN + t)) * Di + h * 64 + col;
    half8 kv = *(const half8*)&kpre[g];
    half8 vvv = *(const half8*)&vpre[g];
#pragma unroll
    for (int j = 0; j < 8; ++j) { kn[t][col + j] = (float)kv[j]; vv[t][col + j] = (float)vvv[j]; }
    if (tid < 96) {
      int which = tid >> 5, t2 = tid & 31;
      const float* gp = (which == 0) ? lr : ((which == 1) ? decay : mom);
      float val = gp[s * Seq + c * CLEN + t2];
      if (which == 0) gl[t2] = val; else if (which == 1) gd[t2] = val; else gm[t2] = val;
    }
  }
  __syncthreads();
  {
    float gk = gkf[h * 64 + lane];
#pragma unroll
    for (int tt = 0; tt < 8; ++tt) {
      int t = wv * 8 + tt;
      float kvv = kn[t][lane];
      float ss = kvv * kvv;
#pragma unroll
      for (int m = 1; m < 64; m <<= 1) ss += __shfl_xor(ss, m);
      kn[t][lane] = kvv * (1.f / fmaxf(sqrtf(ss) * 0.125f, 1e-8f)) * gk;
    }
  }
  __syncthreads();

  float Zl[16], Sl[16];
#pragma unroll
  for (int jj = 0; jj < 16; ++jj) { Zl[jj] = 0.f; Sl[jj] = 0.f; }
  float Mcum = 1.f, Dcum = 1.f, wacc = 0.f;

  for (int t = 0; t < CLEN; ++t) {
    float l = gl[t], dd = gd[t], mm = gm[t];
    float vi = vv[t][i];
    Mcum *= mm;
#pragma unroll
    for (int jj = 0; jj < 16; ++jj) {
      Zl[jj] = fmaf(mm, Zl[jj], -vi * kn[t][j0 + jj]);
      Sl[jj] = fmaf(dd, Sl[jj], -l * Zl[jj]);
    }
    wacc = fmaf(dd, wacc, -l * Mcum);
    Dcum *= dd;
  }
  size_t base = ((size_t)(s * CHUNK + c)) * 4096 + (size_t)i * 64 + j0;
  half8 zo0, zo1, so0, so1;
#pragma unroll
  for (int jj = 0; jj < 8; ++jj) {
    zo0[jj] = (_Float16)Zl[jj];     zo1[jj] = (_Float16)Zl[jj + 8];
    so0[jj] = (_Float16)Sl[jj];     so1[jj] = (_Float16)Sl[jj + 8];
  }
  *(half8*)&ZS_Z[base] = zo0; *(half8*)&ZS_Z[base + 8] = zo1;
  *(half8*)&ZS_S[base] = so0; *(half8*)&ZS_S[base + 8] = so1;
  if (tid == 0) {
    Mc[s * CHUNK + c] = Mcum; Dc[s * CHUNK + c] = Dcum; Wc[s * CHUNK + c] = wacc;
  }
}

__global__ __launch_bounds__(256) void k_phaseB(
    _Float16* __restrict__ ZS_Z, _Float16* __restrict__ ZS_S,
    const float* __restrict__ Mc, const float* __restrict__ Dc,
    const float* __restrict__ Wc)
{
  int s = blockIdx.x;
  int e = blockIdx.y * 256 + threadIdx.x;
  float Z = 0.f, S = 0.f;
  for (int c = 0; c < CHUNK; ++c) {
    size_t base = ((size_t)(s * CHUNK + c)) * 4096 + e;
    float mc = Mc[s * CHUNK + c], dc = Dc[s * CHUNK + c], wc = Wc[s * CHUNK + c];
    float zl = (float)ZS_Z[base], sl = (float)ZS_S[base];
    ZS_Z[base] = (_Float16)Z; ZS_S[base] = (_Float16)S;   // chunk inputs
    S = fmaf(dc, S, fmaf(wc, Z, sl));  // uses OLD Z (= chunk input)
    Z = fmaf(mc, Z, zl);
  }
}

__global__ __launch_bounds__(256) void k_phaseC(
    const _Float16* __restrict__ qpre, const _Float16* __restrict__ kpre,
    const _Float16* __restrict__ vpre,
    const float* __restrict__ gqf, const float* __restrict__ gkf,
    const float* __restrict__ lr, const float* __restrict__ decay,
    const float* __restrict__ mom,
    const _Float16* __restrict__ ZS_Z, const _Float16* __restrict__ ZS_S,
    _Float16* __restrict__ yb)
{
  int c = blockIdx.x, s = blockIdx.y;
  int b = s >> 3, h = s & 7;
  int tid = threadIdx.x, lane = tid & 63, wv = tid >> 6;
  int i = tid >> 2, j0 = (tid & 3) * 16;
  __shared__ float kn[CLEN][64], vv[CLEN][64], qn[CLEN][64];
  __shared__ float gl[CLEN], gd[CLEN], gm[CLEN];

  float Zi_[16], Si_[16], Zl[16], Sl[16];
  size_t base = ((size_t)(s * CHUNK + c)) * 4096 + (size_t)i * 64 + j0;
  {
    half8 z0 = *(const half8*)&ZS_Z[base], z1 = *(const half8*)&ZS_Z[base + 8];
    half8 s0 = *(const half8*)&ZS_S[base], s1 = *(const half8*)&ZS_S[base + 8];
#pragma unroll
    for (int jj = 0; jj < 8; ++jj) {
      Zi_[jj] = (float)z0[jj]; Zi_[jj + 8] = (float)z1[jj];
      Si_[jj] = (float)s0[jj]; Si_[jj + 8] = (float)s1[jj];
      Zl[jj] = 0.f; Zl[jj + 8] = 0.f; Sl[jj] = 0.f; Sl[jj + 8] = 0.f;
    }
  }
  {
    int t = tid >> 3, col = (tid & 7) * 8;
    size_t g = ((size_t)(b * Seq + c * CLEN + t)) * Di + h * 64 + col;
    half8 kv = *(const half8*)&kpre[g];
    half8 vvv = *(const half8*)&vpre[g];
    half8 qv = *(const half8*)&qpre[g];
#pragma unroll
    for (int j = 0; j < 8; ++j) {
      kn[t][col + j] = (float)kv[j]; vv[t][col + j] = (float)vvv[j];
      qn[t][col + j] = (float)qv[j];
    }
    if (tid < 96) {
      int which = tid >> 5, t2 = tid & 31;
      const float* gp = (which == 0) ? lr : ((which == 1) ? decay : mom);
      float val = gp[s * Seq + c * CLEN + t2];
      if (which == 0) gl[t2] = val; else if (which == 1) gd[t2] = val; else gm[t2] = val;
    }
  }
  __syncthreads();
  {
    float gk = gkf[h * 64 + lane];
    float gq = gqf[h * 64 + lane];
#pragma unroll
    for (int tt = 0; tt < 8; ++tt) {
      int t = wv * 8 + tt;
      float kvv = kn[t][lane];
      float ssk = kvv * kvv;
      float qvv = qn[t][lane];
      float ssq = qvv * qvv;
#pragma unroll
      for (int m = 1; m < 64; m <<= 1) { ssk += __shfl_xor(ssk, m); ssq += __shfl_xor(ssq, m); }
      kn[t][lane] = kvv * (1.f / fmaxf(sqrtf(ssk) * 0.125f, 1e-8f)) * gk;
      qn[t][lane] = qvv * (1.f / fmaxf(sqrtf(ssq) * 0.125f, 1e-8f)) * gq;
    }
  }
  __syncthreads();

  float Mcum = 1.f, Dcum = 1.f, wacc = 0.f;
  float Dprev = 1.f, wprev = 0.f;

  for (int t = 0; t < CLEN; ++t) {
    float l = gl[t], dd = gd[t], mm = gm[t];

    // y_t with state BEFORE this step's update
    float yp = 0.f;
#pragma unroll
    for (int jj = 0; jj < 16; ++jj) {
      float tmp = fmaf(Dprev, Si_[jj], fmaf(wprev, Zi_[jj], Sl[jj]));
      yp = fmaf(tmp, qn[t][j0 + jj], yp);
    }
    yp += __shfl_xor(yp, 1);
    yp += __shfl_xor(yp, 2);
    if ((tid & 3) == 0)
      yb[((size_t)(b * Seq + c * CLEN + t)) * Di + h * 64 + i] = (_Float16)yp;

    float vi = vv[t][i];
    Mcum *= mm;
#pragma unroll
    for (int jj = 0; jj < 16; ++jj) {
      Zl[jj] = fmaf(mm, Zl[jj], -vi * kn[t][j0 + jj]);
      Sl[jj] = fmaf(dd, Sl[jj], -l * Zl[jj]);
    }
    wacc = fmaf(dd, wacc, -l * Mcum);
    Dcum *= dd;
    Dprev = Dcum; wprev = wacc;
  }
}

// ---------------------------------------------------------------------------
extern "C" void kernel_launch(void* const* d_in, const int* in_sizes, int n_in,
                              void* d_out, int out_size, void* d_ws, size_t ws_size,
                              hipStream_t stream) {
  InPtrs ip;
  for (int i = 0; i < 17; ++i) { ip.p[i] = d_in[i]; ip.n[i] = in_sizes[i]; }

  char* p = (char*)d_ws;
  auto take = [&](size_t bytes) -> char* {
    char* q = p; p += (bytes + 255) & ~(size_t)255; return q;
  };
  int* flags           = (int*)take(32 * 4);
  _Float16* xaf        = (_Float16*)take((size_t)BN * Dim * 2);   // 4 MB
  _Float16* qc         = (_Float16*)take((size_t)BN * Dim * 2);   // 4 MB
  _Float16* kc         = (_Float16*)take((size_t)BN * Dim * 2);   // 4 MB
  _Float16* vc         = (_Float16*)take((size_t)BN * Dim * 2);   // 4 MB
  _Float16* qpre       = (_Float16*)take((size_t)BN * Di * 2);    // 2 MB
  _Float16* kpre       = (_Float16*)take((size_t)BN * Di * 2);    // 2 MB
  _Float16* vpre       = (_Float16*)take((size_t)BN * Di * 2);    // 2 MB
  float* lrA           = (float*)take((size_t)NSEQ * Seq * 4);
  float* decayA        = (float*)take((size_t)NSEQ * Seq * 4);
  float* momA          = (float*)take((size_t)NSEQ * Seq * 4);
  float* Mc            = (float*)take((size_t)NSEQ * CHUNK * 4);
  float* Dc            = (float*)take((size_t)NSEQ * CHUNK * 4);
  float* Wc            = (float*)take((size_t)NSEQ * CHUNK * 4);
  _Float16* wqT        = (_Float16*)take((size_t)Di * Dim * 2);   // 1 MB
  _Float16* wkT        = (_Float16*)take((size_t)Di * Dim * 2);   // 1 MB
  _Float16* wvT        = (_Float16*)take((size_t)Di * Dim * 2);   // 1 MB
  _Float16* woT        = (_Float16*)take((size_t)Dim * Di * 2);   // 1 MB
  float* gqf           = (float*)take(Di * 4);
  float* gkf           = (float*)take(Di * 4);
  // Aliases: qc/kc/vc are dead after the QKV GEMM
  _Float16* ZS_Z       = qc;   // 4 MB needed, 4 MB available
  _Float16* ZS_S       = kc;   // 4 MB
  _Float16* yb         = vc;   // 2 MB

  k_sniff<<<17, 64, 0, stream>>>(ip, flags);
  k_prep_w<<<dim3(16, 16, 4), 256, 0, stream>>>(d_in[2], d_in[3], d_in[4], d_in[5],
                                                flags, wqT, wkT, wvT, woT);
  k_prep_gamma<<<1, 256, 0, stream>>>(d_in[9], d_in[10], flags, gqf, gkf);

  k_rms_gates<<<BN, 256, 0, stream>>>(d_in[0], d_in[1], d_in[11], d_in[13], d_in[15],
                                      d_in[12], d_in[14], d_in[16], flags,
                                      xaf, lrA, decayA, momA);
  k_conv<<<BN, 256, 0, stream>>>(xaf, d_in[6], d_in[7], d_in[8], flags, qc, kc, vc);

  dim3 g1(Di / 64, BN / 64, 3);
  k_gemm_bt<<<g1, 256, 0, stream>>>(qc, kc, vc, wqT, wkT, wvT,
                                    qpre, kpre, vpre, flags, Di, Dim, 0);

  k_phaseA<<<dim3(CHUNK, NSEQ), 256, 0, stream>>>(kpre, vpre, gkf,
                                                  lrA, decayA, momA,
                                                  ZS_Z, ZS_S, Mc, Dc, Wc);
  k_phaseB<<<dim3(NSEQ, 16), 256, 0, stream>>>(ZS_Z, ZS_S, Mc, Dc, Wc);
  k_phaseC<<<dim3(CHUNK, NSEQ), 256, 0, stream>>>(qpre, kpre, vpre, gqf, gkf,
                                                  lrA, decayA, momA,
                                                  ZS_Z, ZS_S, yb);

  dim3 g2(Dim / 64, BN / 64, 1);
  k_gemm_bt<<<g2, 256, 0, stream>>>(yb, yb, yb, woT, woT, woT,
                                    d_out, d_out, d_out, flags, Dim, Di, 1);
}

// Round 8
// 251.072 us; speedup vs baseline: 1.7936x; 1.2420x over previous
//
#include <hip/hip_runtime.h>
#include <math.h>

#define DEV __device__ __forceinline__

constexpr int Bb   = 2;
constexpr int Seq  = 1024;
constexpr int Dim  = 1024;
constexpr int Hh   = 8;
constexpr int Dh   = 64;
constexpr int Di   = 512;
constexpr int BN   = Bb * Seq;       // 2048
constexpr int NSEQ = Bb * Hh;        // 16
constexpr int CHUNK = 32;            // chunks per sequence
constexpr int CLEN  = Seq / CHUNK;   // 32
constexpr float EPSV = 1.1920929e-07f;

typedef _Float16 half8 __attribute__((ext_vector_type(8)));
typedef float    f32x4 __attribute__((ext_vector_type(4)));

DEV float bf2f(unsigned short u) {
  union { unsigned int i; float f; } x; x.i = ((unsigned int)u) << 16; return x.f;
}
DEV unsigned short f2bf(float f) {
  union { float f; unsigned int i; } x; x.f = f;
  unsigned int r = x.i + 0x7fffu + ((x.i >> 16) & 1u);
  return (unsigned short)(r >> 16);
}
// flag: 1 -> fp32, 0 -> bf16
DEV float ldin(const void* p, int f32, size_t i) {
  if (f32) return ((const float*)p)[i];
  return bf2f(((const unsigned short*)p)[i]);
}

struct InPtrs { const void* p[17]; int n[17]; };

// ---------------------------------------------------------------------------
// K0: dtype sniffer (proven round 6). flags[b]: 1 = fp32, 0 = bf16.
// ---------------------------------------------------------------------------
__global__ __launch_bounds__(64) void k_sniff(InPtrs ip, int* __restrict__ flags) {
  int b = blockIdx.x, tid = threadIdx.x;
  const unsigned short* u = (const unsigned short*)ip.p[b];
  int count = ip.n[b];
  int j = 2 * tid;
  int valid = 0, bad = 0;
  if (j < count) {
    valid = 1;
    float v = bf2f(u[j]);
    float a = fabsf(v);
    if (!(a >= 1e-12f && a <= 1e4f)) bad = 1;
  }
#pragma unroll
  for (int m = 1; m < 64; m <<= 1) { valid += __shfl_xor(valid, m); bad += __shfl_xor(bad, m); }
  if (tid == 0) flags[b] = (2 * bad > valid) ? 1 : 0;
}

// ---------------------------------------------------------------------------
// K0b: weight prep — convert + transpose wq/wk/wv (1024x512) and wo (512x1024)
// into f16 [N][K] layout.
// ---------------------------------------------------------------------------
__global__ __launch_bounds__(256) void k_prep_w(
    const void* __restrict__ wq, const void* __restrict__ wk,
    const void* __restrict__ wv, const void* __restrict__ wo,
    const int* __restrict__ flags,
    _Float16* __restrict__ wqT, _Float16* __restrict__ wkT,
    _Float16* __restrict__ wvT, _Float16* __restrict__ woT)
{
  int z = blockIdx.z;
  const void* src = (z == 0) ? wq : ((z == 1) ? wk : ((z == 2) ? wv : wo));
  _Float16* dst   = (z == 0) ? wqT : ((z == 1) ? wkT : ((z == 2) ? wvT : woT));
  int f = flags[(z == 0) ? 2 : ((z == 1) ? 3 : ((z == 2) ? 4 : 5))];
  int Kd = (z < 3) ? Dim : Di;   // rows of src
  int Nn = (z < 3) ? Di : Dim;   // cols of src
  int n0 = blockIdx.x * 64, k0 = blockIdx.y * 64;
  if (n0 >= Nn || k0 >= Kd) return;

  __shared__ float tile[64][65];
  int tid = threadIdx.x;
  int r = tid >> 4, c4 = (tid & 15) * 4;
#pragma unroll
  for (int rr = 0; rr < 4; ++rr) {
    int k = rr * 16 + r;
#pragma unroll
    for (int j = 0; j < 4; ++j)
      tile[k][c4 + j] = ldin(src, f, (size_t)(k0 + k) * Nn + n0 + c4 + j);
  }
  __syncthreads();
#pragma unroll
  for (int rr = 0; rr < 4; ++rr) {
    int n = rr * 16 + r;
    _Float16 o4[4];
#pragma unroll
    for (int j = 0; j < 4; ++j) o4[j] = (_Float16)tile[c4 + j][n];
    *(ushort4*)&dst[(size_t)(n0 + n) * Kd + k0 + c4] = *(ushort4*)o4;
  }
}

// K0c: decode gamma_q/gamma_k to f32, gate biases to f32[24]
__global__ __launch_bounds__(256) void k_prep_gamma(
    const void* __restrict__ gq, const void* __restrict__ gk,
    const void* __restrict__ lr_b, const void* __restrict__ decay_b,
    const void* __restrict__ mom_b,
    const int* __restrict__ flags,
    float* __restrict__ gqf, float* __restrict__ gkf, float* __restrict__ gbf)
{
  int tid = threadIdx.x;
  int f9 = flags[9], f10 = flags[10];
  for (int i = tid; i < Di; i += 256) {
    gqf[i] = ldin(gq, f9, i);
    gkf[i] = ldin(gk, f10, i);
  }
  if (tid < 24) {
    int g = tid >> 3, h = tid & 7;
    const void* Bp = (g == 0) ? lr_b : ((g == 1) ? decay_b : mom_b);
    int fB = (g == 0) ? flags[12] : ((g == 1) ? flags[14] : flags[16]);
    gbf[tid] = ldin(Bp, fB, h);
  }
}

// K0d: pack gate weights transposed f16 WgT[64][1024]; rows 0-7=lr_w heads,
// 8-15=decay_w, 16-23=mom_w, 24-63=0.
__global__ __launch_bounds__(256) void k_prep_gates(
    const void* __restrict__ lr_w, const void* __restrict__ decay_w,
    const void* __restrict__ mom_w, const int* __restrict__ flags,
    _Float16* __restrict__ WgT)
{
  int row = blockIdx.x;           // 0..63
  int tid = threadIdx.x;
  if (row < 24) {
    int g = row >> 3, h = row & 7;
    const void* W = (g == 0) ? lr_w : ((g == 1) ? decay_w : mom_w);
    int f = (g == 0) ? flags[11] : ((g == 1) ? flags[13] : flags[15]);
#pragma unroll
    for (int it = 0; it < 4; ++it) {
      int d = it * 256 + tid;
      WgT[(size_t)row * Dim + d] = (_Float16)ldin(W, f, (size_t)d * Hh + h);
    }
  } else {
#pragma unroll
    for (int it = 0; it < 4; ++it)
      WgT[(size_t)row * Dim + it * 256 + tid] = (_Float16)0.f;
  }
}

// ---------------------------------------------------------------------------
// K1: pure RMSNorm(x) -> xaf (f16). One block per row.
// ---------------------------------------------------------------------------
__global__ __launch_bounds__(256) void k_rms(
    const void* __restrict__ x, const void* __restrict__ w_rms,
    const int* __restrict__ flags, _Float16* __restrict__ xaf)
{
  __shared__ float red[4];
  int r = blockIdx.x;
  int tid = threadIdx.x, lane = tid & 63, wid = tid >> 6;
  int fx = flags[0], fw = flags[1];

  size_t rb = (size_t)r * Dim + tid * 4;
  float v0, v1, v2, v3;
  if (fx) {
    float4 u = *(const float4*)((const float*)x + rb);
    v0 = u.x; v1 = u.y; v2 = u.z; v3 = u.w;
  } else {
    ushort4 u = *(const ushort4*)((const unsigned short*)x + rb);
    v0 = bf2f(u.x); v1 = bf2f(u.y); v2 = bf2f(u.z); v3 = bf2f(u.w);
  }
  float ss = v0 * v0 + v1 * v1 + v2 * v2 + v3 * v3;
#pragma unroll
  for (int m = 1; m < 64; m <<= 1) ss += __shfl_xor(ss, m);
  if (lane == 0) red[wid] = ss;
  __syncthreads();
  float scale = rsqrtf((red[0] + red[1] + red[2] + red[3]) * (1.0f / Dim) + EPSV);

  float w0, w1, w2, w3;
  if (fw) {
    float4 u = *(const float4*)((const float*)w_rms + tid * 4);
    w0 = u.x; w1 = u.y; w2 = u.z; w3 = u.w;
  } else {
    ushort4 u = *(const ushort4*)((const unsigned short*)w_rms + tid * 4);
    w0 = bf2f(u.x); w1 = bf2f(u.y); w2 = bf2f(u.z); w3 = bf2f(u.w);
  }
  _Float16 t4[4] = {(_Float16)(v0 * scale * w0), (_Float16)(v1 * scale * w1),
                    (_Float16)(v2 * scale * w2), (_Float16)(v3 * scale * w3)};
  *(ushort4*)&xaf[rb] = *(ushort4*)t4;
}

// ---------------------------------------------------------------------------
// K1b: gate GEMM. xaf[BN][1024] @ WgT[64][1024]^T -> sigmoid -> lr/decay/mom.
// One 64-row tile per block, 32 blocks.
// ---------------------------------------------------------------------------
__global__ __launch_bounds__(256) void k_gates(
    const _Float16* __restrict__ xaf, const _Float16* __restrict__ WgT,
    const float* __restrict__ gbf,
    float* __restrict__ lr, float* __restrict__ decay, float* __restrict__ mom)
{
  __shared__ __align__(16) _Float16 As[64][40];
  __shared__ __align__(16) _Float16 Bs[64][40];

  int tid = threadIdx.x, lane = tid & 63, wvid = tid >> 6;
  int m0 = blockIdx.x * 64;
  int srow = tid >> 2, scol = (tid & 3) * 8;
  int mrow = lane & 15, quad = lane >> 4;

  f32x4 acc[4];
#pragma unroll
  for (int mi = 0; mi < 4; ++mi) acc[mi] = (f32x4){0.f, 0.f, 0.f, 0.f};

  for (int kt = 0; kt < Dim; kt += 32) {
    __syncthreads();
    *(uint4*)&As[srow][scol] = *(const uint4*)&xaf[(size_t)(m0 + srow) * Dim + kt + scol];
    *(uint4*)&Bs[srow][scol] = *(const uint4*)&WgT[(size_t)srow * Dim + kt + scol];
    __syncthreads();
    half8 bfr = *(const half8*)&Bs[wvid * 16 + mrow][quad * 8];
#pragma unroll
    for (int mi = 0; mi < 4; ++mi) {
      half8 afr = *(const half8*)&As[mi * 16 + mrow][quad * 8];
      acc[mi] = __builtin_amdgcn_mfma_f32_16x16x32_f16(afr, bfr, acc[mi], 0, 0, 0);
    }
  }

  int col = wvid * 16 + mrow;          // 0..63; only 0..23 are real gates
  if (col < 24) {
    int g = col >> 3, h = col & 7;
    float bias = gbf[col];
    float* Op = (g == 0) ? lr : ((g == 1) ? decay : mom);
#pragma unroll
    for (int mi = 0; mi < 4; ++mi) {
#pragma unroll
      for (int r2 = 0; r2 < 4; ++r2) {
        int row = m0 + mi * 16 + quad * 4 + r2;
        int b = row >> 10, t = row & (Seq - 1);
        float z = acc[mi][r2] + bias;
        Op[(b * Hh + h) * Seq + t] = 1.f / (1.f + expf(-z));
      }
    }
  }
}

// ---------------------------------------------------------------------------
// K2: depthwise conv (unchanged)
// ---------------------------------------------------------------------------
__global__ __launch_bounds__(256) void k_conv(
    const _Float16* __restrict__ xaf,
    const void* __restrict__ cq, const void* __restrict__ ck,
    const void* __restrict__ cv, const int* __restrict__ flags,
    _Float16* __restrict__ qc, _Float16* __restrict__ kc,
    _Float16* __restrict__ vc)
{
  int r = blockIdx.x, b = r >> 10, t = r & (Seq - 1);
  int c0 = threadIdx.x * 4;
  int f6 = flags[6], f7 = flags[7], f8 = flags[8];

  float lwq[16], lwk[16], lwv[16];
#pragma unroll
  for (int e = 0; e < 16; ++e) {
    lwq[e] = ldin(cq, f6, (size_t)c0 * 4 + e);
    lwk[e] = ldin(ck, f7, (size_t)c0 * 4 + e);
    lwv[e] = ldin(cv, f8, (size_t)c0 * 4 + e);
  }

  float aq[4] = {0.f, 0.f, 0.f, 0.f};
  float ak[4] = {0.f, 0.f, 0.f, 0.f};
  float av[4] = {0.f, 0.f, 0.f, 0.f};
#pragma unroll
  for (int kk = 0; kk < 4; ++kk) {
    int ts = t - 2 + kk;
    float xv[4] = {0.f, 0.f, 0.f, 0.f};
    if (ts >= 0 && ts < Seq) {
      ushort4 u = *(const ushort4*)&xaf[((size_t)(b * Seq + ts)) * Dim + c0];
      _Float16 hx[4]; *(ushort4*)hx = u;
      xv[0] = (float)hx[0]; xv[1] = (float)hx[1];
      xv[2] = (float)hx[2]; xv[3] = (float)hx[3];
    }
#pragma unroll
    for (int j = 0; j < 4; ++j) {
      aq[j] = fmaf(xv[j], lwq[j * 4 + kk], aq[j]);
      ak[j] = fmaf(xv[j], lwk[j * 4 + kk], ak[j]);
      av[j] = fmaf(xv[j], lwv[j * 4 + kk], av[j]);
    }
  }
  _Float16 tq[4], tk[4], tv[4];
#pragma unroll
  for (int j = 0; j < 4; ++j) {
    tq[j] = (_Float16)aq[j]; tk[j] = (_Float16)ak[j]; tv[j] = (_Float16)av[j];
  }
  *(ushort4*)&qc[(size_t)r * Dim + c0] = *(ushort4*)tq;
  *(ushort4*)&kc[(size_t)r * Dim + c0] = *(ushort4*)tk;
  *(ushort4*)&vc[(size_t)r * Dim + c0] = *(ushort4*)tv;
}

// ---------------------------------------------------------------------------
// K3: MFMA GEMM with pre-transposed f16 B [N][K]. 64x64 tile, BK=32.
// ---------------------------------------------------------------------------
__global__ __launch_bounds__(256) void k_gemm_bt(
    const _Float16* __restrict__ A0, const _Float16* __restrict__ A1,
    const _Float16* __restrict__ A2,
    const _Float16* __restrict__ B0, const _Float16* __restrict__ B1,
    const _Float16* __restrict__ B2,
    void* __restrict__ C0, void* __restrict__ C1, void* __restrict__ C2,
    const int* __restrict__ flags,
    int Nn, int Kd, int is_final)
{
  int z = blockIdx.z;
  const _Float16* A  = (z == 0) ? A0 : ((z == 1) ? A1 : A2);
  const _Float16* Bt = (z == 0) ? B0 : ((z == 1) ? B1 : B2);
  void* C = (z == 0) ? C0 : ((z == 1) ? C1 : C2);

  __shared__ __align__(16) _Float16 As[64][40];
  __shared__ __align__(16) _Float16 Bs[64][40];

  int tid = threadIdx.x, lane = tid & 63, wvid = tid >> 6;
  int n0 = blockIdx.x * 64, m0 = blockIdx.y * 64;
  int srow = tid >> 2, scol = (tid & 3) * 8;
  int mrow = lane & 15, quad = lane >> 4;

  f32x4 acc[4];
#pragma unroll
  for (int mi = 0; mi < 4; ++mi) acc[mi] = (f32x4){0.f, 0.f, 0.f, 0.f};

  for (int kt = 0; kt < Kd; kt += 32) {
    __syncthreads();
    *(uint4*)&As[srow][scol] = *(const uint4*)&A[(size_t)(m0 + srow) * Kd + kt + scol];
    *(uint4*)&Bs[srow][scol] = *(const uint4*)&Bt[(size_t)(n0 + srow) * Kd + kt + scol];
    __syncthreads();
    half8 bfr = *(const half8*)&Bs[wvid * 16 + mrow][quad * 8];
#pragma unroll
    for (int mi = 0; mi < 4; ++mi) {
      half8 afr = *(const half8*)&As[mi * 16 + mrow][quad * 8];
      acc[mi] = __builtin_amdgcn_mfma_f32_16x16x32_f16(afr, bfr, acc[mi], 0, 0, 0);
    }
  }

  int any_bf16 = 0;
  if (is_final) {
#pragma unroll
    for (int i2 = 0; i2 < 17; ++i2) any_bf16 |= (flags[i2] == 0);
  }

  int col = n0 + wvid * 16 + mrow;
#pragma unroll
  for (int mi = 0; mi < 4; ++mi) {
#pragma unroll
    for (int r2 = 0; r2 < 4; ++r2) {
      int row = m0 + mi * 16 + quad * 4 + r2;
      float v = acc[mi][r2];
      size_t idx = (size_t)row * Nn + col;
      if (!is_final)        ((_Float16*)C)[idx] = (_Float16)v;
      else if (any_bf16)    ((unsigned short*)C)[idx] = f2bf(v);
      else                  ((float*)C)[idx] = v;
    }
  }
}

// ---------------------------------------------------------------------------
// Recurrence phases (unchanged from round 7).
// ---------------------------------------------------------------------------
__global__ __launch_bounds__(256) void k_phaseA(
    const _Float16* __restrict__ kpre, const _Float16* __restrict__ vpre,
    const float* __restrict__ gkf,
    const float* __restrict__ lr, const float* __restrict__ decay,
    const float* __restrict__ mom,
    _Float16* __restrict__ ZS_Z, _Float16* __restrict__ ZS_S,
    float* __restrict__ Mc, float* __restrict__ Dc, float* __restrict__ Wc)
{
  int c = blockIdx.x, s = blockIdx.y;
  int b = s >> 3, h = s & 7;
  int tid = threadIdx.x, lane = tid & 63, wv = tid >> 6;
  int i = tid >> 2, j0 = (tid & 3) * 16;
  __shared__ float kn[CLEN][64], vv[CLEN][64];
  __shared__ float gl[CLEN], gd[CLEN], gm[CLEN];

  {
    int t = tid >> 3, col = (tid & 7) * 8;
    size_t g = ((size_t)(b * Seq + c * CLEN + t)) * Di + h * 64 + col;
    half8 kv = *(const half8*)&kpre[g];
    half8 vvv = *(const half8*)&vpre[g];
#pragma unroll
    for (int j = 0; j < 8; ++j) { kn[t][col + j] = (float)kv[j]; vv[t][col + j] = (float)vvv[j]; }
    if (tid < 96) {
      int which = tid >> 5, t2 = tid & 31;
      const float* gp = (which == 0) ? lr : ((which == 1) ? decay : mom);
      float val = gp[s * Seq + c * CLEN + t2];
      if (which == 0) gl[t2] = val; else if (which == 1) gd[t2] = val; else gm[t2] = val;
    }
  }
  __syncthreads();
  {
    float gk = gkf[h * 64 + lane];
#pragma unroll
    for (int tt = 0; tt < 8; ++tt) {
      int t = wv * 8 + tt;
      float kvv = kn[t][lane];
      float ss = kvv * kvv;
#pragma unroll
      for (int m = 1; m < 64; m <<= 1) ss += __shfl_xor(ss, m);
      kn[t][lane] = kvv * (1.f / fmaxf(sqrtf(ss) * 0.125f, 1e-8f)) * gk;
    }
  }
  __syncthreads();

  float Zl[16], Sl[16];
#pragma unroll
  for (int jj = 0; jj < 16; ++jj) { Zl[jj] = 0.f; Sl[jj] = 0.f; }
  float Mcum = 1.f, Dcum = 1.f, wacc = 0.f;

  for (int t = 0; t < CLEN; ++t) {
    float l = gl[t], dd = gd[t], mm = gm[t];
    float vi = vv[t][i];
    Mcum *= mm;
#pragma unroll
    for (int jj = 0; jj < 16; ++jj) {
      Zl[jj] = fmaf(mm, Zl[jj], -vi * kn[t][j0 + jj]);
      Sl[jj] = fmaf(dd, Sl[jj], -l * Zl[jj]);
    }
    wacc = fmaf(dd, wacc, -l * Mcum);
    Dcum *= dd;
  }
  size_t base = ((size_t)(s * CHUNK + c)) * 4096 + (size_t)i * 64 + j0;
  half8 zo0, zo1, so0, so1;
#pragma unroll
  for (int jj = 0; jj < 8; ++jj) {
    zo0[jj] = (_Float16)Zl[jj];     zo1[jj] = (_Float16)Zl[jj + 8];
    so0[jj] = (_Float16)Sl[jj];     so1[jj] = (_Float16)Sl[jj + 8];
  }
  *(half8*)&ZS_Z[base] = zo0; *(half8*)&ZS_Z[base + 8] = zo1;
  *(half8*)&ZS_S[base] = so0; *(half8*)&ZS_S[base + 8] = so1;
  if (tid == 0) {
    Mc[s * CHUNK + c] = Mcum; Dc[s * CHUNK + c] = Dcum; Wc[s * CHUNK + c] = wacc;
  }
}

__global__ __launch_bounds__(256) void k_phaseB(
    _Float16* __restrict__ ZS_Z, _Float16* __restrict__ ZS_S,
    const float* __restrict__ Mc, const float* __restrict__ Dc,
    const float* __restrict__ Wc)
{
  int s = blockIdx.x;
  int e = blockIdx.y * 256 + threadIdx.x;
  float Z = 0.f, S = 0.f;
  for (int c = 0; c < CHUNK; ++c) {
    size_t base = ((size_t)(s * CHUNK + c)) * 4096 + e;
    float mc = Mc[s * CHUNK + c], dc = Dc[s * CHUNK + c], wc = Wc[s * CHUNK + c];
    float zl = (float)ZS_Z[base], sl = (float)ZS_S[base];
    ZS_Z[base] = (_Float16)Z; ZS_S[base] = (_Float16)S;   // chunk inputs
    S = fmaf(dc, S, fmaf(wc, Z, sl));  // uses OLD Z (= chunk input)
    Z = fmaf(mc, Z, zl);
  }
}

__global__ __launch_bounds__(256) void k_phaseC(
    const _Float16* __restrict__ qpre, const _Float16* __restrict__ kpre,
    const _Float16* __restrict__ vpre,
    const float* __restrict__ gqf, const float* __restrict__ gkf,
    const float* __restrict__ lr, const float* __restrict__ decay,
    const float* __restrict__ mom,
    const _Float16* __restrict__ ZS_Z, const _Float16* __restrict__ ZS_S,
    _Float16* __restrict__ yb)
{
  int c = blockIdx.x, s = blockIdx.y;
  int b = s >> 3, h = s & 7;
  int tid = threadIdx.x, lane = tid & 63, wv = tid >> 6;
  int i = tid >> 2, j0 = (tid & 3) * 16;
  __shared__ float kn[CLEN][64], vv[CLEN][64], qn[CLEN][64];
  __shared__ float gl[CLEN], gd[CLEN], gm[CLEN];

  float Zi_[16], Si_[16], Zl[16], Sl[16];
  size_t base = ((size_t)(s * CHUNK + c)) * 4096 + (size_t)i * 64 + j0;
  {
    half8 z0 = *(const half8*)&ZS_Z[base], z1 = *(const half8*)&ZS_Z[base + 8];
    half8 s0 = *(const half8*)&ZS_S[base], s1 = *(const half8*)&ZS_S[base + 8];
#pragma unroll
    for (int jj = 0; jj < 8; ++jj) {
      Zi_[jj] = (float)z0[jj]; Zi_[jj + 8] = (float)z1[jj];
      Si_[jj] = (float)s0[jj]; Si_[jj + 8] = (float)s1[jj];
      Zl[jj] = 0.f; Zl[jj + 8] = 0.f; Sl[jj] = 0.f; Sl[jj + 8] = 0.f;
    }
  }
  {
    int t = tid >> 3, col = (tid & 7) * 8;
    size_t g = ((size_t)(b * Seq + c * CLEN + t)) * Di + h * 64 + col;
    half8 kv = *(const half8*)&kpre[g];
    half8 vvv = *(const half8*)&vpre[g];
    half8 qv = *(const half8*)&qpre[g];
#pragma unroll
    for (int j = 0; j < 8; ++j) {
      kn[t][col + j] = (float)kv[j]; vv[t][col + j] = (float)vvv[j];
      qn[t][col + j] = (float)qv[j];
    }
    if (tid < 96) {
      int which = tid >> 5, t2 = tid & 31;
      const float* gp = (which == 0) ? lr : ((which == 1) ? decay : mom);
      float val = gp[s * Seq + c * CLEN + t2];
      if (which == 0) gl[t2] = val; else if (which == 1) gd[t2] = val; else gm[t2] = val;
    }
  }
  __syncthreads();
  {
    float gk = gkf[h * 64 + lane];
    float gq = gqf[h * 64 + lane];
#pragma unroll
    for (int tt = 0; tt < 8; ++tt) {
      int t = wv * 8 + tt;
      float kvv = kn[t][lane];
      float ssk = kvv * kvv;
      float qvv = qn[t][lane];
      float ssq = qvv * qvv;
#pragma unroll
      for (int m = 1; m < 64; m <<= 1) { ssk += __shfl_xor(ssk, m); ssq += __shfl_xor(ssq, m); }
      kn[t][lane] = kvv * (1.f / fmaxf(sqrtf(ssk) * 0.125f, 1e-8f)) * gk;
      qn[t][lane] = qvv * (1.f / fmaxf(sqrtf(ssq) * 0.125f, 1e-8f)) * gq;
    }
  }
  __syncthreads();

  float Mcum = 1.f, Dcum = 1.f, wacc = 0.f;
  float Dprev = 1.f, wprev = 0.f;

  for (int t = 0; t < CLEN; ++t) {
    float l = gl[t], dd = gd[t], mm = gm[t];

    float yp = 0.f;
#pragma unroll
    for (int jj = 0; jj < 16; ++jj) {
      float tmp = fmaf(Dprev, Si_[jj], fmaf(wprev, Zi_[jj], Sl[jj]));
      yp = fmaf(tmp, qn[t][j0 + jj], yp);
    }
    yp += __shfl_xor(yp, 1);
    yp += __shfl_xor(yp, 2);
    if ((tid & 3) == 0)
      yb[((size_t)(b * Seq + c * CLEN + t)) * Di + h * 64 + i] = (_Float16)yp;

    float vi = vv[t][i];
    Mcum *= mm;
#pragma unroll
    for (int jj = 0; jj < 16; ++jj) {
      Zl[jj] = fmaf(mm, Zl[jj], -vi * kn[t][j0 + jj]);
      Sl[jj] = fmaf(dd, Sl[jj], -l * Zl[jj]);
    }
    wacc = fmaf(dd, wacc, -l * Mcum);
    Dcum *= dd;
    Dprev = Dcum; wprev = wacc;
  }
}

// ---------------------------------------------------------------------------
extern "C" void kernel_launch(void* const* d_in, const int* in_sizes, int n_in,
                              void* d_out, int out_size, void* d_ws, size_t ws_size,
                              hipStream_t stream) {
  InPtrs ip;
  for (int i = 0; i < 17; ++i) { ip.p[i] = d_in[i]; ip.n[i] = in_sizes[i]; }

  char* p = (char*)d_ws;
  auto take = [&](size_t bytes) -> char* {
    char* q = p; p += (bytes + 255) & ~(size_t)255; return q;
  };
  int* flags           = (int*)take(32 * 4);
  _Float16* xaf        = (_Float16*)take((size_t)BN * Dim * 2);   // 4 MB
  _Float16* qc         = (_Float16*)take((size_t)BN * Dim * 2);   // 4 MB
  _Float16* kc         = (_Float16*)take((size_t)BN * Dim * 2);   // 4 MB
  _Float16* vc         = (_Float16*)take((size_t)BN * Dim * 2);   // 4 MB
  _Float16* qpre       = (_Float16*)take((size_t)BN * Di * 2);    // 2 MB
  _Float16* kpre       = (_Float16*)take((size_t)BN * Di * 2);    // 2 MB
  _Float16* vpre       = (_Float16*)take((size_t)BN * Di * 2);    // 2 MB
  float* lrA           = (float*)take((size_t)NSEQ * Seq * 4);
  float* decayA        = (float*)take((size_t)NSEQ * Seq * 4);
  float* momA          = (float*)take((size_t)NSEQ * Seq * 4);
  float* Mc            = (float*)take((size_t)NSEQ * CHUNK * 4);
  float* Dc            = (float*)take((size_t)NSEQ * CHUNK * 4);
  float* Wc            = (float*)take((size_t)NSEQ * CHUNK * 4);
  _Float16* wqT        = (_Float16*)take((size_t)Di * Dim * 2);   // 1 MB
  _Float16* wkT        = (_Float16*)take((size_t)Di * Dim * 2);   // 1 MB
  _Float16* wvT        = (_Float16*)take((size_t)Di * Dim * 2);   // 1 MB
  _Float16* woT        = (_Float16*)take((size_t)Dim * Di * 2);   // 1 MB
  _Float16* WgT        = (_Float16*)take((size_t)64 * Dim * 2);   // 128 KB
  float* gqf           = (float*)take(Di * 4);
  float* gkf           = (float*)take(Di * 4);
  float* gbf           = (float*)take(32 * 4);
  // Aliases: qc/kc/vc are dead after the QKV GEMM
  _Float16* ZS_Z       = qc;
  _Float16* ZS_S       = kc;
  _Float16* yb         = vc;

  k_sniff<<<17, 64, 0, stream>>>(ip, flags);
  k_prep_w<<<dim3(16, 16, 4), 256, 0, stream>>>(d_in[2], d_in[3], d_in[4], d_in[5],
                                                flags, wqT, wkT, wvT, woT);
  k_prep_gamma<<<1, 256, 0, stream>>>(d_in[9], d_in[10], d_in[12], d_in[14], d_in[16],
                                      flags, gqf, gkf, gbf);
  k_prep_gates<<<64, 256, 0, stream>>>(d_in[11], d_in[13], d_in[15], flags, WgT);

  k_rms<<<BN, 256, 0, stream>>>(d_in[0], d_in[1], flags, xaf);
  k_gates<<<BN / 64, 256, 0, stream>>>(xaf, WgT, gbf, lrA, decayA, momA);
  k_conv<<<BN, 256, 0, stream>>>(xaf, d_in[6], d_in[7], d_in[8], flags, qc, kc, vc);

  dim3 g1(Di / 64, BN / 64, 3);
  k_gemm_bt<<<g1, 256, 0, stream>>>(qc, kc, vc, wqT, wkT, wvT,
                                    qpre, kpre, vpre, flags, Di, Dim, 0);

  k_phaseA<<<dim3(CHUNK, NSEQ), 256, 0, stream>>>(kpre, vpre, gkf,
                                                  lrA, decayA, momA,
                                                  ZS_Z, ZS_S, Mc, Dc, Wc);
  k_phaseB<<<dim3(NSEQ, 16), 256, 0, stream>>>(ZS_Z, ZS_S, Mc, Dc, Wc);
  k_phaseC<<<dim3(CHUNK, NSEQ), 256, 0, stream>>>(qpre, kpre, vpre, gqf, gkf,
                                                  lrA, decayA, momA,
                                                  ZS_Z, ZS_S, yb);

  dim3 g2(Dim / 64, BN / 64, 1);
  k_gemm_bt<<<g2, 256, 0, stream>>>(yb, yb, yb, woT, woT, woT,
                                    d_out, d_out, d_out, flags, Dim, Di, 1);
}

// Round 9
// 211.235 us; speedup vs baseline: 2.1319x; 1.1886x over previous
//
#include <hip/hip_runtime.h>
#include <math.h>

#define DEV __device__ __forceinline__

constexpr int Bb   = 2;
constexpr int Seq  = 1024;
constexpr int Dim  = 1024;
constexpr int Hh   = 8;
constexpr int Dh   = 64;
constexpr int Di   = 512;
constexpr int BN   = Bb * Seq;       // 2048
constexpr int NSEQ = Bb * Hh;        // 16
constexpr int CHUNK = 32;            // chunks per sequence
constexpr int CLEN  = Seq / CHUNK;   // 32
constexpr float EPSV = 1.1920929e-07f;
constexpr int NT   = 16;             // conv timesteps per block

typedef _Float16 half8 __attribute__((ext_vector_type(8)));
typedef float    f32x4 __attribute__((ext_vector_type(4)));

DEV float bf2f(unsigned short u) {
  union { unsigned int i; float f; } x; x.i = ((unsigned int)u) << 16; return x.f;
}
DEV unsigned short f2bf(float f) {
  union { float f; unsigned int i; } x; x.f = f;
  unsigned int r = x.i + 0x7fffu + ((x.i >> 16) & 1u);
  return (unsigned short)(r >> 16);
}
// flag: 1 -> fp32, 0 -> bf16
DEV float ldin(const void* p, int f32, size_t i) {
  if (f32) return ((const float*)p)[i];
  return bf2f(((const unsigned short*)p)[i]);
}

struct InPtrs { const void* p[17]; int n[17]; };

// ---------------------------------------------------------------------------
// K0: dtype sniffer (proven round 6). flags[b]: 1 = fp32, 0 = bf16.
// ---------------------------------------------------------------------------
__global__ __launch_bounds__(64) void k_sniff(InPtrs ip, int* __restrict__ flags) {
  int b = blockIdx.x, tid = threadIdx.x;
  const unsigned short* u = (const unsigned short*)ip.p[b];
  int count = ip.n[b];
  int j = 2 * tid;
  int valid = 0, bad = 0;
  if (j < count) {
    valid = 1;
    float v = bf2f(u[j]);
    float a = fabsf(v);
    if (!(a >= 1e-12f && a <= 1e4f)) bad = 1;
  }
#pragma unroll
  for (int m = 1; m < 64; m <<= 1) { valid += __shfl_xor(valid, m); bad += __shfl_xor(bad, m); }
  if (tid == 0) flags[b] = (2 * bad > valid) ? 1 : 0;
}

// ---------------------------------------------------------------------------
// K0b: weight prep — convert + transpose wq/wk/wv (1024x512) and wo (512x1024)
// into f16 [N][K] layout.
// ---------------------------------------------------------------------------
__global__ __launch_bounds__(256) void k_prep_w(
    const void* __restrict__ wq, const void* __restrict__ wk,
    const void* __restrict__ wv, const void* __restrict__ wo,
    const int* __restrict__ flags,
    _Float16* __restrict__ wqT, _Float16* __restrict__ wkT,
    _Float16* __restrict__ wvT, _Float16* __restrict__ woT)
{
  int z = blockIdx.z;
  const void* src = (z == 0) ? wq : ((z == 1) ? wk : ((z == 2) ? wv : wo));
  _Float16* dst   = (z == 0) ? wqT : ((z == 1) ? wkT : ((z == 2) ? wvT : woT));
  int f = flags[(z == 0) ? 2 : ((z == 1) ? 3 : ((z == 2) ? 4 : 5))];
  int Kd = (z < 3) ? Dim : Di;   // rows of src
  int Nn = (z < 3) ? Di : Dim;   // cols of src
  int n0 = blockIdx.x * 64, k0 = blockIdx.y * 64;
  if (n0 >= Nn || k0 >= Kd) return;

  __shared__ float tile[64][65];
  int tid = threadIdx.x;
  int r = tid >> 4, c4 = (tid & 15) * 4;
#pragma unroll
  for (int rr = 0; rr < 4; ++rr) {
    int k = rr * 16 + r;
#pragma unroll
    for (int j = 0; j < 4; ++j)
      tile[k][c4 + j] = ldin(src, f, (size_t)(k0 + k) * Nn + n0 + c4 + j);
  }
  __syncthreads();
#pragma unroll
  for (int rr = 0; rr < 4; ++rr) {
    int n = rr * 16 + r;
    _Float16 o4[4];
#pragma unroll
    for (int j = 0; j < 4; ++j) o4[j] = (_Float16)tile[c4 + j][n];
    *(ushort4*)&dst[(size_t)(n0 + n) * Kd + k0 + c4] = *(ushort4*)o4;
  }
}

// K0c: decode gamma_q/gamma_k to f32, gate biases to f32[24]
__global__ __launch_bounds__(256) void k_prep_gamma(
    const void* __restrict__ gq, const void* __restrict__ gk,
    const void* __restrict__ lr_b, const void* __restrict__ decay_b,
    const void* __restrict__ mom_b,
    const int* __restrict__ flags,
    float* __restrict__ gqf, float* __restrict__ gkf, float* __restrict__ gbf)
{
  int tid = threadIdx.x;
  int f9 = flags[9], f10 = flags[10];
  for (int i = tid; i < Di; i += 256) {
    gqf[i] = ldin(gq, f9, i);
    gkf[i] = ldin(gk, f10, i);
  }
  if (tid < 24) {
    int g = tid >> 3, h = tid & 7;
    const void* Bp = (g == 0) ? lr_b : ((g == 1) ? decay_b : mom_b);
    int fB = (g == 0) ? flags[12] : ((g == 1) ? flags[14] : flags[16]);
    gbf[tid] = ldin(Bp, fB, h);
  }
}

// K0d: pack gate weights transposed f16 WgT[64][1024]
__global__ __launch_bounds__(256) void k_prep_gates(
    const void* __restrict__ lr_w, const void* __restrict__ decay_w,
    const void* __restrict__ mom_w, const int* __restrict__ flags,
    _Float16* __restrict__ WgT)
{
  int row = blockIdx.x;           // 0..63
  int tid = threadIdx.x;
  if (row < 24) {
    int g = row >> 3, h = row & 7;
    const void* W = (g == 0) ? lr_w : ((g == 1) ? decay_w : mom_w);
    int f = (g == 0) ? flags[11] : ((g == 1) ? flags[13] : flags[15]);
#pragma unroll
    for (int it = 0; it < 4; ++it) {
      int d = it * 256 + tid;
      WgT[(size_t)row * Dim + d] = (_Float16)ldin(W, f, (size_t)d * Hh + h);
    }
  } else {
#pragma unroll
    for (int it = 0; it < 4; ++it)
      WgT[(size_t)row * Dim + it * 256 + tid] = (_Float16)0.f;
  }
}

// K0e: pack conv weights f16 [Dim][4] per matrix (flag-decoded once)
__global__ __launch_bounds__(256) void k_prep_conv(
    const void* __restrict__ cq, const void* __restrict__ ck,
    const void* __restrict__ cv, const int* __restrict__ flags,
    _Float16* __restrict__ wcq, _Float16* __restrict__ wck,
    _Float16* __restrict__ wcv)
{
  int tid = blockIdx.x * 256 + threadIdx.x;   // 0..4095
  int f6 = flags[6], f7 = flags[7], f8 = flags[8];
  wcq[tid] = (_Float16)ldin(cq, f6, tid);
  wck[tid] = (_Float16)ldin(ck, f7, tid);
  wcv[tid] = (_Float16)ldin(cv, f8, tid);
}

// ---------------------------------------------------------------------------
// K1: pure RMSNorm(x) -> xaf (f16). One block per row.
// ---------------------------------------------------------------------------
__global__ __launch_bounds__(256) void k_rms(
    const void* __restrict__ x, const void* __restrict__ w_rms,
    const int* __restrict__ flags, _Float16* __restrict__ xaf)
{
  __shared__ float red[4];
  int r = blockIdx.x;
  int tid = threadIdx.x, lane = tid & 63, wid = tid >> 6;
  int fx = flags[0], fw = flags[1];

  size_t rb = (size_t)r * Dim + tid * 4;
  float v0, v1, v2, v3;
  if (fx) {
    float4 u = *(const float4*)((const float*)x + rb);
    v0 = u.x; v1 = u.y; v2 = u.z; v3 = u.w;
  } else {
    ushort4 u = *(const ushort4*)((const unsigned short*)x + rb);
    v0 = bf2f(u.x); v1 = bf2f(u.y); v2 = bf2f(u.z); v3 = bf2f(u.w);
  }
  float ss = v0 * v0 + v1 * v1 + v2 * v2 + v3 * v3;
#pragma unroll
  for (int m = 1; m < 64; m <<= 1) ss += __shfl_xor(ss, m);
  if (lane == 0) red[wid] = ss;
  __syncthreads();
  float scale = rsqrtf((red[0] + red[1] + red[2] + red[3]) * (1.0f / Dim) + EPSV);

  float w0, w1, w2, w3;
  if (fw) {
    float4 u = *(const float4*)((const float*)w_rms + tid * 4);
    w0 = u.x; w1 = u.y; w2 = u.z; w3 = u.w;
  } else {
    ushort4 u = *(const ushort4*)((const unsigned short*)w_rms + tid * 4);
    w0 = bf2f(u.x); w1 = bf2f(u.y); w2 = bf2f(u.z); w3 = bf2f(u.w);
  }
  _Float16 t4[4] = {(_Float16)(v0 * scale * w0), (_Float16)(v1 * scale * w1),
                    (_Float16)(v2 * scale * w2), (_Float16)(v3 * scale * w3)};
  *(ushort4*)&xaf[rb] = *(ushort4*)t4;
}

// ---------------------------------------------------------------------------
// K1b: gate GEMM. xaf[BN][1024] @ WgT[64][1024]^T -> sigmoid -> lr/decay/mom.
// ---------------------------------------------------------------------------
__global__ __launch_bounds__(256) void k_gates(
    const _Float16* __restrict__ xaf, const _Float16* __restrict__ WgT,
    const float* __restrict__ gbf,
    float* __restrict__ lr, float* __restrict__ decay, float* __restrict__ mom)
{
  __shared__ __align__(16) _Float16 As[64][40];
  __shared__ __align__(16) _Float16 Bs[64][40];

  int tid = threadIdx.x, lane = tid & 63, wvid = tid >> 6;
  int m0 = blockIdx.x * 64;
  int srow = tid >> 2, scol = (tid & 3) * 8;
  int mrow = lane & 15, quad = lane >> 4;

  f32x4 acc[4];
#pragma unroll
  for (int mi = 0; mi < 4; ++mi) acc[mi] = (f32x4){0.f, 0.f, 0.f, 0.f};

  for (int kt = 0; kt < Dim; kt += 32) {
    __syncthreads();
    *(uint4*)&As[srow][scol] = *(const uint4*)&xaf[(size_t)(m0 + srow) * Dim + kt + scol];
    *(uint4*)&Bs[srow][scol] = *(const uint4*)&WgT[(size_t)srow * Dim + kt + scol];
    __syncthreads();
    half8 bfr = *(const half8*)&Bs[wvid * 16 + mrow][quad * 8];
#pragma unroll
    for (int mi = 0; mi < 4; ++mi) {
      half8 afr = *(const half8*)&As[mi * 16 + mrow][quad * 8];
      acc[mi] = __builtin_amdgcn_mfma_f32_16x16x32_f16(afr, bfr, acc[mi], 0, 0, 0);
    }
  }

  int col = wvid * 16 + mrow;          // 0..63; only 0..23 are real gates
  if (col < 24) {
    int g = col >> 3, h = col & 7;
    float bias = gbf[col];
    float* Op = (g == 0) ? lr : ((g == 1) ? decay : mom);
#pragma unroll
    for (int mi = 0; mi < 4; ++mi) {
#pragma unroll
      for (int r2 = 0; r2 < 4; ++r2) {
        int row = m0 + mi * 16 + quad * 4 + r2;
        int b = row >> 10, t = row & (Seq - 1);
        float z = acc[mi][r2] + bias;
        Op[(b * Hh + h) * Seq + t] = 1.f / (1.f + expf(-z));
      }
    }
  }
}

// ---------------------------------------------------------------------------
// K2 v2: depthwise conv, time-tiled. Block = (t-tile tb, batch b); thread owns
// 4 channels, marches NT timesteps with a sliding 4-row window.
// out[t] = sum_k xa[t-2+k]*w[k], zero padded.
// ---------------------------------------------------------------------------
__global__ __launch_bounds__(256) void k_conv(
    const _Float16* __restrict__ xaf,
    const _Float16* __restrict__ wcq, const _Float16* __restrict__ wck,
    const _Float16* __restrict__ wcv,
    _Float16* __restrict__ qc, _Float16* __restrict__ kc,
    _Float16* __restrict__ vc)
{
  int tb = blockIdx.x, b = blockIdx.y;
  int t0 = tb * NT;
  int c0 = threadIdx.x * 4;

  // weights: [ch][tap] f16, 4 ch -> 16 f16 = 2 uint4 per matrix
  _Float16 lwq[16], lwk[16], lwv[16];
  *(uint4*)&lwq[0] = *(const uint4*)&wcq[c0 * 4];
  *(uint4*)&lwq[8] = *(const uint4*)&wcq[c0 * 4 + 8];
  *(uint4*)&lwk[0] = *(const uint4*)&wck[c0 * 4];
  *(uint4*)&lwk[8] = *(const uint4*)&wck[c0 * 4 + 8];
  *(uint4*)&lwv[0] = *(const uint4*)&wcv[c0 * 4];
  *(uint4*)&lwv[8] = *(const uint4*)&wcv[c0 * 4 + 8];

  // sliding window rows t-2, t-1, t, t+1 (as f32x4 per thread)
  float win[4][4];
  auto loadrow = [&](int ts, float dst[4]) {
    if (ts >= 0 && ts < Seq) {
      ushort4 u = *(const ushort4*)&xaf[((size_t)(b * Seq + ts)) * Dim + c0];
      _Float16 hx[4]; *(ushort4*)hx = u;
      dst[0] = (float)hx[0]; dst[1] = (float)hx[1];
      dst[2] = (float)hx[2]; dst[3] = (float)hx[3];
    } else {
      dst[0] = 0.f; dst[1] = 0.f; dst[2] = 0.f; dst[3] = 0.f;
    }
  };
  loadrow(t0 - 2, win[0]);
  loadrow(t0 - 1, win[1]);
  loadrow(t0,     win[2]);

#pragma unroll
  for (int tt = 0; tt < NT; ++tt) {
    int t = t0 + tt;
    loadrow(t + 1, win[(tt + 3) & 3]);
    const float* r0 = win[(tt + 0) & 3];   // t-2
    const float* r1 = win[(tt + 1) & 3];   // t-1
    const float* r2 = win[(tt + 2) & 3];   // t
    const float* r3 = win[(tt + 3) & 3];   // t+1

    _Float16 tq[4], tk[4], tv[4];
#pragma unroll
    for (int j = 0; j < 4; ++j) {
      float aq = r0[j] * (float)lwq[j * 4 + 0] + r1[j] * (float)lwq[j * 4 + 1]
               + r2[j] * (float)lwq[j * 4 + 2] + r3[j] * (float)lwq[j * 4 + 3];
      float ak = r0[j] * (float)lwk[j * 4 + 0] + r1[j] * (float)lwk[j * 4 + 1]
               + r2[j] * (float)lwk[j * 4 + 2] + r3[j] * (float)lwk[j * 4 + 3];
      float av = r0[j] * (float)lwv[j * 4 + 0] + r1[j] * (float)lwv[j * 4 + 1]
               + r2[j] * (float)lwv[j * 4 + 2] + r3[j] * (float)lwv[j * 4 + 3];
      tq[j] = (_Float16)aq; tk[j] = (_Float16)ak; tv[j] = (_Float16)av;
    }
    size_t o = ((size_t)(b * Seq + t)) * Dim + c0;
    *(ushort4*)&qc[o] = *(ushort4*)tq;
    *(ushort4*)&kc[o] = *(ushort4*)tk;
    *(ushort4*)&vc[o] = *(ushort4*)tv;
  }
}

// ---------------------------------------------------------------------------
// K3: MFMA GEMM with pre-transposed f16 B [N][K]. 64x64 tile, BK=32.
// ---------------------------------------------------------------------------
__global__ __launch_bounds__(256) void k_gemm_bt(
    const _Float16* __restrict__ A0, const _Float16* __restrict__ A1,
    const _Float16* __restrict__ A2,
    const _Float16* __restrict__ B0, const _Float16* __restrict__ B1,
    const _Float16* __restrict__ B2,
    void* __restrict__ C0, void* __restrict__ C1, void* __restrict__ C2,
    const int* __restrict__ flags,
    int Nn, int Kd, int is_final)
{
  int z = blockIdx.z;
  const _Float16* A  = (z == 0) ? A0 : ((z == 1) ? A1 : A2);
  const _Float16* Bt = (z == 0) ? B0 : ((z == 1) ? B1 : B2);
  void* C = (z == 0) ? C0 : ((z == 1) ? C1 : C2);

  __shared__ __align__(16) _Float16 As[64][40];
  __shared__ __align__(16) _Float16 Bs[64][40];

  int tid = threadIdx.x, lane = tid & 63, wvid = tid >> 6;
  int n0 = blockIdx.x * 64, m0 = blockIdx.y * 64;
  int srow = tid >> 2, scol = (tid & 3) * 8;
  int mrow = lane & 15, quad = lane >> 4;

  f32x4 acc[4];
#pragma unroll
  for (int mi = 0; mi < 4; ++mi) acc[mi] = (f32x4){0.f, 0.f, 0.f, 0.f};

  for (int kt = 0; kt < Kd; kt += 32) {
    __syncthreads();
    *(uint4*)&As[srow][scol] = *(const uint4*)&A[(size_t)(m0 + srow) * Kd + kt + scol];
    *(uint4*)&Bs[srow][scol] = *(const uint4*)&Bt[(size_t)(n0 + srow) * Kd + kt + scol];
    __syncthreads();
    half8 bfr = *(const half8*)&Bs[wvid * 16 + mrow][quad * 8];
#pragma unroll
    for (int mi = 0; mi < 4; ++mi) {
      half8 afr = *(const half8*)&As[mi * 16 + mrow][quad * 8];
      acc[mi] = __builtin_amdgcn_mfma_f32_16x16x32_f16(afr, bfr, acc[mi], 0, 0, 0);
    }
  }

  int any_bf16 = 0;
  if (is_final) {
#pragma unroll
    for (int i2 = 0; i2 < 17; ++i2) any_bf16 |= (flags[i2] == 0);
  }

  int col = n0 + wvid * 16 + mrow;
#pragma unroll
  for (int mi = 0; mi < 4; ++mi) {
#pragma unroll
    for (int r2 = 0; r2 < 4; ++r2) {
      int row = m0 + mi * 16 + quad * 4 + r2;
      float v = acc[mi][r2];
      size_t idx = (size_t)row * Nn + col;
      if (!is_final)        ((_Float16*)C)[idx] = (_Float16)v;
      else if (any_bf16)    ((unsigned short*)C)[idx] = f2bf(v);
      else                  ((float*)C)[idx] = v;
    }
  }
}

// ---------------------------------------------------------------------------
// Recurrence phases (unchanged).
// ---------------------------------------------------------------------------
__global__ __launch_bounds__(256) void k_phaseA(
    const _Float16* __restrict__ kpre, const _Float16* __restrict__ vpre,
    const float* __restrict__ gkf,
    const float* __restrict__ lr, const float* __restrict__ decay,
    const float* __restrict__ mom,
    _Float16* __restrict__ ZS_Z, _Float16* __restrict__ ZS_S,
    float* __restrict__ Mc, float* __restrict__ Dc, float* __restrict__ Wc)
{
  int c = blockIdx.x, s = blockIdx.y;
  int b = s >> 3, h = s & 7;
  int tid = threadIdx.x, lane = tid & 63, wv = tid >> 6;
  int i = tid >> 2, j0 = (tid & 3) * 16;
  __shared__ float kn[CLEN][64], vv[CLEN][64];
  __shared__ float gl[CLEN], gd[CLEN], gm[CLEN];

  {
    int t = tid >> 3, col = (tid & 7) * 8;
    size_t g = ((size_t)(b * Seq + c * CLEN + t)) * Di + h * 64 + col;
    half8 kv = *(const half8*)&kpre[g];
    half8 vvv = *(const half8*)&vpre[g];
#pragma unroll
    for (int j = 0; j < 8; ++j) { kn[t][col + j] = (float)kv[j]; vv[t][col + j] = (float)vvv[j]; }
    if (tid < 96) {
      int which = tid >> 5, t2 = tid & 31;
      const float* gp = (which == 0) ? lr : ((which == 1) ? decay : mom);
      float val = gp[s * Seq + c * CLEN + t2];
      if (which == 0) gl[t2] = val; else if (which == 1) gd[t2] = val; else gm[t2] = val;
    }
  }
  __syncthreads();
  {
    float gk = gkf[h * 64 + lane];
#pragma unroll
    for (int tt = 0; tt < 8; ++tt) {
      int t = wv * 8 + tt;
      float kvv = kn[t][lane];
      float ss = kvv * kvv;
#pragma unroll
      for (int m = 1; m < 64; m <<= 1) ss += __shfl_xor(ss, m);
      kn[t][lane] = kvv * (1.f / fmaxf(sqrtf(ss) * 0.125f, 1e-8f)) * gk;
    }
  }
  __syncthreads();

  float Zl[16], Sl[16];
#pragma unroll
  for (int jj = 0; jj < 16; ++jj) { Zl[jj] = 0.f; Sl[jj] = 0.f; }
  float Mcum = 1.f, Dcum = 1.f, wacc = 0.f;

  for (int t = 0; t < CLEN; ++t) {
    float l = gl[t], dd = gd[t], mm = gm[t];
    float vi = vv[t][i];
    Mcum *= mm;
#pragma unroll
    for (int jj = 0; jj < 16; ++jj) {
      Zl[jj] = fmaf(mm, Zl[jj], -vi * kn[t][j0 + jj]);
      Sl[jj] = fmaf(dd, Sl[jj], -l * Zl[jj]);
    }
    wacc = fmaf(dd, wacc, -l * Mcum);
    Dcum *= dd;
  }
  size_t base = ((size_t)(s * CHUNK + c)) * 4096 + (size_t)i * 64 + j0;
  half8 zo0, zo1, so0, so1;
#pragma unroll
  for (int jj = 0; jj < 8; ++jj) {
    zo0[jj] = (_Float16)Zl[jj];     zo1[jj] = (_Float16)Zl[jj + 8];
    so0[jj] = (_Float16)Sl[jj];     so1[jj] = (_Float16)Sl[jj + 8];
  }
  *(half8*)&ZS_Z[base] = zo0; *(half8*)&ZS_Z[base + 8] = zo1;
  *(half8*)&ZS_S[base] = so0; *(half8*)&ZS_S[base + 8] = so1;
  if (tid == 0) {
    Mc[s * CHUNK + c] = Mcum; Dc[s * CHUNK + c] = Dcum; Wc[s * CHUNK + c] = wacc;
  }
}

__global__ __launch_bounds__(256) void k_phaseB(
    _Float16* __restrict__ ZS_Z, _Float16* __restrict__ ZS_S,
    const float* __restrict__ Mc, const float* __restrict__ Dc,
    const float* __restrict__ Wc)
{
  int s = blockIdx.x;
  int e = blockIdx.y * 256 + threadIdx.x;
  float Z = 0.f, S = 0.f;
  for (int c = 0; c < CHUNK; ++c) {
    size_t base = ((size_t)(s * CHUNK + c)) * 4096 + e;
    float mc = Mc[s * CHUNK + c], dc = Dc[s * CHUNK + c], wc = Wc[s * CHUNK + c];
    float zl = (float)ZS_Z[base], sl = (float)ZS_S[base];
    ZS_Z[base] = (_Float16)Z; ZS_S[base] = (_Float16)S;   // chunk inputs
    S = fmaf(dc, S, fmaf(wc, Z, sl));  // uses OLD Z (= chunk input)
    Z = fmaf(mc, Z, zl);
  }
}

__global__ __launch_bounds__(256) void k_phaseC(
    const _Float16* __restrict__ qpre, const _Float16* __restrict__ kpre,
    const _Float16* __restrict__ vpre,
    const float* __restrict__ gqf, const float* __restrict__ gkf,
    const float* __restrict__ lr, const float* __restrict__ decay,
    const float* __restrict__ mom,
    const _Float16* __restrict__ ZS_Z, const _Float16* __restrict__ ZS_S,
    _Float16* __restrict__ yb)
{
  int c = blockIdx.x, s = blockIdx.y;
  int b = s >> 3, h = s & 7;
  int tid = threadIdx.x, lane = tid & 63, wv = tid >> 6;
  int i = tid >> 2, j0 = (tid & 3) * 16;
  __shared__ float kn[CLEN][64], vv[CLEN][64], qn[CLEN][64];
  __shared__ float gl[CLEN], gd[CLEN], gm[CLEN];

  float Zi_[16], Si_[16], Zl[16], Sl[16];
  size_t base = ((size_t)(s * CHUNK + c)) * 4096 + (size_t)i * 64 + j0;
  {
    half8 z0 = *(const half8*)&ZS_Z[base], z1 = *(const half8*)&ZS_Z[base + 8];
    half8 s0 = *(const half8*)&ZS_S[base], s1 = *(const half8*)&ZS_S[base + 8];
#pragma unroll
    for (int jj = 0; jj < 8; ++jj) {
      Zi_[jj] = (float)z0[jj]; Zi_[jj + 8] = (float)z1[jj];
      Si_[jj] = (float)s0[jj]; Si_[jj + 8] = (float)s1[jj];
      Zl[jj] = 0.f; Zl[jj + 8] = 0.f; Sl[jj] = 0.f; Sl[jj + 8] = 0.f;
    }
  }
  {
    int t = tid >> 3, col = (tid & 7) * 8;
    size_t g = ((size_t)(b * Seq + c * CLEN + t)) * Di + h * 64 + col;
    half8 kv = *(const half8*)&kpre[g];
    half8 vvv = *(const half8*)&vpre[g];
    half8 qv = *(const half8*)&qpre[g];
#pragma unroll
    for (int j = 0; j < 8; ++j) {
      kn[t][col + j] = (float)kv[j]; vv[t][col + j] = (float)vvv[j];
      qn[t][col + j] = (float)qv[j];
    }
    if (tid < 96) {
      int which = tid >> 5, t2 = tid & 31;
      const float* gp = (which == 0) ? lr : ((which == 1) ? decay : mom);
      float val = gp[s * Seq + c * CLEN + t2];
      if (which == 0) gl[t2] = val; else if (which == 1) gd[t2] = val; else gm[t2] = val;
    }
  }
  __syncthreads();
  {
    float gk = gkf[h * 64 + lane];
    float gq = gqf[h * 64 + lane];
#pragma unroll
    for (int tt = 0; tt < 8; ++tt) {
      int t = wv * 8 + tt;
      float kvv = kn[t][lane];
      float ssk = kvv * kvv;
      float qvv = qn[t][lane];
      float ssq = qvv * qvv;
#pragma unroll
      for (int m = 1; m < 64; m <<= 1) { ssk += __shfl_xor(ssk, m); ssq += __shfl_xor(ssq, m); }
      kn[t][lane] = kvv * (1.f / fmaxf(sqrtf(ssk) * 0.125f, 1e-8f)) * gk;
      qn[t][lane] = qvv * (1.f / fmaxf(sqrtf(ssq) * 0.125f, 1e-8f)) * gq;
    }
  }
  __syncthreads();

  float Mcum = 1.f, Dcum = 1.f, wacc = 0.f;
  float Dprev = 1.f, wprev = 0.f;

  for (int t = 0; t < CLEN; ++t) {
    float l = gl[t], dd = gd[t], mm = gm[t];

    float yp = 0.f;
#pragma unroll
    for (int jj = 0; jj < 16; ++jj) {
      float tmp = fmaf(Dprev, Si_[jj], fmaf(wprev, Zi_[jj], Sl[jj]));
      yp = fmaf(tmp, qn[t][j0 + jj], yp);
    }
    yp += __shfl_xor(yp, 1);
    yp += __shfl_xor(yp, 2);
    if ((tid & 3) == 0)
      yb[((size_t)(b * Seq + c * CLEN + t)) * Di + h * 64 + i] = (_Float16)yp;

    float vi = vv[t][i];
    Mcum *= mm;
#pragma unroll
    for (int jj = 0; jj < 16; ++jj) {
      Zl[jj] = fmaf(mm, Zl[jj], -vi * kn[t][j0 + jj]);
      Sl[jj] = fmaf(dd, Sl[jj], -l * Zl[jj]);
    }
    wacc = fmaf(dd, wacc, -l * Mcum);
    Dcum *= dd;
    Dprev = Dcum; wprev = wacc;
  }
}

// ---------------------------------------------------------------------------
extern "C" void kernel_launch(void* const* d_in, const int* in_sizes, int n_in,
                              void* d_out, int out_size, void* d_ws, size_t ws_size,
                              hipStream_t stream) {
  InPtrs ip;
  for (int i = 0; i < 17; ++i) { ip.p[i] = d_in[i]; ip.n[i] = in_sizes[i]; }

  char* p = (char*)d_ws;
  auto take = [&](size_t bytes) -> char* {
    char* q = p; p += (bytes + 255) & ~(size_t)255; return q;
  };
  int* flags           = (int*)take(32 * 4);
  _Float16* xaf        = (_Float16*)take((size_t)BN * Dim * 2);   // 4 MB
  _Float16* qc         = (_Float16*)take((size_t)BN * Dim * 2);   // 4 MB
  _Float16* kc         = (_Float16*)take((size_t)BN * Dim * 2);   // 4 MB
  _Float16* vc         = (_Float16*)take((size_t)BN * Dim * 2);   // 4 MB
  _Float16* qpre       = (_Float16*)take((size_t)BN * Di * 2);    // 2 MB
  _Float16* kpre       = (_Float16*)take((size_t)BN * Di * 2);    // 2 MB
  _Float16* vpre       = (_Float16*)take((size_t)BN * Di * 2);    // 2 MB
  float* lrA           = (float*)take((size_t)NSEQ * Seq * 4);
  float* decayA        = (float*)take((size_t)NSEQ * Seq * 4);
  float* momA          = (float*)take((size_t)NSEQ * Seq * 4);
  float* Mc            = (float*)take((size_t)NSEQ * CHUNK * 4);
  float* Dc            = (float*)take((size_t)NSEQ * CHUNK * 4);
  float* Wc            = (float*)take((size_t)NSEQ * CHUNK * 4);
  _Float16* wqT        = (_Float16*)take((size_t)Di * Dim * 2);   // 1 MB
  _Float16* wkT        = (_Float16*)take((size_t)Di * Dim * 2);   // 1 MB
  _Float16* wvT        = (_Float16*)take((size_t)Di * Dim * 2);   // 1 MB
  _Float16* woT        = (_Float16*)take((size_t)Dim * Di * 2);   // 1 MB
  _Float16* WgT        = (_Float16*)take((size_t)64 * Dim * 2);   // 128 KB
  _Float16* wcq        = (_Float16*)take((size_t)Dim * 4 * 2);
  _Float16* wck        = (_Float16*)take((size_t)Dim * 4 * 2);
  _Float16* wcv        = (_Float16*)take((size_t)Dim * 4 * 2);
  float* gqf           = (float*)take(Di * 4);
  float* gkf           = (float*)take(Di * 4);
  float* gbf           = (float*)take(32 * 4);
  // Aliases: qc/kc/vc are dead after the QKV GEMM
  _Float16* ZS_Z       = qc;
  _Float16* ZS_S       = kc;
  _Float16* yb         = vc;

  k_sniff<<<17, 64, 0, stream>>>(ip, flags);
  k_prep_w<<<dim3(16, 16, 4), 256, 0, stream>>>(d_in[2], d_in[3], d_in[4], d_in[5],
                                                flags, wqT, wkT, wvT, woT);
  k_prep_gamma<<<1, 256, 0, stream>>>(d_in[9], d_in[10], d_in[12], d_in[14], d_in[16],
                                      flags, gqf, gkf, gbf);
  k_prep_gates<<<64, 256, 0, stream>>>(d_in[11], d_in[13], d_in[15], flags, WgT);
  k_prep_conv<<<16, 256, 0, stream>>>(d_in[6], d_in[7], d_in[8], flags, wcq, wck, wcv);

  k_rms<<<BN, 256, 0, stream>>>(d_in[0], d_in[1], flags, xaf);
  k_gates<<<BN / 64, 256, 0, stream>>>(xaf, WgT, gbf, lrA, decayA, momA);
  k_conv<<<dim3(Seq / NT, Bb), 256, 0, stream>>>(xaf, wcq, wck, wcv, qc, kc, vc);

  dim3 g1(Di / 64, BN / 64, 3);
  k_gemm_bt<<<g1, 256, 0, stream>>>(qc, kc, vc, wqT, wkT, wvT,
                                    qpre, kpre, vpre, flags, Di, Dim, 0);

  k_phaseA<<<dim3(CHUNK, NSEQ), 256, 0, stream>>>(kpre, vpre, gkf,
                                                  lrA, decayA, momA,
                                                  ZS_Z, ZS_S, Mc, Dc, Wc);
  k_phaseB<<<dim3(NSEQ, 16), 256, 0, stream>>>(ZS_Z, ZS_S, Mc, Dc, Wc);
  k_phaseC<<<dim3(CHUNK, NSEQ), 256, 0, stream>>>(qpre, kpre, vpre, gqf, gkf,
                                                  lrA, decayA, momA,
                                                  ZS_Z, ZS_S, yb);

  dim3 g2(Dim / 64, BN / 64, 1);
  k_gemm_bt<<<g2, 256, 0, stream>>>(yb, yb, yb, woT, woT, woT,
                                    d_out, d_out, d_out, flags, Dim, Di, 1);
}

// Round 10
// 208.439 us; speedup vs baseline: 2.1605x; 1.0134x over previous
//
#include <hip/hip_runtime.h>
#include <math.h>

#define DEV __device__ __forceinline__

constexpr int Bb   = 2;
constexpr int Seq  = 1024;
constexpr int Dim  = 1024;
constexpr int Hh   = 8;
constexpr int Dh   = 64;
constexpr int Di   = 512;
constexpr int BN   = Bb * Seq;       // 2048
constexpr int NSEQ = Bb * Hh;        // 16
constexpr int CHUNK = 32;            // chunks per sequence
constexpr int CLEN  = Seq / CHUNK;   // 32
constexpr float EPSV = 1.1920929e-07f;
constexpr int NT   = 16;             // conv timesteps per block

typedef _Float16 half8 __attribute__((ext_vector_type(8)));
typedef float    f32x4 __attribute__((ext_vector_type(4)));

DEV float bf2f(unsigned short u) {
  union { unsigned int i; float f; } x; x.i = ((unsigned int)u) << 16; return x.f;
}
DEV unsigned short f2bf(float f) {
  union { float f; unsigned int i; } x; x.f = f;
  unsigned int r = x.i + 0x7fffu + ((x.i >> 16) & 1u);
  return (unsigned short)(r >> 16);
}
// flag: 1 -> fp32, 0 -> bf16
DEV float ldin(const void* p, int f32, size_t i) {
  if (f32) return ((const float*)p)[i];
  return bf2f(((const unsigned short*)p)[i]);
}

struct InPtrs { const void* p[17]; int n[17]; };

// ---------------------------------------------------------------------------
// K0: dtype sniffer (proven). flags[b]: 1 = fp32, 0 = bf16.
// ---------------------------------------------------------------------------
__global__ __launch_bounds__(64) void k_sniff(InPtrs ip, int* __restrict__ flags) {
  int b = blockIdx.x, tid = threadIdx.x;
  const unsigned short* u = (const unsigned short*)ip.p[b];
  int count = ip.n[b];
  int j = 2 * tid;
  int valid = 0, bad = 0;
  if (j < count) {
    valid = 1;
    float v = bf2f(u[j]);
    float a = fabsf(v);
    if (!(a >= 1e-12f && a <= 1e4f)) bad = 1;
  }
#pragma unroll
  for (int m = 1; m < 64; m <<= 1) { valid += __shfl_xor(valid, m); bad += __shfl_xor(bad, m); }
  if (tid == 0) flags[b] = (2 * bad > valid) ? 1 : 0;
}

// ---------------------------------------------------------------------------
// K0b: ALL weight prep in one launch. Block roles:
//   [0,1024)    : transpose+convert wq/wk/wv/wo -> f16 [N][K]
//   [1024,1088) : gate weights -> WgT[64][1024]
//   [1088,1104) : conv weights -> f16 [Dim][4] x3
//   1104        : gammas + gate biases -> f32
// ---------------------------------------------------------------------------
__global__ __launch_bounds__(256) void k_prep_all(
    const void* __restrict__ wq, const void* __restrict__ wk,
    const void* __restrict__ wv, const void* __restrict__ wo,
    const void* __restrict__ lr_w, const void* __restrict__ decay_w,
    const void* __restrict__ mom_w,
    const void* __restrict__ cq, const void* __restrict__ ck,
    const void* __restrict__ cv,
    const void* __restrict__ gq, const void* __restrict__ gk,
    const void* __restrict__ lr_b, const void* __restrict__ decay_b,
    const void* __restrict__ mom_b,
    const int* __restrict__ flags,
    _Float16* __restrict__ wqT, _Float16* __restrict__ wkT,
    _Float16* __restrict__ wvT, _Float16* __restrict__ woT,
    _Float16* __restrict__ WgT,
    _Float16* __restrict__ wcq, _Float16* __restrict__ wck,
    _Float16* __restrict__ wcv,
    float* __restrict__ gqf, float* __restrict__ gkf, float* __restrict__ gbf)
{
  int blk = blockIdx.x;
  int tid = threadIdx.x;

  if (blk < 1024) {
    int z = blk >> 8, bx = blk & 15, by = (blk >> 4) & 15;
    const void* src = (z == 0) ? wq : ((z == 1) ? wk : ((z == 2) ? wv : wo));
    _Float16* dst   = (z == 0) ? wqT : ((z == 1) ? wkT : ((z == 2) ? wvT : woT));
    int f = flags[(z == 0) ? 2 : ((z == 1) ? 3 : ((z == 2) ? 4 : 5))];
    int Kd = (z < 3) ? Dim : Di;
    int Nn = (z < 3) ? Di : Dim;
    int n0 = bx * 64, k0 = by * 64;
    if (n0 >= Nn || k0 >= Kd) return;

    __shared__ float tile[64][65];
    int r = tid >> 4, c4 = (tid & 15) * 4;
#pragma unroll
    for (int rr = 0; rr < 4; ++rr) {
      int k = rr * 16 + r;
#pragma unroll
      for (int j = 0; j < 4; ++j)
        tile[k][c4 + j] = ldin(src, f, (size_t)(k0 + k) * Nn + n0 + c4 + j);
    }
    __syncthreads();
#pragma unroll
    for (int rr = 0; rr < 4; ++rr) {
      int n = rr * 16 + r;
      _Float16 o4[4];
#pragma unroll
      for (int j = 0; j < 4; ++j) o4[j] = (_Float16)tile[c4 + j][n];
      *(ushort4*)&dst[(size_t)(n0 + n) * Kd + k0 + c4] = *(ushort4*)o4;
    }
  } else if (blk < 1088) {
    int row = blk - 1024;   // 0..63
    if (row < 24) {
      int g = row >> 3, h = row & 7;
      const void* W = (g == 0) ? lr_w : ((g == 1) ? decay_w : mom_w);
      int f = (g == 0) ? flags[11] : ((g == 1) ? flags[13] : flags[15]);
#pragma unroll
      for (int it = 0; it < 4; ++it) {
        int d = it * 256 + tid;
        WgT[(size_t)row * Dim + d] = (_Float16)ldin(W, f, (size_t)d * Hh + h);
      }
    } else {
#pragma unroll
      for (int it = 0; it < 4; ++it)
        WgT[(size_t)row * Dim + it * 256 + tid] = (_Float16)0.f;
    }
  } else if (blk < 1104) {
    int e = (blk - 1088) * 256 + tid;   // 0..4095
    int f6 = flags[6], f7 = flags[7], f8 = flags[8];
    wcq[e] = (_Float16)ldin(cq, f6, e);
    wck[e] = (_Float16)ldin(ck, f7, e);
    wcv[e] = (_Float16)ldin(cv, f8, e);
  } else {
    int f9 = flags[9], f10 = flags[10];
    for (int i = tid; i < Di; i += 256) {
      gqf[i] = ldin(gq, f9, i);
      gkf[i] = ldin(gk, f10, i);
    }
    if (tid < 24) {
      int g = tid >> 3, h = tid & 7;
      const void* Bp = (g == 0) ? lr_b : ((g == 1) ? decay_b : mom_b);
      int fB = (g == 0) ? flags[12] : ((g == 1) ? flags[14] : flags[16]);
      gbf[tid] = ldin(Bp, fB, h);
    }
  }
}

// ---------------------------------------------------------------------------
// K1: pure RMSNorm(x) -> xaf (f16). One block per row.
// ---------------------------------------------------------------------------
__global__ __launch_bounds__(256) void k_rms(
    const void* __restrict__ x, const void* __restrict__ w_rms,
    const int* __restrict__ flags, _Float16* __restrict__ xaf)
{
  __shared__ float red[4];
  int r = blockIdx.x;
  int tid = threadIdx.x, lane = tid & 63, wid = tid >> 6;
  int fx = flags[0], fw = flags[1];

  size_t rb = (size_t)r * Dim + tid * 4;
  float v0, v1, v2, v3;
  if (fx) {
    float4 u = *(const float4*)((const float*)x + rb);
    v0 = u.x; v1 = u.y; v2 = u.z; v3 = u.w;
  } else {
    ushort4 u = *(const ushort4*)((const unsigned short*)x + rb);
    v0 = bf2f(u.x); v1 = bf2f(u.y); v2 = bf2f(u.z); v3 = bf2f(u.w);
  }
  float ss = v0 * v0 + v1 * v1 + v2 * v2 + v3 * v3;
#pragma unroll
  for (int m = 1; m < 64; m <<= 1) ss += __shfl_xor(ss, m);
  if (lane == 0) red[wid] = ss;
  __syncthreads();
  float scale = rsqrtf((red[0] + red[1] + red[2] + red[3]) * (1.0f / Dim) + EPSV);

  float w0, w1, w2, w3;
  if (fw) {
    float4 u = *(const float4*)((const float*)w_rms + tid * 4);
    w0 = u.x; w1 = u.y; w2 = u.z; w3 = u.w;
  } else {
    ushort4 u = *(const ushort4*)((const unsigned short*)w_rms + tid * 4);
    w0 = bf2f(u.x); w1 = bf2f(u.y); w2 = bf2f(u.z); w3 = bf2f(u.w);
  }
  _Float16 t4[4] = {(_Float16)(v0 * scale * w0), (_Float16)(v1 * scale * w1),
                    (_Float16)(v2 * scale * w2), (_Float16)(v3 * scale * w3)};
  *(ushort4*)&xaf[rb] = *(ushort4*)t4;
}

// ---------------------------------------------------------------------------
// K1b: gate GEMM (proven). xaf @ WgT^T -> sigmoid -> lr/decay/mom.
// ---------------------------------------------------------------------------
__global__ __launch_bounds__(256) void k_gates(
    const _Float16* __restrict__ xaf, const _Float16* __restrict__ WgT,
    const float* __restrict__ gbf,
    float* __restrict__ lr, float* __restrict__ decay, float* __restrict__ mom)
{
  __shared__ __align__(16) _Float16 As[64][40];
  __shared__ __align__(16) _Float16 Bs[64][40];

  int tid = threadIdx.x, lane = tid & 63, wvid = tid >> 6;
  int m0 = blockIdx.x * 64;
  int srow = tid >> 2, scol = (tid & 3) * 8;
  int mrow = lane & 15, quad = lane >> 4;

  f32x4 acc[4];
#pragma unroll
  for (int mi = 0; mi < 4; ++mi) acc[mi] = (f32x4){0.f, 0.f, 0.f, 0.f};

  for (int kt = 0; kt < Dim; kt += 32) {
    __syncthreads();
    *(uint4*)&As[srow][scol] = *(const uint4*)&xaf[(size_t)(m0 + srow) * Dim + kt + scol];
    *(uint4*)&Bs[srow][scol] = *(const uint4*)&WgT[(size_t)srow * Dim + kt + scol];
    __syncthreads();
    half8 bfr = *(const half8*)&Bs[wvid * 16 + mrow][quad * 8];
#pragma unroll
    for (int mi = 0; mi < 4; ++mi) {
      half8 afr = *(const half8*)&As[mi * 16 + mrow][quad * 8];
      acc[mi] = __builtin_amdgcn_mfma_f32_16x16x32_f16(afr, bfr, acc[mi], 0, 0, 0);
    }
  }

  int col = wvid * 16 + mrow;          // 0..63; only 0..23 real
  if (col < 24) {
    int g = col >> 3, h = col & 7;
    float bias = gbf[col];
    float* Op = (g == 0) ? lr : ((g == 1) ? decay : mom);
#pragma unroll
    for (int mi = 0; mi < 4; ++mi) {
#pragma unroll
      for (int r2 = 0; r2 < 4; ++r2) {
        int row = m0 + mi * 16 + quad * 4 + r2;
        int b = row >> 10, t = row & (Seq - 1);
        float z = acc[mi][r2] + bias;
        Op[(b * Hh + h) * Seq + t] = 1.f / (1.f + expf(-z));
      }
    }
  }
}

// ---------------------------------------------------------------------------
// K2: depthwise conv, time-tiled (proven round 9).
// ---------------------------------------------------------------------------
__global__ __launch_bounds__(256) void k_conv(
    const _Float16* __restrict__ xaf,
    const _Float16* __restrict__ wcq, const _Float16* __restrict__ wck,
    const _Float16* __restrict__ wcv,
    _Float16* __restrict__ qc, _Float16* __restrict__ kc,
    _Float16* __restrict__ vc)
{
  int tb = blockIdx.x, b = blockIdx.y;
  int t0 = tb * NT;
  int c0 = threadIdx.x * 4;

  _Float16 lwq[16], lwk[16], lwv[16];
  *(uint4*)&lwq[0] = *(const uint4*)&wcq[c0 * 4];
  *(uint4*)&lwq[8] = *(const uint4*)&wcq[c0 * 4 + 8];
  *(uint4*)&lwk[0] = *(const uint4*)&wck[c0 * 4];
  *(uint4*)&lwk[8] = *(const uint4*)&wck[c0 * 4 + 8];
  *(uint4*)&lwv[0] = *(const uint4*)&wcv[c0 * 4];
  *(uint4*)&lwv[8] = *(const uint4*)&wcv[c0 * 4 + 8];

  float win[4][4];
  auto loadrow = [&](int ts, float dst[4]) {
    if (ts >= 0 && ts < Seq) {
      ushort4 u = *(const ushort4*)&xaf[((size_t)(b * Seq + ts)) * Dim + c0];
      _Float16 hx[4]; *(ushort4*)hx = u;
      dst[0] = (float)hx[0]; dst[1] = (float)hx[1];
      dst[2] = (float)hx[2]; dst[3] = (float)hx[3];
    } else {
      dst[0] = 0.f; dst[1] = 0.f; dst[2] = 0.f; dst[3] = 0.f;
    }
  };
  loadrow(t0 - 2, win[0]);
  loadrow(t0 - 1, win[1]);
  loadrow(t0,     win[2]);

#pragma unroll
  for (int tt = 0; tt < NT; ++tt) {
    int t = t0 + tt;
    loadrow(t + 1, win[(tt + 3) & 3]);
    const float* r0 = win[(tt + 0) & 3];
    const float* r1 = win[(tt + 1) & 3];
    const float* r2 = win[(tt + 2) & 3];
    const float* r3 = win[(tt + 3) & 3];

    _Float16 tq[4], tk[4], tv[4];
#pragma unroll
    for (int j = 0; j < 4; ++j) {
      float aq = r0[j] * (float)lwq[j * 4 + 0] + r1[j] * (float)lwq[j * 4 + 1]
               + r2[j] * (float)lwq[j * 4 + 2] + r3[j] * (float)lwq[j * 4 + 3];
      float ak = r0[j] * (float)lwk[j * 4 + 0] + r1[j] * (float)lwk[j * 4 + 1]
               + r2[j] * (float)lwk[j * 4 + 2] + r3[j] * (float)lwk[j * 4 + 3];
      float av = r0[j] * (float)lwv[j * 4 + 0] + r1[j] * (float)lwv[j * 4 + 1]
               + r2[j] * (float)lwv[j * 4 + 2] + r3[j] * (float)lwv[j * 4 + 3];
      tq[j] = (_Float16)aq; tk[j] = (_Float16)ak; tv[j] = (_Float16)av;
    }
    size_t o = ((size_t)(b * Seq + t)) * Dim + c0;
    *(ushort4*)&qc[o] = *(ushort4*)tq;
    *(ushort4*)&kc[o] = *(ushort4*)tk;
    *(ushort4*)&vc[o] = *(ushort4*)tv;
  }
}

// ---------------------------------------------------------------------------
// K3 v2: MFMA GEMM, 128M x 64N tile, BK=32, pre-transposed f16 B [N][K].
// 4 waves: wave w owns rows [w*32, w*32+32) x all 64 cols -> 8 MFMA/wave/kt.
// ---------------------------------------------------------------------------
__global__ __launch_bounds__(256) void k_gemm_128(
    const _Float16* __restrict__ A0, const _Float16* __restrict__ A1,
    const _Float16* __restrict__ A2,
    const _Float16* __restrict__ B0, const _Float16* __restrict__ B1,
    const _Float16* __restrict__ B2,
    void* __restrict__ C0, void* __restrict__ C1, void* __restrict__ C2,
    const int* __restrict__ flags,
    int Nn, int Kd, int is_final)
{
  int z = blockIdx.z;
  const _Float16* A  = (z == 0) ? A0 : ((z == 1) ? A1 : A2);
  const _Float16* Bt = (z == 0) ? B0 : ((z == 1) ? B1 : B2);
  void* C = (z == 0) ? C0 : ((z == 1) ? C1 : C2);

  __shared__ __align__(16) _Float16 As[128][40];
  __shared__ __align__(16) _Float16 Bs[64][40];

  int tid = threadIdx.x, lane = tid & 63, wv = tid >> 6;
  int n0 = blockIdx.x * 64, m0 = blockIdx.y * 128;
  int mrow = lane & 15, quad = lane >> 4;
  int wm = wv * 32;

  // staging slots
  int ar0 = tid >> 2,        ac0 = (tid & 3) * 8;          // A rows 0..63
  int ar1 = (tid + 256) >> 2;                              // A rows 64..127

  f32x4 acc[2][4];
#pragma unroll
  for (int mi = 0; mi < 2; ++mi)
#pragma unroll
    for (int ni = 0; ni < 4; ++ni) acc[mi][ni] = (f32x4){0.f, 0.f, 0.f, 0.f};

  for (int kt = 0; kt < Kd; kt += 32) {
    __syncthreads();
    *(uint4*)&As[ar0][ac0] = *(const uint4*)&A[(size_t)(m0 + ar0) * Kd + kt + ac0];
    *(uint4*)&As[ar1][ac0] = *(const uint4*)&A[(size_t)(m0 + ar1) * Kd + kt + ac0];
    *(uint4*)&Bs[ar0][ac0] = *(const uint4*)&Bt[(size_t)(n0 + ar0) * Kd + kt + ac0];
    __syncthreads();

    half8 bfr[4];
#pragma unroll
    for (int ni = 0; ni < 4; ++ni)
      bfr[ni] = *(const half8*)&Bs[ni * 16 + mrow][quad * 8];
#pragma unroll
    for (int mi = 0; mi < 2; ++mi) {
      half8 afr = *(const half8*)&As[wm + mi * 16 + mrow][quad * 8];
#pragma unroll
      for (int ni = 0; ni < 4; ++ni)
        acc[mi][ni] = __builtin_amdgcn_mfma_f32_16x16x32_f16(afr, bfr[ni], acc[mi][ni], 0, 0, 0);
    }
  }

  int any_bf16 = 0;
  if (is_final) {
#pragma unroll
    for (int i2 = 0; i2 < 17; ++i2) any_bf16 |= (flags[i2] == 0);
  }

#pragma unroll
  for (int mi = 0; mi < 2; ++mi) {
#pragma unroll
    for (int ni = 0; ni < 4; ++ni) {
      int col = n0 + ni * 16 + mrow;
#pragma unroll
      for (int r2 = 0; r2 < 4; ++r2) {
        int row = m0 + wm + mi * 16 + quad * 4 + r2;
        float v = acc[mi][ni][r2];
        size_t idx = (size_t)row * Nn + col;
        if (!is_final)        ((_Float16*)C)[idx] = (_Float16)v;
        else if (any_bf16)    ((unsigned short*)C)[idx] = f2bf(v);
        else                  ((float*)C)[idx] = v;
      }
    }
  }
}

// ---------------------------------------------------------------------------
// Recurrence phases (proven, unchanged).
// ---------------------------------------------------------------------------
__global__ __launch_bounds__(256) void k_phaseA(
    const _Float16* __restrict__ kpre, const _Float16* __restrict__ vpre,
    const float* __restrict__ gkf,
    const float* __restrict__ lr, const float* __restrict__ decay,
    const float* __restrict__ mom,
    _Float16* __restrict__ ZS_Z, _Float16* __restrict__ ZS_S,
    float* __restrict__ Mc, float* __restrict__ Dc, float* __restrict__ Wc)
{
  int c = blockIdx.x, s = blockIdx.y;
  int b = s >> 3, h = s & 7;
  int tid = threadIdx.x, lane = tid & 63, wv = tid >> 6;
  int i = tid >> 2, j0 = (tid & 3) * 16;
  __shared__ float kn[CLEN][64], vv[CLEN][64];
  __shared__ float gl[CLEN], gd[CLEN], gm[CLEN];

  {
    int t = tid >> 3, col = (tid & 7) * 8;
    size_t g = ((size_t)(b * Seq + c * CLEN + t)) * Di + h * 64 + col;
    half8 kv = *(const half8*)&kpre[g];
    half8 vvv = *(const half8*)&vpre[g];
#pragma unroll
    for (int j = 0; j < 8; ++j) { kn[t][col + j] = (float)kv[j]; vv[t][col + j] = (float)vvv[j]; }
    if (tid < 96) {
      int which = tid >> 5, t2 = tid & 31;
      const float* gp = (which == 0) ? lr : ((which == 1) ? decay : mom);
      float val = gp[s * Seq + c * CLEN + t2];
      if (which == 0) gl[t2] = val; else if (which == 1) gd[t2] = val; else gm[t2] = val;
    }
  }
  __syncthreads();
  {
    float gk = gkf[h * 64 + lane];
#pragma unroll
    for (int tt = 0; tt < 8; ++tt) {
      int t = wv * 8 + tt;
      float kvv = kn[t][lane];
      float ss = kvv * kvv;
#pragma unroll
      for (int m = 1; m < 64; m <<= 1) ss += __shfl_xor(ss, m);
      kn[t][lane] = kvv * (1.f / fmaxf(sqrtf(ss) * 0.125f, 1e-8f)) * gk;
    }
  }
  __syncthreads();

  float Zl[16], Sl[16];
#pragma unroll
  for (int jj = 0; jj < 16; ++jj) { Zl[jj] = 0.f; Sl[jj] = 0.f; }
  float Mcum = 1.f, Dcum = 1.f, wacc = 0.f;

  for (int t = 0; t < CLEN; ++t) {
    float l = gl[t], dd = gd[t], mm = gm[t];
    float vi = vv[t][i];
    Mcum *= mm;
#pragma unroll
    for (int jj = 0; jj < 16; ++jj) {
      Zl[jj] = fmaf(mm, Zl[jj], -vi * kn[t][j0 + jj]);
      Sl[jj] = fmaf(dd, Sl[jj], -l * Zl[jj]);
    }
    wacc = fmaf(dd, wacc, -l * Mcum);
    Dcum *= dd;
  }
  size_t base = ((size_t)(s * CHUNK + c)) * 4096 + (size_t)i * 64 + j0;
  half8 zo0, zo1, so0, so1;
#pragma unroll
  for (int jj = 0; jj < 8; ++jj) {
    zo0[jj] = (_Float16)Zl[jj];     zo1[jj] = (_Float16)Zl[jj + 8];
    so0[jj] = (_Float16)Sl[jj];     so1[jj] = (_Float16)Sl[jj + 8];
  }
  *(half8*)&ZS_Z[base] = zo0; *(half8*)&ZS_Z[base + 8] = zo1;
  *(half8*)&ZS_S[base] = so0; *(half8*)&ZS_S[base + 8] = so1;
  if (tid == 0) {
    Mc[s * CHUNK + c] = Mcum; Dc[s * CHUNK + c] = Dcum; Wc[s * CHUNK + c] = wacc;
  }
}

__global__ __launch_bounds__(256) void k_phaseB(
    _Float16* __restrict__ ZS_Z, _Float16* __restrict__ ZS_S,
    const float* __restrict__ Mc, const float* __restrict__ Dc,
    const float* __restrict__ Wc)
{
  int s = blockIdx.x;
  int e = blockIdx.y * 256 + threadIdx.x;
  float Z = 0.f, S = 0.f;
  for (int c = 0; c < CHUNK; ++c) {
    size_t base = ((size_t)(s * CHUNK + c)) * 4096 + e;
    float mc = Mc[s * CHUNK + c], dc = Dc[s * CHUNK + c], wc = Wc[s * CHUNK + c];
    float zl = (float)ZS_Z[base], sl = (float)ZS_S[base];
    ZS_Z[base] = (_Float16)Z; ZS_S[base] = (_Float16)S;   // chunk inputs
    S = fmaf(dc, S, fmaf(wc, Z, sl));  // uses OLD Z (= chunk input)
    Z = fmaf(mc, Z, zl);
  }
}

__global__ __launch_bounds__(256) void k_phaseC(
    const _Float16* __restrict__ qpre, const _Float16* __restrict__ kpre,
    const _Float16* __restrict__ vpre,
    const float* __restrict__ gqf, const float* __restrict__ gkf,
    const float* __restrict__ lr, const float* __restrict__ decay,
    const float* __restrict__ mom,
    const _Float16* __restrict__ ZS_Z, const _Float16* __restrict__ ZS_S,
    _Float16* __restrict__ yb)
{
  int c = blockIdx.x, s = blockIdx.y;
  int b = s >> 3, h = s & 7;
  int tid = threadIdx.x, lane = tid & 63, wv = tid >> 6;
  int i = tid >> 2, j0 = (tid & 3) * 16;
  __shared__ float kn[CLEN][64], vv[CLEN][64], qn[CLEN][64];
  __shared__ float gl[CLEN], gd[CLEN], gm[CLEN];

  float Zi_[16], Si_[16], Zl[16], Sl[16];
  size_t base = ((size_t)(s * CHUNK + c)) * 4096 + (size_t)i * 64 + j0;
  {
    half8 z0 = *(const half8*)&ZS_Z[base], z1 = *(const half8*)&ZS_Z[base + 8];
    half8 s0 = *(const half8*)&ZS_S[base], s1 = *(const half8*)&ZS_S[base + 8];
#pragma unroll
    for (int jj = 0; jj < 8; ++jj) {
      Zi_[jj] = (float)z0[jj]; Zi_[jj + 8] = (float)z1[jj];
      Si_[jj] = (float)s0[jj]; Si_[jj + 8] = (float)s1[jj];
      Zl[jj] = 0.f; Zl[jj + 8] = 0.f; Sl[jj] = 0.f; Sl[jj + 8] = 0.f;
    }
  }
  {
    int t = tid >> 3, col = (tid & 7) * 8;
    size_t g = ((size_t)(b * Seq + c * CLEN + t)) * Di + h * 64 + col;
    half8 kv = *(const half8*)&kpre[g];
    half8 vvv = *(const half8*)&vpre[g];
    half8 qv = *(const half8*)&qpre[g];
#pragma unroll
    for (int j = 0; j < 8; ++j) {
      kn[t][col + j] = (float)kv[j]; vv[t][col + j] = (float)vvv[j];
      qn[t][col + j] = (float)qv[j];
    }
    if (tid < 96) {
      int which = tid >> 5, t2 = tid & 31;
      const float* gp = (which == 0) ? lr : ((which == 1) ? decay : mom);
      float val = gp[s * Seq + c * CLEN + t2];
      if (which == 0) gl[t2] = val; else if (which == 1) gd[t2] = val; else gm[t2] = val;
    }
  }
  __syncthreads();
  {
    float gk = gkf[h * 64 + lane];
    float gq = gqf[h * 64 + lane];
#pragma unroll
    for (int tt = 0; tt < 8; ++tt) {
      int t = wv * 8 + tt;
      float kvv = kn[t][lane];
      float ssk = kvv * kvv;
      float qvv = qn[t][lane];
      float ssq = qvv * qvv;
#pragma unroll
      for (int m = 1; m < 64; m <<= 1) { ssk += __shfl_xor(ssk, m); ssq += __shfl_xor(ssq, m); }
      kn[t][lane] = kvv * (1.f / fmaxf(sqrtf(ssk) * 0.125f, 1e-8f)) * gk;
      qn[t][lane] = qvv * (1.f / fmaxf(sqrtf(ssq) * 0.125f, 1e-8f)) * gq;
    }
  }
  __syncthreads();

  float Mcum = 1.f, Dcum = 1.f, wacc = 0.f;
  float Dprev = 1.f, wprev = 0.f;

  for (int t = 0; t < CLEN; ++t) {
    float l = gl[t], dd = gd[t], mm = gm[t];

    float yp = 0.f;
#pragma unroll
    for (int jj = 0; jj < 16; ++jj) {
      float tmp = fmaf(Dprev, Si_[jj], fmaf(wprev, Zi_[jj], Sl[jj]));
      yp = fmaf(tmp, qn[t][j0 + jj], yp);
    }
    yp += __shfl_xor(yp, 1);
    yp += __shfl_xor(yp, 2);
    if ((tid & 3) == 0)
      yb[((size_t)(b * Seq + c * CLEN + t)) * Di + h * 64 + i] = (_Float16)yp;

    float vi = vv[t][i];
    Mcum *= mm;
#pragma unroll
    for (int jj = 0; jj < 16; ++jj) {
      Zl[jj] = fmaf(mm, Zl[jj], -vi * kn[t][j0 + jj]);
      Sl[jj] = fmaf(dd, Sl[jj], -l * Zl[jj]);
    }
    wacc = fmaf(dd, wacc, -l * Mcum);
    Dcum *= dd;
    Dprev = Dcum; wprev = wacc;
  }
}

// ---------------------------------------------------------------------------
extern "C" void kernel_launch(void* const* d_in, const int* in_sizes, int n_in,
                              void* d_out, int out_size, void* d_ws, size_t ws_size,
                              hipStream_t stream) {
  InPtrs ip;
  for (int i = 0; i < 17; ++i) { ip.p[i] = d_in[i]; ip.n[i] = in_sizes[i]; }

  char* p = (char*)d_ws;
  auto take = [&](size_t bytes) -> char* {
    char* q = p; p += (bytes + 255) & ~(size_t)255; return q;
  };
  int* flags           = (int*)take(32 * 4);
  _Float16* xaf        = (_Float16*)take((size_t)BN * Dim * 2);   // 4 MB
  _Float16* qc         = (_Float16*)take((size_t)BN * Dim * 2);   // 4 MB
  _Float16* kc         = (_Float16*)take((size_t)BN * Dim * 2);   // 4 MB
  _Float16* vc         = (_Float16*)take((size_t)BN * Dim * 2);   // 4 MB
  _Float16* qpre       = (_Float16*)take((size_t)BN * Di * 2);    // 2 MB
  _Float16* kpre       = (_Float16*)take((size_t)BN * Di * 2);    // 2 MB
  _Float16* vpre       = (_Float16*)take((size_t)BN * Di * 2);    // 2 MB
  float* lrA           = (float*)take((size_t)NSEQ * Seq * 4);
  float* decayA        = (float*)take((size_t)NSEQ * Seq * 4);
  float* momA          = (float*)take((size_t)NSEQ * Seq * 4);
  float* Mc            = (float*)take((size_t)NSEQ * CHUNK * 4);
  float* Dc            = (float*)take((size_t)NSEQ * CHUNK * 4);
  float* Wc            = (float*)take((size_t)NSEQ * CHUNK * 4);
  _Float16* wqT        = (_Float16*)take((size_t)Di * Dim * 2);   // 1 MB
  _Float16* wkT        = (_Float16*)take((size_t)Di * Dim * 2);   // 1 MB
  _Float16* wvT        = (_Float16*)take((size_t)Di * Dim * 2);   // 1 MB
  _Float16* woT        = (_Float16*)take((size_t)Dim * Di * 2);   // 1 MB
  _Float16* WgT        = (_Float16*)take((size_t)64 * Dim * 2);   // 128 KB
  _Float16* wcq        = (_Float16*)take((size_t)Dim * 4 * 2);
  _Float16* wck        = (_Float16*)take((size_t)Dim * 4 * 2);
  _Float16* wcv        = (_Float16*)take((size_t)Dim * 4 * 2);
  float* gqf           = (float*)take(Di * 4);
  float* gkf           = (float*)take(Di * 4);
  float* gbf           = (float*)take(32 * 4);
  // Aliases: qc/kc/vc are dead after the QKV GEMM
  _Float16* ZS_Z       = qc;
  _Float16* ZS_S       = kc;
  _Float16* yb         = vc;

  k_sniff<<<17, 64, 0, stream>>>(ip, flags);
  k_prep_all<<<1105, 256, 0, stream>>>(
      d_in[2], d_in[3], d_in[4], d_in[5],
      d_in[11], d_in[13], d_in[15],
      d_in[6], d_in[7], d_in[8],
      d_in[9], d_in[10], d_in[12], d_in[14], d_in[16],
      flags, wqT, wkT, wvT, woT, WgT, wcq, wck, wcv, gqf, gkf, gbf);

  k_rms<<<BN, 256, 0, stream>>>(d_in[0], d_in[1], flags, xaf);
  k_gates<<<BN / 64, 256, 0, stream>>>(xaf, WgT, gbf, lrA, decayA, momA);
  k_conv<<<dim3(Seq / NT, Bb), 256, 0, stream>>>(xaf, wcq, wck, wcv, qc, kc, vc);

  dim3 g1(Di / 64, BN / 128, 3);
  k_gemm_128<<<g1, 256, 0, stream>>>(qc, kc, vc, wqT, wkT, wvT,
                                     qpre, kpre, vpre, flags, Di, Dim, 0);

  k_phaseA<<<dim3(CHUNK, NSEQ), 256, 0, stream>>>(kpre, vpre, gkf,
                                                  lrA, decayA, momA,
                                                  ZS_Z, ZS_S, Mc, Dc, Wc);
  k_phaseB<<<dim3(NSEQ, 16), 256, 0, stream>>>(ZS_Z, ZS_S, Mc, Dc, Wc);
  k_phaseC<<<dim3(CHUNK, NSEQ), 256, 0, stream>>>(qpre, kpre, vpre, gqf, gkf,
                                                  lrA, decayA, momA,
                                                  ZS_Z, ZS_S, yb);

  dim3 g2(Dim / 64, BN / 128, 1);
  k_gemm_128<<<g2, 256, 0, stream>>>(yb, yb, yb, woT, woT, woT,
                                     d_out, d_out, d_out, flags, Dim, Di, 1);
}

// Round 11
// 195.640 us; speedup vs baseline: 2.3018x; 1.0654x over previous
//
#include <hip/hip_runtime.h>
#include <math.h>

#define DEV __device__ __forceinline__

constexpr int Bb   = 2;
constexpr int Seq  = 1024;
constexpr int Dim  = 1024;
constexpr int Hh   = 8;
constexpr int Dh   = 64;
constexpr int Di   = 512;
constexpr int BN   = Bb * Seq;       // 2048
constexpr int NSEQ = Bb * Hh;        // 16
constexpr int CHUNK = 32;            // chunks per sequence
constexpr int CLEN  = Seq / CHUNK;   // 32
constexpr float EPSV = 1.1920929e-07f;
constexpr int NT2  = 8;              // conv timesteps per block (fused kernel)
constexpr int KSPL = 8;              // gate GEMM K-splits

typedef _Float16 half8 __attribute__((ext_vector_type(8)));
typedef float    f32x4 __attribute__((ext_vector_type(4)));

DEV float bf2f(unsigned short u) {
  union { unsigned int i; float f; } x; x.i = ((unsigned int)u) << 16; return x.f;
}
DEV unsigned short f2bf(float f) {
  union { float f; unsigned int i; } x; x.f = f;
  unsigned int r = x.i + 0x7fffu + ((x.i >> 16) & 1u);
  return (unsigned short)(r >> 16);
}
// flag: 1 -> fp32, 0 -> bf16
DEV float ldin(const void* p, int f32, size_t i) {
  if (f32) return ((const float*)p)[i];
  return bf2f(((const unsigned short*)p)[i]);
}
// per-thread sample vote for self-sniff (call with tid<64, reduce in wave)
DEV int sniff_vote(const void* p, int n, int tid) {
  int j = 2 * tid, valid = 0, bad = 0;
  if (j < n) {
    valid = 1;
    float v = bf2f(((const unsigned short*)p)[j]);
    float a = fabsf(v);
    if (!(a >= 1e-12f && a <= 1e4f)) bad = 1;
  }
#pragma unroll
  for (int m = 1; m < 64; m <<= 1) { valid += __shfl_xor(valid, m); bad += __shfl_xor(bad, m); }
  return (2 * bad > valid) ? 1 : 0;
}

struct InPtrs { const void* p[17]; int n[17]; };

// ---------------------------------------------------------------------------
// K0: ALL weight prep, self-sniffing. Block roles:
//   [0,1024)    : transpose+convert wq/wk/wv/wo -> f16 [N][K]
//   [1024,1088) : gate weights -> WgT[64][1024]
//   [1088,1104) : conv weights -> f16 [Dim][4] x3
//   1104        : full flags[17] + gammas + gate biases
// ---------------------------------------------------------------------------
__global__ __launch_bounds__(256) void k_prep_all(
    InPtrs ip,
    int* __restrict__ flags,
    _Float16* __restrict__ wqT, _Float16* __restrict__ wkT,
    _Float16* __restrict__ wvT, _Float16* __restrict__ woT,
    _Float16* __restrict__ WgT,
    _Float16* __restrict__ wcq, _Float16* __restrict__ wck,
    _Float16* __restrict__ wcv,
    float* __restrict__ gqf, float* __restrict__ gkf, float* __restrict__ gbf)
{
  int blk = blockIdx.x;
  int tid = threadIdx.x;
  __shared__ int sfl[8];

  if (blk < 1024) {
    int z = blk >> 8, bx = blk & 15, by = (blk >> 4) & 15;
    int idx = (z == 0) ? 2 : ((z == 1) ? 3 : ((z == 2) ? 4 : 5));
    const void* src = ip.p[idx];
    _Float16* dst   = (z == 0) ? wqT : ((z == 1) ? wkT : ((z == 2) ? wvT : woT));
    int Kd = (z < 3) ? Dim : Di;
    int Nn = (z < 3) ? Di : Dim;
    int n0 = bx * 64, k0 = by * 64;
    if (n0 >= Nn || k0 >= Kd) return;

    if (tid < 64) { int f = sniff_vote(src, ip.n[idx], tid); if (tid == 0) sfl[0] = f; }
    __syncthreads();
    int f = sfl[0];

    __shared__ float tile[64][65];
    int r = tid >> 4, c4 = (tid & 15) * 4;
#pragma unroll
    for (int rr = 0; rr < 4; ++rr) {
      int k = rr * 16 + r;
#pragma unroll
      for (int j = 0; j < 4; ++j)
        tile[k][c4 + j] = ldin(src, f, (size_t)(k0 + k) * Nn + n0 + c4 + j);
    }
    __syncthreads();
#pragma unroll
    for (int rr = 0; rr < 4; ++rr) {
      int n = rr * 16 + r;
      _Float16 o4[4];
#pragma unroll
      for (int j = 0; j < 4; ++j) o4[j] = (_Float16)tile[c4 + j][n];
      *(ushort4*)&dst[(size_t)(n0 + n) * Kd + k0 + c4] = *(ushort4*)o4;
    }
  } else if (blk < 1088) {
    int row = blk - 1024;   // 0..63
    if (row < 24) {
      int g = row >> 3, h = row & 7;
      int idx = (g == 0) ? 11 : ((g == 1) ? 13 : 15);
      const void* W = ip.p[idx];
      if (tid < 64) { int f = sniff_vote(W, ip.n[idx], tid); if (tid == 0) sfl[0] = f; }
      __syncthreads();
      int f = sfl[0];
#pragma unroll
      for (int it = 0; it < 4; ++it) {
        int d = it * 256 + tid;
        WgT[(size_t)row * Dim + d] = (_Float16)ldin(W, f, (size_t)d * Hh + h);
      }
    } else {
#pragma unroll
      for (int it = 0; it < 4; ++it)
        WgT[(size_t)row * Dim + it * 256 + tid] = (_Float16)0.f;
    }
  } else if (blk < 1104) {
    if (tid < 64) {
      int f6 = sniff_vote(ip.p[6], ip.n[6], tid);
      int f7 = sniff_vote(ip.p[7], ip.n[7], tid);
      int f8 = sniff_vote(ip.p[8], ip.n[8], tid);
      if (tid == 0) { sfl[0] = f6; sfl[1] = f7; sfl[2] = f8; }
    }
    __syncthreads();
    int e = (blk - 1088) * 256 + tid;   // 0..4095
    wcq[e] = (_Float16)ldin(ip.p[6], sfl[0], e);
    wck[e] = (_Float16)ldin(ip.p[7], sfl[1], e);
    wcv[e] = (_Float16)ldin(ip.p[8], sfl[2], e);
  } else {
    // full flags for all 17 inputs (consumed by k_rmsconv + final epilogue)
    __shared__ int allf[17];
    for (int ii = 0; ii < 17; ++ii) {
      if (tid < 64) {
        int f = sniff_vote(ip.p[ii], ip.n[ii], tid);
        if (tid == 0) { flags[ii] = f; allf[ii] = f; }
      }
    }
    __syncthreads();
    int f9 = allf[9], f10 = allf[10];
    for (int i = tid; i < Di; i += 256) {
      gqf[i] = ldin(ip.p[9], f9, i);
      gkf[i] = ldin(ip.p[10], f10, i);
    }
    if (tid < 24) {
      int g = tid >> 3, h = tid & 7;
      int idx = (g == 0) ? 12 : ((g == 1) ? 14 : 16);
      gbf[tid] = ldin(ip.p[idx], allf[idx], h);
    }
  }
}

// ---------------------------------------------------------------------------
// K1: fused RMSNorm + depthwise conv. Block = (t-tile of NT2, batch).
// Computes xa for rows [t0-2, t0+NT2] (halo), keeps in LDS, writes xaf for
// own rows, then conv from LDS -> qc/kc/vc.
// ---------------------------------------------------------------------------
__global__ __launch_bounds__(256) void k_rmsconv(
    const void* __restrict__ x, const void* __restrict__ w_rms,
    const int* __restrict__ flags,
    const _Float16* __restrict__ wcq, const _Float16* __restrict__ wck,
    const _Float16* __restrict__ wcv,
    _Float16* __restrict__ xaf,
    _Float16* __restrict__ qc, _Float16* __restrict__ kc,
    _Float16* __restrict__ vc)
{
  constexpr int NR = NT2 + 3;   // 11 rows: t0-2 .. t0+NT2
  __shared__ _Float16 xas[NR][Dim];
  __shared__ float red[4];
  int tb = blockIdx.x, b = blockIdx.y;
  int t0 = tb * NT2;
  int tid = threadIdx.x, lane = tid & 63, wid = tid >> 6;
  int c0 = tid * 4;
  int fx = flags[0], fw = flags[1];

  float w0, w1, w2, w3;
  if (fw) {
    float4 u = *(const float4*)((const float*)w_rms + c0);
    w0 = u.x; w1 = u.y; w2 = u.z; w3 = u.w;
  } else {
    ushort4 u = *(const ushort4*)((const unsigned short*)w_rms + c0);
    w0 = bf2f(u.x); w1 = bf2f(u.y); w2 = bf2f(u.z); w3 = bf2f(u.w);
  }

  for (int rr = 0; rr < NR; ++rr) {
    int r = t0 - 2 + rr;
    float v0 = 0.f, v1 = 0.f, v2 = 0.f, v3 = 0.f;
    bool inr = (r >= 0 && r < Seq);
    if (inr) {
      size_t rb = (size_t)(b * Seq + r) * Dim + c0;
      if (fx) {
        float4 u = *(const float4*)((const float*)x + rb);
        v0 = u.x; v1 = u.y; v2 = u.z; v3 = u.w;
      } else {
        ushort4 u = *(const ushort4*)((const unsigned short*)x + rb);
        v0 = bf2f(u.x); v1 = bf2f(u.y); v2 = bf2f(u.z); v3 = bf2f(u.w);
      }
    }
    float ss = v0 * v0 + v1 * v1 + v2 * v2 + v3 * v3;
#pragma unroll
    for (int m = 1; m < 64; m <<= 1) ss += __shfl_xor(ss, m);
    if (lane == 0) red[wid] = ss;
    __syncthreads();
    float scale = rsqrtf((red[0] + red[1] + red[2] + red[3]) * (1.0f / Dim) + EPSV);

    _Float16 t4[4] = {(_Float16)(v0 * scale * w0), (_Float16)(v1 * scale * w1),
                      (_Float16)(v2 * scale * w2), (_Float16)(v3 * scale * w3)};
    *(ushort4*)&xas[rr][c0] = *(ushort4*)t4;
    if (inr && r >= t0 && r < t0 + NT2)
      *(ushort4*)&xaf[(size_t)(b * Seq + r) * Dim + c0] = *(ushort4*)t4;
    __syncthreads();   // protect red before next row
  }

  _Float16 lwq[16], lwk[16], lwv[16];
  *(uint4*)&lwq[0] = *(const uint4*)&wcq[c0 * 4];
  *(uint4*)&lwq[8] = *(const uint4*)&wcq[c0 * 4 + 8];
  *(uint4*)&lwk[0] = *(const uint4*)&wck[c0 * 4];
  *(uint4*)&lwk[8] = *(const uint4*)&wck[c0 * 4 + 8];
  *(uint4*)&lwv[0] = *(const uint4*)&wcv[c0 * 4];
  *(uint4*)&lwv[8] = *(const uint4*)&wcv[c0 * 4 + 8];

#pragma unroll
  for (int tt = 0; tt < NT2; ++tt) {
    float rv[4][4];
#pragma unroll
    for (int k = 0; k < 4; ++k) {
      _Float16 hx[4];
      *(ushort4*)hx = *(const ushort4*)&xas[tt + k][c0];
#pragma unroll
      for (int j = 0; j < 4; ++j) rv[k][j] = (float)hx[j];
    }
    _Float16 tq[4], tk[4], tv[4];
#pragma unroll
    for (int j = 0; j < 4; ++j) {
      float aq = rv[0][j] * (float)lwq[j * 4 + 0] + rv[1][j] * (float)lwq[j * 4 + 1]
               + rv[2][j] * (float)lwq[j * 4 + 2] + rv[3][j] * (float)lwq[j * 4 + 3];
      float ak = rv[0][j] * (float)lwk[j * 4 + 0] + rv[1][j] * (float)lwk[j * 4 + 1]
               + rv[2][j] * (float)lwk[j * 4 + 2] + rv[3][j] * (float)lwk[j * 4 + 3];
      float av = rv[0][j] * (float)lwv[j * 4 + 0] + rv[1][j] * (float)lwv[j * 4 + 1]
               + rv[2][j] * (float)lwv[j * 4 + 2] + rv[3][j] * (float)lwv[j * 4 + 3];
      tq[j] = (_Float16)aq; tk[j] = (_Float16)ak; tv[j] = (_Float16)av;
    }
    size_t o = ((size_t)(b * Seq + t0 + tt)) * Dim + c0;
    *(ushort4*)&qc[o] = *(ushort4*)tq;
    *(ushort4*)&kc[o] = *(ushort4*)tk;
    *(ushort4*)&vc[o] = *(ushort4*)tv;
  }
}

// ---------------------------------------------------------------------------
// K1b: gate GEMM, K-split. Block (m-tile, ksplit). Writes raw fp32 partials
// gpart[ks][row][32]; bias+sigmoid+reduce happens in phaseA/C.
// ---------------------------------------------------------------------------
__global__ __launch_bounds__(256) void k_gates(
    const _Float16* __restrict__ xaf, const _Float16* __restrict__ WgT,
    float* __restrict__ gpart)
{
  __shared__ __align__(16) _Float16 As[64][40];
  __shared__ __align__(16) _Float16 Bs[64][40];

  int tid = threadIdx.x, lane = tid & 63, wvid = tid >> 6;
  int m0 = blockIdx.x * 64, ks = blockIdx.y;
  int srow = tid >> 2, scol = (tid & 3) * 8;
  int mrow = lane & 15, quad = lane >> 4;
  int kbase = ks * (Dim / KSPL);      // 128-wide K chunk

  f32x4 acc[4];
#pragma unroll
  for (int mi = 0; mi < 4; ++mi) acc[mi] = (f32x4){0.f, 0.f, 0.f, 0.f};

  for (int kt = kbase; kt < kbase + Dim / KSPL; kt += 32) {
    __syncthreads();
    *(uint4*)&As[srow][scol] = *(const uint4*)&xaf[(size_t)(m0 + srow) * Dim + kt + scol];
    *(uint4*)&Bs[srow][scol] = *(const uint4*)&WgT[(size_t)srow * Dim + kt + scol];
    __syncthreads();
    half8 bfr = *(const half8*)&Bs[wvid * 16 + mrow][quad * 8];
#pragma unroll
    for (int mi = 0; mi < 4; ++mi) {
      half8 afr = *(const half8*)&As[mi * 16 + mrow][quad * 8];
      acc[mi] = __builtin_amdgcn_mfma_f32_16x16x32_f16(afr, bfr, acc[mi], 0, 0, 0);
    }
  }

  int col = wvid * 16 + mrow;          // only 0..23 real
  if (col < 24) {
#pragma unroll
    for (int mi = 0; mi < 4; ++mi) {
#pragma unroll
      for (int r2 = 0; r2 < 4; ++r2) {
        int row = m0 + mi * 16 + quad * 4 + r2;
        gpart[((size_t)ks * BN + row) * 32 + col] = acc[mi][r2];
      }
    }
  }
}

// ---------------------------------------------------------------------------
// K3: MFMA GEMM, 128M x 64N tile, BK=32, pre-transposed f16 B [N][K].
// ---------------------------------------------------------------------------
__global__ __launch_bounds__(256) void k_gemm_128(
    const _Float16* __restrict__ A0, const _Float16* __restrict__ A1,
    const _Float16* __restrict__ A2,
    const _Float16* __restrict__ B0, const _Float16* __restrict__ B1,
    const _Float16* __restrict__ B2,
    void* __restrict__ C0, void* __restrict__ C1, void* __restrict__ C2,
    const int* __restrict__ flags,
    int Nn, int Kd, int is_final)
{
  int z = blockIdx.z;
  const _Float16* A  = (z == 0) ? A0 : ((z == 1) ? A1 : A2);
  const _Float16* Bt = (z == 0) ? B0 : ((z == 1) ? B1 : B2);
  void* C = (z == 0) ? C0 : ((z == 1) ? C1 : C2);

  __shared__ __align__(16) _Float16 As[128][40];
  __shared__ __align__(16) _Float16 Bs[64][40];

  int tid = threadIdx.x, lane = tid & 63, wv = tid >> 6;
  int n0 = blockIdx.x * 64, m0 = blockIdx.y * 128;
  int mrow = lane & 15, quad = lane >> 4;
  int wm = wv * 32;

  int ar0 = tid >> 2, ac0 = (tid & 3) * 8;
  int ar1 = (tid + 256) >> 2;

  f32x4 acc[2][4];
#pragma unroll
  for (int mi = 0; mi < 2; ++mi)
#pragma unroll
    for (int ni = 0; ni < 4; ++ni) acc[mi][ni] = (f32x4){0.f, 0.f, 0.f, 0.f};

  for (int kt = 0; kt < Kd; kt += 32) {
    __syncthreads();
    *(uint4*)&As[ar0][ac0] = *(const uint4*)&A[(size_t)(m0 + ar0) * Kd + kt + ac0];
    *(uint4*)&As[ar1][ac0] = *(const uint4*)&A[(size_t)(m0 + ar1) * Kd + kt + ac0];
    *(uint4*)&Bs[ar0][ac0] = *(const uint4*)&Bt[(size_t)(n0 + ar0) * Kd + kt + ac0];
    __syncthreads();

    half8 bfr[4];
#pragma unroll
    for (int ni = 0; ni < 4; ++ni)
      bfr[ni] = *(const half8*)&Bs[ni * 16 + mrow][quad * 8];
#pragma unroll
    for (int mi = 0; mi < 2; ++mi) {
      half8 afr = *(const half8*)&As[wm + mi * 16 + mrow][quad * 8];
#pragma unroll
      for (int ni = 0; ni < 4; ++ni)
        acc[mi][ni] = __builtin_amdgcn_mfma_f32_16x16x32_f16(afr, bfr[ni], acc[mi][ni], 0, 0, 0);
    }
  }

  int any_bf16 = 0;
  if (is_final) {
#pragma unroll
    for (int i2 = 0; i2 < 17; ++i2) any_bf16 |= (flags[i2] == 0);
  }

#pragma unroll
  for (int mi = 0; mi < 2; ++mi) {
#pragma unroll
    for (int ni = 0; ni < 4; ++ni) {
      int col = n0 + ni * 16 + mrow;
#pragma unroll
      for (int r2 = 0; r2 < 4; ++r2) {
        int row = m0 + wm + mi * 16 + quad * 4 + r2;
        float v = acc[mi][ni][r2];
        size_t idx = (size_t)row * Nn + col;
        if (!is_final)        ((_Float16*)C)[idx] = (_Float16)v;
        else if (any_bf16)    ((unsigned short*)C)[idx] = f2bf(v);
        else                  ((float*)C)[idx] = v;
      }
    }
  }
}

// ---------------------------------------------------------------------------
// Gate preload helper: reduce KSPL partials + bias + sigmoid (96 threads)
// ---------------------------------------------------------------------------
DEV void load_gates(const float* __restrict__ gpart, const float* __restrict__ gbf,
                    int b, int h, int c, int tid,
                    float* gl, float* gd, float* gm)
{
  if (tid < 96) {
    int which = tid >> 5, t2 = tid & 31;
    int col = which * 8 + h;
    int row = b * Seq + c * CLEN + t2;
    float acc = gbf[col];
#pragma unroll
    for (int ks = 0; ks < KSPL; ++ks)
      acc += gpart[((size_t)ks * BN + row) * 32 + col];
    float sg = 1.f / (1.f + expf(-acc));
    if (which == 0) gl[t2] = sg; else if (which == 1) gd[t2] = sg; else gm[t2] = sg;
  }
}

// ---------------------------------------------------------------------------
// Recurrence phases.
// ---------------------------------------------------------------------------
__global__ __launch_bounds__(256) void k_phaseA(
    const _Float16* __restrict__ kpre, const _Float16* __restrict__ vpre,
    const float* __restrict__ gkf,
    const float* __restrict__ gpart, const float* __restrict__ gbf,
    _Float16* __restrict__ ZS_Z, _Float16* __restrict__ ZS_S,
    float* __restrict__ Mc, float* __restrict__ Dc, float* __restrict__ Wc)
{
  int c = blockIdx.x, s = blockIdx.y;
  int b = s >> 3, h = s & 7;
  int tid = threadIdx.x, lane = tid & 63, wv = tid >> 6;
  int i = tid >> 2, j0 = (tid & 3) * 16;
  __shared__ float kn[CLEN][64], vv[CLEN][64];
  __shared__ float gl[CLEN], gd[CLEN], gm[CLEN];

  {
    int t = tid >> 3, col = (tid & 7) * 8;
    size_t g = ((size_t)(b * Seq + c * CLEN + t)) * Di + h * 64 + col;
    half8 kv = *(const half8*)&kpre[g];
    half8 vvv = *(const half8*)&vpre[g];
#pragma unroll
    for (int j = 0; j < 8; ++j) { kn[t][col + j] = (float)kv[j]; vv[t][col + j] = (float)vvv[j]; }
    load_gates(gpart, gbf, b, h, c, tid, gl, gd, gm);
  }
  __syncthreads();
  {
    float gk = gkf[h * 64 + lane];
#pragma unroll
    for (int tt = 0; tt < 8; ++tt) {
      int t = wv * 8 + tt;
      float kvv = kn[t][lane];
      float ss = kvv * kvv;
#pragma unroll
      for (int m = 1; m < 64; m <<= 1) ss += __shfl_xor(ss, m);
      kn[t][lane] = kvv * (1.f / fmaxf(sqrtf(ss) * 0.125f, 1e-8f)) * gk;
    }
  }
  __syncthreads();

  float Zl[16], Sl[16];
#pragma unroll
  for (int jj = 0; jj < 16; ++jj) { Zl[jj] = 0.f; Sl[jj] = 0.f; }
  float Mcum = 1.f, Dcum = 1.f, wacc = 0.f;

  for (int t = 0; t < CLEN; ++t) {
    float l = gl[t], dd = gd[t], mm = gm[t];
    float vi = vv[t][i];
    Mcum *= mm;
#pragma unroll
    for (int jj = 0; jj < 16; ++jj) {
      Zl[jj] = fmaf(mm, Zl[jj], -vi * kn[t][j0 + jj]);
      Sl[jj] = fmaf(dd, Sl[jj], -l * Zl[jj]);
    }
    wacc = fmaf(dd, wacc, -l * Mcum);
    Dcum *= dd;
  }
  size_t base = ((size_t)(s * CHUNK + c)) * 4096 + (size_t)i * 64 + j0;
  half8 zo0, zo1, so0, so1;
#pragma unroll
  for (int jj = 0; jj < 8; ++jj) {
    zo0[jj] = (_Float16)Zl[jj];     zo1[jj] = (_Float16)Zl[jj + 8];
    so0[jj] = (_Float16)Sl[jj];     so1[jj] = (_Float16)Sl[jj + 8];
  }
  *(half8*)&ZS_Z[base] = zo0; *(half8*)&ZS_Z[base + 8] = zo1;
  *(half8*)&ZS_S[base] = so0; *(half8*)&ZS_S[base + 8] = so1;
  if (tid == 0) {
    Mc[s * CHUNK + c] = Mcum; Dc[s * CHUNK + c] = Dcum; Wc[s * CHUNK + c] = wacc;
  }
}

__global__ __launch_bounds__(256) void k_phaseB(
    _Float16* __restrict__ ZS_Z, _Float16* __restrict__ ZS_S,
    const float* __restrict__ Mc, const float* __restrict__ Dc,
    const float* __restrict__ Wc)
{
  int s = blockIdx.x;
  int e = blockIdx.y * 256 + threadIdx.x;
  float Z = 0.f, S = 0.f;
  for (int c = 0; c < CHUNK; ++c) {
    size_t base = ((size_t)(s * CHUNK + c)) * 4096 + e;
    float mc = Mc[s * CHUNK + c], dc = Dc[s * CHUNK + c], wc = Wc[s * CHUNK + c];
    float zl = (float)ZS_Z[base], sl = (float)ZS_S[base];
    ZS_Z[base] = (_Float16)Z; ZS_S[base] = (_Float16)S;   // chunk inputs
    S = fmaf(dc, S, fmaf(wc, Z, sl));  // uses OLD Z (= chunk input)
    Z = fmaf(mc, Z, zl);
  }
}

__global__ __launch_bounds__(256) void k_phaseC(
    const _Float16* __restrict__ qpre, const _Float16* __restrict__ kpre,
    const _Float16* __restrict__ vpre,
    const float* __restrict__ gqf, const float* __restrict__ gkf,
    const float* __restrict__ gpart, const float* __restrict__ gbf,
    const _Float16* __restrict__ ZS_Z, const _Float16* __restrict__ ZS_S,
    _Float16* __restrict__ yb)
{
  int c = blockIdx.x, s = blockIdx.y;
  int b = s >> 3, h = s & 7;
  int tid = threadIdx.x, lane = tid & 63, wv = tid >> 6;
  int i = tid >> 2, j0 = (tid & 3) * 16;
  __shared__ float kn[CLEN][64], vv[CLEN][64], qn[CLEN][64];
  __shared__ float gl[CLEN], gd[CLEN], gm[CLEN];

  float Zi_[16], Si_[16], Zl[16], Sl[16];
  size_t base = ((size_t)(s * CHUNK + c)) * 4096 + (size_t)i * 64 + j0;
  {
    half8 z0 = *(const half8*)&ZS_Z[base], z1 = *(const half8*)&ZS_Z[base + 8];
    half8 s0 = *(const half8*)&ZS_S[base], s1 = *(const half8*)&ZS_S[base + 8];
#pragma unroll
    for (int jj = 0; jj < 8; ++jj) {
      Zi_[jj] = (float)z0[jj]; Zi_[jj + 8] = (float)z1[jj];
      Si_[jj] = (float)s0[jj]; Si_[jj + 8] = (float)s1[jj];
      Zl[jj] = 0.f; Zl[jj + 8] = 0.f; Sl[jj] = 0.f; Sl[jj + 8] = 0.f;
    }
  }
  {
    int t = tid >> 3, col = (tid & 7) * 8;
    size_t g = ((size_t)(b * Seq + c * CLEN + t)) * Di + h * 64 + col;
    half8 kv = *(const half8*)&kpre[g];
    half8 vvv = *(const half8*)&vpre[g];
    half8 qv = *(const half8*)&qpre[g];
#pragma unroll
    for (int j = 0; j < 8; ++j) {
      kn[t][col + j] = (float)kv[j]; vv[t][col + j] = (float)vvv[j];
      qn[t][col + j] = (float)qv[j];
    }
    load_gates(gpart, gbf, b, h, c, tid, gl, gd, gm);
  }
  __syncthreads();
  {
    float gk = gkf[h * 64 + lane];
    float gq = gqf[h * 64 + lane];
#pragma unroll
    for (int tt = 0; tt < 8; ++tt) {
      int t = wv * 8 + tt;
      float kvv = kn[t][lane];
      float ssk = kvv * kvv;
      float qvv = qn[t][lane];
      float ssq = qvv * qvv;
#pragma unroll
      for (int m = 1; m < 64; m <<= 1) { ssk += __shfl_xor(ssk, m); ssq += __shfl_xor(ssq, m); }
      kn[t][lane] = kvv * (1.f / fmaxf(sqrtf(ssk) * 0.125f, 1e-8f)) * gk;
      qn[t][lane] = qvv * (1.f / fmaxf(sqrtf(ssq) * 0.125f, 1e-8f)) * gq;
    }
  }
  __syncthreads();

  float Mcum = 1.f, Dcum = 1.f, wacc = 0.f;
  float Dprev = 1.f, wprev = 0.f;

  for (int t = 0; t < CLEN; ++t) {
    float l = gl[t], dd = gd[t], mm = gm[t];

    float yp = 0.f;
#pragma unroll
    for (int jj = 0; jj < 16; ++jj) {
      float tmp = fmaf(Dprev, Si_[jj], fmaf(wprev, Zi_[jj], Sl[jj]));
      yp = fmaf(tmp, qn[t][j0 + jj], yp);
    }
    yp += __shfl_xor(yp, 1);
    yp += __shfl_xor(yp, 2);
    if ((tid & 3) == 0)
      yb[((size_t)(b * Seq + c * CLEN + t)) * Di + h * 64 + i] = (_Float16)yp;

    float vi = vv[t][i];
    Mcum *= mm;
#pragma unroll
    for (int jj = 0; jj < 16; ++jj) {
      Zl[jj] = fmaf(mm, Zl[jj], -vi * kn[t][j0 + jj]);
      Sl[jj] = fmaf(dd, Sl[jj], -l * Zl[jj]);
    }
    wacc = fmaf(dd, wacc, -l * Mcum);
    Dcum *= dd;
    Dprev = Dcum; wprev = wacc;
  }
}

// ---------------------------------------------------------------------------
extern "C" void kernel_launch(void* const* d_in, const int* in_sizes, int n_in,
                              void* d_out, int out_size, void* d_ws, size_t ws_size,
                              hipStream_t stream) {
  InPtrs ip;
  for (int i = 0; i < 17; ++i) { ip.p[i] = d_in[i]; ip.n[i] = in_sizes[i]; }

  char* p = (char*)d_ws;
  auto take = [&](size_t bytes) -> char* {
    char* q = p; p += (bytes + 255) & ~(size_t)255; return q;
  };
  int* flags           = (int*)take(32 * 4);
  _Float16* xaf        = (_Float16*)take((size_t)BN * Dim * 2);   // 4 MB
  _Float16* qc         = (_Float16*)take((size_t)BN * Dim * 2);   // 4 MB
  _Float16* kc         = (_Float16*)take((size_t)BN * Dim * 2);   // 4 MB
  _Float16* vc         = (_Float16*)take((size_t)BN * Dim * 2);   // 4 MB
  _Float16* qpre       = (_Float16*)take((size_t)BN * Di * 2);    // 2 MB
  _Float16* kpre       = (_Float16*)take((size_t)BN * Di * 2);    // 2 MB
  _Float16* vpre       = (_Float16*)take((size_t)BN * Di * 2);    // 2 MB
  float* gpart         = (float*)take((size_t)KSPL * BN * 32 * 4); // 2 MB
  float* Mc            = (float*)take((size_t)NSEQ * CHUNK * 4);
  float* Dc            = (float*)take((size_t)NSEQ * CHUNK * 4);
  float* Wc            = (float*)take((size_t)NSEQ * CHUNK * 4);
  _Float16* wqT        = (_Float16*)take((size_t)Di * Dim * 2);   // 1 MB
  _Float16* wkT        = (_Float16*)take((size_t)Di * Dim * 2);   // 1 MB
  _Float16* wvT        = (_Float16*)take((size_t)Di * Dim * 2);   // 1 MB
  _Float16* woT        = (_Float16*)take((size_t)Dim * Di * 2);   // 1 MB
  _Float16* WgT        = (_Float16*)take((size_t)64 * Dim * 2);   // 128 KB
  _Float16* wcq        = (_Float16*)take((size_t)Dim * 4 * 2);
  _Float16* wck        = (_Float16*)take((size_t)Dim * 4 * 2);
  _Float16* wcv        = (_Float16*)take((size_t)Dim * 4 * 2);
  float* gqf           = (float*)take(Di * 4);
  float* gkf           = (float*)take(Di * 4);
  float* gbf           = (float*)take(32 * 4);
  // Aliases: qc/kc/vc are dead after the QKV GEMM
  _Float16* ZS_Z       = qc;
  _Float16* ZS_S       = kc;
  _Float16* yb         = vc;

  k_prep_all<<<1105, 256, 0, stream>>>(ip, flags, wqT, wkT, wvT, woT, WgT,
                                       wcq, wck, wcv, gqf, gkf, gbf);

  k_rmsconv<<<dim3(Seq / NT2, Bb), 256, 0, stream>>>(
      d_in[0], d_in[1], flags, wcq, wck, wcv, xaf, qc, kc, vc);

  k_gates<<<dim3(BN / 64, KSPL), 256, 0, stream>>>(xaf, WgT, gpart);

  dim3 g1(Di / 64, BN / 128, 3);
  k_gemm_128<<<g1, 256, 0, stream>>>(qc, kc, vc, wqT, wkT, wvT,
                                     qpre, kpre, vpre, flags, Di, Dim, 0);

  k_phaseA<<<dim3(CHUNK, NSEQ), 256, 0, stream>>>(kpre, vpre, gkf,
                                                  gpart, gbf,
                                                  ZS_Z, ZS_S, Mc, Dc, Wc);
  k_phaseB<<<dim3(NSEQ, 16), 256, 0, stream>>>(ZS_Z, ZS_S, Mc, Dc, Wc);
  k_phaseC<<<dim3(CHUNK, NSEQ), 256, 0, stream>>>(qpre, kpre, vpre, gqf, gkf,
                                                  gpart, gbf,
                                                  ZS_Z, ZS_S, yb);

  dim3 g2(Dim / 64, BN / 128, 1);
  k_gemm_128<<<g2, 256, 0, stream>>>(yb, yb, yb, woT, woT, woT,
                                     d_out, d_out, d_out, flags, Dim, Di, 1);
}

// Round 12
// 186.319 us; speedup vs baseline: 2.4170x; 1.0500x over previous
//
#include <hip/hip_runtime.h>
#include <math.h>

#define DEV __device__ __forceinline__

constexpr int Bb   = 2;
constexpr int Seq  = 1024;
constexpr int Dim  = 1024;
constexpr int Hh   = 8;
constexpr int Dh   = 64;
constexpr int Di   = 512;
constexpr int BN   = Bb * Seq;       // 2048
constexpr int NSEQ = Bb * Hh;        // 16
constexpr int CHUNK = 32;            // chunks per sequence
constexpr int CLEN  = Seq / CHUNK;   // 32
constexpr float EPSV = 1.1920929e-07f;
constexpr int NT2  = 8;              // conv timesteps per block (fused kernel)
constexpr int KSPL = 8;              // gate GEMM K-splits

typedef _Float16 half8 __attribute__((ext_vector_type(8)));
typedef float    f32x4 __attribute__((ext_vector_type(4)));

DEV float bf2f(unsigned short u) {
  union { unsigned int i; float f; } x; x.i = ((unsigned int)u) << 16; return x.f;
}
DEV unsigned short f2bf(float f) {
  union { float f; unsigned int i; } x; x.f = f;
  unsigned int r = x.i + 0x7fffu + ((x.i >> 16) & 1u);
  return (unsigned short)(r >> 16);
}
// flag: 1 -> fp32, 0 -> bf16
DEV float ldin(const void* p, int f32, size_t i) {
  if (f32) return ((const float*)p)[i];
  return bf2f(((const unsigned short*)p)[i]);
}
DEV void ld4(const void* p, int f32, size_t i, float* dst) {
  if (f32) {
    float4 u = *(const float4*)((const float*)p + i);
    dst[0] = u.x; dst[1] = u.y; dst[2] = u.z; dst[3] = u.w;
  } else {
    ushort4 u = *(const ushort4*)((const unsigned short*)p + i);
    dst[0] = bf2f(u.x); dst[1] = bf2f(u.y); dst[2] = bf2f(u.z); dst[3] = bf2f(u.w);
  }
}
// per-thread sample vote for self-sniff (call with tid<64, reduce in wave)
DEV int sniff_vote(const void* p, int n, int tid) {
  int j = 2 * tid, valid = 0, bad = 0;
  if (j < n) {
    valid = 1;
    float v = bf2f(((const unsigned short*)p)[j]);
    float a = fabsf(v);
    if (!(a >= 1e-12f && a <= 1e4f)) bad = 1;
  }
#pragma unroll
  for (int m = 1; m < 64; m <<= 1) { valid += __shfl_xor(valid, m); bad += __shfl_xor(bad, m); }
  return (2 * bad > valid) ? 1 : 0;
}

struct InPtrs { const void* p[17]; int n[17]; };

// ---------------------------------------------------------------------------
// K0: ALL weight prep, self-sniffing. Block roles:
//   [0,1024)    : transpose+convert wq/wk/wv/wo -> f16 [N][K]  (vectorized)
//   [1024,1088) : gate weights -> WgT[64][1024]
//   [1088,1104) : conv weights -> f16 [Dim][4] x3
//   1104        : full flags[17] + gammas + gate biases
// ---------------------------------------------------------------------------
__global__ __launch_bounds__(256) void k_prep_all(
    InPtrs ip,
    int* __restrict__ flags,
    _Float16* __restrict__ wqT, _Float16* __restrict__ wkT,
    _Float16* __restrict__ wvT, _Float16* __restrict__ woT,
    _Float16* __restrict__ WgT,
    _Float16* __restrict__ wcq, _Float16* __restrict__ wck,
    _Float16* __restrict__ wcv,
    float* __restrict__ gqf, float* __restrict__ gkf, float* __restrict__ gbf)
{
  int blk = blockIdx.x;
  int tid = threadIdx.x;
  __shared__ int sfl[8];

  if (blk < 1024) {
    int z = blk >> 8, bx = blk & 15, by = (blk >> 4) & 15;
    int idx = (z == 0) ? 2 : ((z == 1) ? 3 : ((z == 2) ? 4 : 5));
    const void* src = ip.p[idx];
    _Float16* dst   = (z == 0) ? wqT : ((z == 1) ? wkT : ((z == 2) ? wvT : woT));
    int Kd = (z < 3) ? Dim : Di;
    int Nn = (z < 3) ? Di : Dim;
    int n0 = bx * 64, k0 = by * 64;
    if (n0 >= Nn || k0 >= Kd) return;

    if (tid < 64) { int f = sniff_vote(src, ip.n[idx], tid); if (tid == 0) sfl[0] = f; }
    __syncthreads();
    int f = sfl[0];

    __shared__ float tile[64][65];
    int r = tid >> 4, c4 = (tid & 15) * 4;
#pragma unroll
    for (int rr = 0; rr < 4; ++rr) {
      int k = rr * 16 + r;
      ld4(src, f, (size_t)(k0 + k) * Nn + n0 + c4, &tile[k][c4]);
    }
    __syncthreads();
#pragma unroll
    for (int rr = 0; rr < 4; ++rr) {
      int n = rr * 16 + r;
      _Float16 o4[4];
#pragma unroll
      for (int j = 0; j < 4; ++j) o4[j] = (_Float16)tile[c4 + j][n];
      *(ushort4*)&dst[(size_t)(n0 + n) * Kd + k0 + c4] = *(ushort4*)o4;
    }
  } else if (blk < 1088) {
    int row = blk - 1024;   // 0..63
    if (row < 24) {
      int g = row >> 3, h = row & 7;
      int idx = (g == 0) ? 11 : ((g == 1) ? 13 : 15);
      const void* W = ip.p[idx];
      if (tid < 64) { int f = sniff_vote(W, ip.n[idx], tid); if (tid == 0) sfl[0] = f; }
      __syncthreads();
      int f = sfl[0];
#pragma unroll
      for (int it = 0; it < 4; ++it) {
        int d = it * 256 + tid;
        WgT[(size_t)row * Dim + d] = (_Float16)ldin(W, f, (size_t)d * Hh + h);
      }
    } else {
#pragma unroll
      for (int it = 0; it < 4; ++it)
        WgT[(size_t)row * Dim + it * 256 + tid] = (_Float16)0.f;
    }
  } else if (blk < 1104) {
    if (tid < 64) {
      int f6 = sniff_vote(ip.p[6], ip.n[6], tid);
      int f7 = sniff_vote(ip.p[7], ip.n[7], tid);
      int f8 = sniff_vote(ip.p[8], ip.n[8], tid);
      if (tid == 0) { sfl[0] = f6; sfl[1] = f7; sfl[2] = f8; }
    }
    __syncthreads();
    int e = (blk - 1088) * 256 + tid;   // 0..4095
    wcq[e] = (_Float16)ldin(ip.p[6], sfl[0], e);
    wck[e] = (_Float16)ldin(ip.p[7], sfl[1], e);
    wcv[e] = (_Float16)ldin(ip.p[8], sfl[2], e);
  } else {
    __shared__ int allf[17];
    for (int ii = 0; ii < 17; ++ii) {
      if (tid < 64) {
        int f = sniff_vote(ip.p[ii], ip.n[ii], tid);
        if (tid == 0) { flags[ii] = f; allf[ii] = f; }
      }
    }
    __syncthreads();
    int f9 = allf[9], f10 = allf[10];
    for (int i = tid; i < Di; i += 256) {
      gqf[i] = ldin(ip.p[9], f9, i);
      gkf[i] = ldin(ip.p[10], f10, i);
    }
    if (tid < 24) {
      int g = tid >> 3, h = tid & 7;
      int idx = (g == 0) ? 12 : ((g == 1) ? 14 : 16);
      gbf[tid] = ldin(ip.p[idx], allf[idx], h);
    }
  }
}

// ---------------------------------------------------------------------------
// K1: fused RMSNorm + depthwise conv, wave-per-row (1 barrier total).
// Block = (t-tile of NT2, batch). Wave wv handles rows wv, wv+4, wv+8 of the
// 11-row halo window; lane owns 16 contiguous channels.
// ---------------------------------------------------------------------------
__global__ __launch_bounds__(256) void k_rmsconv(
    const void* __restrict__ x, const void* __restrict__ w_rms,
    const int* __restrict__ flags,
    const _Float16* __restrict__ wcq, const _Float16* __restrict__ wck,
    const _Float16* __restrict__ wcv,
    _Float16* __restrict__ xaf,
    _Float16* __restrict__ qc, _Float16* __restrict__ kc,
    _Float16* __restrict__ vc)
{
  constexpr int NR = NT2 + 3;   // 11 rows: t0-2 .. t0+NT2
  __shared__ _Float16 xas[NR][Dim];
  int tb = blockIdx.x, b = blockIdx.y;
  int t0 = tb * NT2;
  int tid = threadIdx.x, lane = tid & 63, wv = tid >> 6;
  int fx = flags[0], fw = flags[1];
  int e0 = lane * 16;

  float wr[16];
#pragma unroll
  for (int q = 0; q < 4; ++q) ld4(w_rms, fw, e0 + q * 4, &wr[q * 4]);

  for (int rr = wv; rr < NR; rr += 4) {
    int r = t0 - 2 + rr;
    float xv[16];
    bool inr = (r >= 0 && r < Seq);
    if (inr) {
      size_t rb = (size_t)(b * Seq + r) * Dim + e0;
#pragma unroll
      for (int q = 0; q < 4; ++q) ld4(x, fx, rb + q * 4, &xv[q * 4]);
    } else {
#pragma unroll
      for (int j = 0; j < 16; ++j) xv[j] = 0.f;
    }
    float ss = 0.f;
#pragma unroll
    for (int j = 0; j < 16; ++j) ss = fmaf(xv[j], xv[j], ss);
#pragma unroll
    for (int m = 1; m < 64; m <<= 1) ss += __shfl_xor(ss, m);
    float scale = rsqrtf(ss * (1.0f / Dim) + EPSV);

    _Float16 o[16];
#pragma unroll
    for (int j = 0; j < 16; ++j) o[j] = (_Float16)(xv[j] * scale * wr[j]);
    *(uint4*)&xas[rr][e0]     = *(uint4*)&o[0];
    *(uint4*)&xas[rr][e0 + 8] = *(uint4*)&o[8];
    if (inr && r >= t0 && r < t0 + NT2) {
      size_t ob = (size_t)(b * Seq + r) * Dim + e0;
      *(uint4*)&xaf[ob]     = *(uint4*)&o[0];
      *(uint4*)&xaf[ob + 8] = *(uint4*)&o[8];
    }
  }
  __syncthreads();

  int c0 = tid * 4;
  _Float16 lwq[16], lwk[16], lwv[16];
  *(uint4*)&lwq[0] = *(const uint4*)&wcq[c0 * 4];
  *(uint4*)&lwq[8] = *(const uint4*)&wcq[c0 * 4 + 8];
  *(uint4*)&lwk[0] = *(const uint4*)&wck[c0 * 4];
  *(uint4*)&lwk[8] = *(const uint4*)&wck[c0 * 4 + 8];
  *(uint4*)&lwv[0] = *(const uint4*)&wcv[c0 * 4];
  *(uint4*)&lwv[8] = *(const uint4*)&wcv[c0 * 4 + 8];

#pragma unroll
  for (int tt = 0; tt < NT2; ++tt) {
    float rv[4][4];
#pragma unroll
    for (int k = 0; k < 4; ++k) {
      _Float16 hx[4];
      *(ushort4*)hx = *(const ushort4*)&xas[tt + k][c0];
#pragma unroll
      for (int j = 0; j < 4; ++j) rv[k][j] = (float)hx[j];
    }
    _Float16 tq[4], tk[4], tv[4];
#pragma unroll
    for (int j = 0; j < 4; ++j) {
      float aq = rv[0][j] * (float)lwq[j * 4 + 0] + rv[1][j] * (float)lwq[j * 4 + 1]
               + rv[2][j] * (float)lwq[j * 4 + 2] + rv[3][j] * (float)lwq[j * 4 + 3];
      float ak = rv[0][j] * (float)lwk[j * 4 + 0] + rv[1][j] * (float)lwk[j * 4 + 1]
               + rv[2][j] * (float)lwk[j * 4 + 2] + rv[3][j] * (float)lwk[j * 4 + 3];
      float av = rv[0][j] * (float)lwv[j * 4 + 0] + rv[1][j] * (float)lwv[j * 4 + 1]
               + rv[2][j] * (float)lwv[j * 4 + 2] + rv[3][j] * (float)lwv[j * 4 + 3];
      tq[j] = (_Float16)aq; tk[j] = (_Float16)ak; tv[j] = (_Float16)av;
    }
    size_t o = ((size_t)(b * Seq + t0 + tt)) * Dim + c0;
    *(ushort4*)&qc[o] = *(ushort4*)tq;
    *(ushort4*)&kc[o] = *(ushort4*)tk;
    *(ushort4*)&vc[o] = *(ushort4*)tv;
  }
}

// ---------------------------------------------------------------------------
// K2: fused mid kernel. Blocks [0,384): QKV MFMA GEMM (128x64 tiles, z=q/k/v).
// Blocks [384,640): gate GEMM K-split partials.
// ---------------------------------------------------------------------------
__global__ __launch_bounds__(256) void k_mid(
    const _Float16* __restrict__ qc, const _Float16* __restrict__ kc,
    const _Float16* __restrict__ vc,
    const _Float16* __restrict__ wqT, const _Float16* __restrict__ wkT,
    const _Float16* __restrict__ wvT,
    const _Float16* __restrict__ xaf, const _Float16* __restrict__ WgT,
    _Float16* __restrict__ qpre, _Float16* __restrict__ kpre,
    _Float16* __restrict__ vpre,
    float* __restrict__ gpart)
{
  __shared__ __align__(16) _Float16 As[128][40];
  __shared__ __align__(16) _Float16 Bs[64][40];

  int blk = blockIdx.x;
  int tid = threadIdx.x, lane = tid & 63, wv = tid >> 6;
  int mrow = lane & 15, quad = lane >> 4;

  if (blk < 384) {
    int z = blk / 128, rem = blk - z * 128;
    int by = rem >> 3, bx = rem & 7;
    const _Float16* A  = (z == 0) ? qc : ((z == 1) ? kc : vc);
    const _Float16* Bt = (z == 0) ? wqT : ((z == 1) ? wkT : wvT);
    _Float16* C        = (z == 0) ? qpre : ((z == 1) ? kpre : vpre);
    int n0 = bx * 64, m0 = by * 128;
    int wm = wv * 32;
    int ar0 = tid >> 2, ac0 = (tid & 3) * 8;
    int ar1 = (tid + 256) >> 2;

    f32x4 acc[2][4];
#pragma unroll
    for (int mi = 0; mi < 2; ++mi)
#pragma unroll
      for (int ni = 0; ni < 4; ++ni) acc[mi][ni] = (f32x4){0.f, 0.f, 0.f, 0.f};

    for (int kt = 0; kt < Dim; kt += 32) {
      __syncthreads();
      *(uint4*)&As[ar0][ac0] = *(const uint4*)&A[(size_t)(m0 + ar0) * Dim + kt + ac0];
      *(uint4*)&As[ar1][ac0] = *(const uint4*)&A[(size_t)(m0 + ar1) * Dim + kt + ac0];
      *(uint4*)&Bs[ar0][ac0] = *(const uint4*)&Bt[(size_t)(n0 + ar0) * Dim + kt + ac0];
      __syncthreads();

      half8 bfr[4];
#pragma unroll
      for (int ni = 0; ni < 4; ++ni)
        bfr[ni] = *(const half8*)&Bs[ni * 16 + mrow][quad * 8];
#pragma unroll
      for (int mi = 0; mi < 2; ++mi) {
        half8 afr = *(const half8*)&As[wm + mi * 16 + mrow][quad * 8];
#pragma unroll
        for (int ni = 0; ni < 4; ++ni)
          acc[mi][ni] = __builtin_amdgcn_mfma_f32_16x16x32_f16(afr, bfr[ni], acc[mi][ni], 0, 0, 0);
      }
    }

#pragma unroll
    for (int mi = 0; mi < 2; ++mi) {
#pragma unroll
      for (int ni = 0; ni < 4; ++ni) {
        int col = n0 + ni * 16 + mrow;
#pragma unroll
        for (int r2 = 0; r2 < 4; ++r2) {
          int row = m0 + wm + mi * 16 + quad * 4 + r2;
          C[(size_t)row * Di + col] = (_Float16)acc[mi][ni][r2];
        }
      }
    }
  } else {
    int g = blk - 384;
    int m0 = (g & 31) * 64, ks = g >> 5;
    int srow = tid >> 2, scol = (tid & 3) * 8;
    int kbase = ks * (Dim / KSPL);

    f32x4 acc[4];
#pragma unroll
    for (int mi = 0; mi < 4; ++mi) acc[mi] = (f32x4){0.f, 0.f, 0.f, 0.f};

    for (int kt = kbase; kt < kbase + Dim / KSPL; kt += 32) {
      __syncthreads();
      *(uint4*)&As[srow][scol] = *(const uint4*)&xaf[(size_t)(m0 + srow) * Dim + kt + scol];
      *(uint4*)&Bs[srow][scol] = *(const uint4*)&WgT[(size_t)srow * Dim + kt + scol];
      __syncthreads();
      half8 bfr = *(const half8*)&Bs[wv * 16 + mrow][quad * 8];
#pragma unroll
      for (int mi = 0; mi < 4; ++mi) {
        half8 afr = *(const half8*)&As[mi * 16 + mrow][quad * 8];
        acc[mi] = __builtin_amdgcn_mfma_f32_16x16x32_f16(afr, bfr, acc[mi], 0, 0, 0);
      }
    }

    int col = wv * 16 + mrow;          // only 0..23 real
    if (col < 24) {
#pragma unroll
      for (int mi = 0; mi < 4; ++mi) {
#pragma unroll
        for (int r2 = 0; r2 < 4; ++r2) {
          int row = m0 + mi * 16 + quad * 4 + r2;
          gpart[((size_t)ks * BN + row) * 32 + col] = acc[mi][r2];
        }
      }
    }
  }
}

// ---------------------------------------------------------------------------
// K3: final MFMA GEMM, 128M x 64N, epilogue dtype by flags.
// ---------------------------------------------------------------------------
__global__ __launch_bounds__(256) void k_gemm_fin(
    const _Float16* __restrict__ A, const _Float16* __restrict__ Bt,
    void* __restrict__ C, const int* __restrict__ flags, int Nn, int Kd)
{
  __shared__ __align__(16) _Float16 As[128][40];
  __shared__ __align__(16) _Float16 Bs[64][40];

  int tid = threadIdx.x, lane = tid & 63, wv = tid >> 6;
  int n0 = blockIdx.x * 64, m0 = blockIdx.y * 128;
  int mrow = lane & 15, quad = lane >> 4;
  int wm = wv * 32;
  int ar0 = tid >> 2, ac0 = (tid & 3) * 8;
  int ar1 = (tid + 256) >> 2;

  f32x4 acc[2][4];
#pragma unroll
  for (int mi = 0; mi < 2; ++mi)
#pragma unroll
    for (int ni = 0; ni < 4; ++ni) acc[mi][ni] = (f32x4){0.f, 0.f, 0.f, 0.f};

  for (int kt = 0; kt < Kd; kt += 32) {
    __syncthreads();
    *(uint4*)&As[ar0][ac0] = *(const uint4*)&A[(size_t)(m0 + ar0) * Kd + kt + ac0];
    *(uint4*)&As[ar1][ac0] = *(const uint4*)&A[(size_t)(m0 + ar1) * Kd + kt + ac0];
    *(uint4*)&Bs[ar0][ac0] = *(const uint4*)&Bt[(size_t)(n0 + ar0) * Kd + kt + ac0];
    __syncthreads();

    half8 bfr[4];
#pragma unroll
    for (int ni = 0; ni < 4; ++ni)
      bfr[ni] = *(const half8*)&Bs[ni * 16 + mrow][quad * 8];
#pragma unroll
    for (int mi = 0; mi < 2; ++mi) {
      half8 afr = *(const half8*)&As[wm + mi * 16 + mrow][quad * 8];
#pragma unroll
      for (int ni = 0; ni < 4; ++ni)
        acc[mi][ni] = __builtin_amdgcn_mfma_f32_16x16x32_f16(afr, bfr[ni], acc[mi][ni], 0, 0, 0);
    }
  }

  int any_bf16 = 0;
#pragma unroll
  for (int i2 = 0; i2 < 17; ++i2) any_bf16 |= (flags[i2] == 0);

#pragma unroll
  for (int mi = 0; mi < 2; ++mi) {
#pragma unroll
    for (int ni = 0; ni < 4; ++ni) {
      int col = n0 + ni * 16 + mrow;
#pragma unroll
      for (int r2 = 0; r2 < 4; ++r2) {
        int row = m0 + wm + mi * 16 + quad * 4 + r2;
        float v = acc[mi][ni][r2];
        size_t idx = (size_t)row * Nn + col;
        if (any_bf16) ((unsigned short*)C)[idx] = f2bf(v);
        else          ((float*)C)[idx] = v;
      }
    }
  }
}

// ---------------------------------------------------------------------------
// Gate preload helper: reduce KSPL partials + bias + sigmoid (96 threads)
// ---------------------------------------------------------------------------
DEV void load_gates(const float* __restrict__ gpart, const float* __restrict__ gbf,
                    int b, int h, int c, int tid,
                    float* gl, float* gd, float* gm)
{
  if (tid < 96) {
    int which = tid >> 5, t2 = tid & 31;
    int col = which * 8 + h;
    int row = b * Seq + c * CLEN + t2;
    float acc = gbf[col];
#pragma unroll
    for (int ks = 0; ks < KSPL; ++ks)
      acc += gpart[((size_t)ks * BN + row) * 32 + col];
    float sg = 1.f / (1.f + expf(-acc));
    if (which == 0) gl[t2] = sg; else if (which == 1) gd[t2] = sg; else gm[t2] = sg;
  }
}

// ---------------------------------------------------------------------------
// Recurrence phases (proven).
// ---------------------------------------------------------------------------
__global__ __launch_bounds__(256) void k_phaseA(
    const _Float16* __restrict__ kpre, const _Float16* __restrict__ vpre,
    const float* __restrict__ gkf,
    const float* __restrict__ gpart, const float* __restrict__ gbf,
    _Float16* __restrict__ ZS_Z, _Float16* __restrict__ ZS_S,
    float* __restrict__ Mc, float* __restrict__ Dc, float* __restrict__ Wc)
{
  int c = blockIdx.x, s = blockIdx.y;
  int b = s >> 3, h = s & 7;
  int tid = threadIdx.x, lane = tid & 63, wv = tid >> 6;
  int i = tid >> 2, j0 = (tid & 3) * 16;
  __shared__ float kn[CLEN][64], vv[CLEN][64];
  __shared__ float gl[CLEN], gd[CLEN], gm[CLEN];

  {
    int t = tid >> 3, col = (tid & 7) * 8;
    size_t g = ((size_t)(b * Seq + c * CLEN + t)) * Di + h * 64 + col;
    half8 kv = *(const half8*)&kpre[g];
    half8 vvv = *(const half8*)&vpre[g];
#pragma unroll
    for (int j = 0; j < 8; ++j) { kn[t][col + j] = (float)kv[j]; vv[t][col + j] = (float)vvv[j]; }
    load_gates(gpart, gbf, b, h, c, tid, gl, gd, gm);
  }
  __syncthreads();
  {
    float gk = gkf[h * 64 + lane];
#pragma unroll
    for (int tt = 0; tt < 8; ++tt) {
      int t = wv * 8 + tt;
      float kvv = kn[t][lane];
      float ss = kvv * kvv;
#pragma unroll
      for (int m = 1; m < 64; m <<= 1) ss += __shfl_xor(ss, m);
      kn[t][lane] = kvv * (1.f / fmaxf(sqrtf(ss) * 0.125f, 1e-8f)) * gk;
    }
  }
  __syncthreads();

  float Zl[16], Sl[16];
#pragma unroll
  for (int jj = 0; jj < 16; ++jj) { Zl[jj] = 0.f; Sl[jj] = 0.f; }
  float Mcum = 1.f, Dcum = 1.f, wacc = 0.f;

  for (int t = 0; t < CLEN; ++t) {
    float l = gl[t], dd = gd[t], mm = gm[t];
    float vi = vv[t][i];
    Mcum *= mm;
#pragma unroll
    for (int jj = 0; jj < 16; ++jj) {
      Zl[jj] = fmaf(mm, Zl[jj], -vi * kn[t][j0 + jj]);
      Sl[jj] = fmaf(dd, Sl[jj], -l * Zl[jj]);
    }
    wacc = fmaf(dd, wacc, -l * Mcum);
    Dcum *= dd;
  }
  size_t base = ((size_t)(s * CHUNK + c)) * 4096 + (size_t)i * 64 + j0;
  half8 zo0, zo1, so0, so1;
#pragma unroll
  for (int jj = 0; jj < 8; ++jj) {
    zo0[jj] = (_Float16)Zl[jj];     zo1[jj] = (_Float16)Zl[jj + 8];
    so0[jj] = (_Float16)Sl[jj];     so1[jj] = (_Float16)Sl[jj + 8];
  }
  *(half8*)&ZS_Z[base] = zo0; *(half8*)&ZS_Z[base + 8] = zo1;
  *(half8*)&ZS_S[base] = so0; *(half8*)&ZS_S[base + 8] = so1;
  if (tid == 0) {
    Mc[s * CHUNK + c] = Mcum; Dc[s * CHUNK + c] = Dcum; Wc[s * CHUNK + c] = wacc;
  }
}

__global__ __launch_bounds__(256) void k_phaseB(
    _Float16* __restrict__ ZS_Z, _Float16* __restrict__ ZS_S,
    const float* __restrict__ Mc, const float* __restrict__ Dc,
    const float* __restrict__ Wc)
{
  int s = blockIdx.x;
  int e = blockIdx.y * 256 + threadIdx.x;
  float Z = 0.f, S = 0.f;
  for (int c = 0; c < CHUNK; ++c) {
    size_t base = ((size_t)(s * CHUNK + c)) * 4096 + e;
    float mc = Mc[s * CHUNK + c], dc = Dc[s * CHUNK + c], wc = Wc[s * CHUNK + c];
    float zl = (float)ZS_Z[base], sl = (float)ZS_S[base];
    ZS_Z[base] = (_Float16)Z; ZS_S[base] = (_Float16)S;   // chunk inputs
    S = fmaf(dc, S, fmaf(wc, Z, sl));  // uses OLD Z (= chunk input)
    Z = fmaf(mc, Z, zl);
  }
}

__global__ __launch_bounds__(256) void k_phaseC(
    const _Float16* __restrict__ qpre, const _Float16* __restrict__ kpre,
    const _Float16* __restrict__ vpre,
    const float* __restrict__ gqf, const float* __restrict__ gkf,
    const float* __restrict__ gpart, const float* __restrict__ gbf,
    const _Float16* __restrict__ ZS_Z, const _Float16* __restrict__ ZS_S,
    _Float16* __restrict__ yb)
{
  int c = blockIdx.x, s = blockIdx.y;
  int b = s >> 3, h = s & 7;
  int tid = threadIdx.x, lane = tid & 63, wv = tid >> 6;
  int i = tid >> 2, j0 = (tid & 3) * 16;
  __shared__ float kn[CLEN][64], vv[CLEN][64], qn[CLEN][64];
  __shared__ float gl[CLEN], gd[CLEN], gm[CLEN];

  float Zi_[16], Si_[16], Zl[16], Sl[16];
  size_t base = ((size_t)(s * CHUNK + c)) * 4096 + (size_t)i * 64 + j0;
  {
    half8 z0 = *(const half8*)&ZS_Z[base], z1 = *(const half8*)&ZS_Z[base + 8];
    half8 s0 = *(const half8*)&ZS_S[base], s1 = *(const half8*)&ZS_S[base + 8];
#pragma unroll
    for (int jj = 0; jj < 8; ++jj) {
      Zi_[jj] = (float)z0[jj]; Zi_[jj + 8] = (float)z1[jj];
      Si_[jj] = (float)s0[jj]; Si_[jj + 8] = (float)s1[jj];
      Zl[jj] = 0.f; Zl[jj + 8] = 0.f; Sl[jj] = 0.f; Sl[jj + 8] = 0.f;
    }
  }
  {
    int t = tid >> 3, col = (tid & 7) * 8;
    size_t g = ((size_t)(b * Seq + c * CLEN + t)) * Di + h * 64 + col;
    half8 kv = *(const half8*)&kpre[g];
    half8 vvv = *(const half8*)&vpre[g];
    half8 qv = *(const half8*)&qpre[g];
#pragma unroll
    for (int j = 0; j < 8; ++j) {
      kn[t][col + j] = (float)kv[j]; vv[t][col + j] = (float)vvv[j];
      qn[t][col + j] = (float)qv[j];
    }
    load_gates(gpart, gbf, b, h, c, tid, gl, gd, gm);
  }
  __syncthreads();
  {
    float gk = gkf[h * 64 + lane];
    float gq = gqf[h * 64 + lane];
#pragma unroll
    for (int tt = 0; tt < 8; ++tt) {
      int t = wv * 8 + tt;
      float kvv = kn[t][lane];
      float ssk = kvv * kvv;
      float qvv = qn[t][lane];
      float ssq = qvv * qvv;
#pragma unroll
      for (int m = 1; m < 64; m <<= 1) { ssk += __shfl_xor(ssk, m); ssq += __shfl_xor(ssq, m); }
      kn[t][lane] = kvv * (1.f / fmaxf(sqrtf(ssk) * 0.125f, 1e-8f)) * gk;
      qn[t][lane] = qvv * (1.f / fmaxf(sqrtf(ssq) * 0.125f, 1e-8f)) * gq;
    }
  }
  __syncthreads();

  float Mcum = 1.f, Dcum = 1.f, wacc = 0.f;
  float Dprev = 1.f, wprev = 0.f;

  for (int t = 0; t < CLEN; ++t) {
    float l = gl[t], dd = gd[t], mm = gm[t];

    float yp = 0.f;
#pragma unroll
    for (int jj = 0; jj < 16; ++jj) {
      float tmp = fmaf(Dprev, Si_[jj], fmaf(wprev, Zi_[jj], Sl[jj]));
      yp = fmaf(tmp, qn[t][j0 + jj], yp);
    }
    yp += __shfl_xor(yp, 1);
    yp += __shfl_xor(yp, 2);
    if ((tid & 3) == 0)
      yb[((size_t)(b * Seq + c * CLEN + t)) * Di + h * 64 + i] = (_Float16)yp;

    float vi = vv[t][i];
    Mcum *= mm;
#pragma unroll
    for (int jj = 0; jj < 16; ++jj) {
      Zl[jj] = fmaf(mm, Zl[jj], -vi * kn[t][j0 + jj]);
      Sl[jj] = fmaf(dd, Sl[jj], -l * Zl[jj]);
    }
    wacc = fmaf(dd, wacc, -l * Mcum);
    Dcum *= dd;
    Dprev = Dcum; wprev = wacc;
  }
}

// ---------------------------------------------------------------------------
extern "C" void kernel_launch(void* const* d_in, const int* in_sizes, int n_in,
                              void* d_out, int out_size, void* d_ws, size_t ws_size,
                              hipStream_t stream) {
  InPtrs ip;
  for (int i = 0; i < 17; ++i) { ip.p[i] = d_in[i]; ip.n[i] = in_sizes[i]; }

  char* p = (char*)d_ws;
  auto take = [&](size_t bytes) -> char* {
    char* q = p; p += (bytes + 255) & ~(size_t)255; return q;
  };
  int* flags           = (int*)take(32 * 4);
  _Float16* xaf        = (_Float16*)take((size_t)BN * Dim * 2);   // 4 MB
  _Float16* qc         = (_Float16*)take((size_t)BN * Dim * 2);   // 4 MB
  _Float16* kc         = (_Float16*)take((size_t)BN * Dim * 2);   // 4 MB
  _Float16* vc         = (_Float16*)take((size_t)BN * Dim * 2);   // 4 MB
  _Float16* qpre       = (_Float16*)take((size_t)BN * Di * 2);    // 2 MB
  _Float16* kpre       = (_Float16*)take((size_t)BN * Di * 2);    // 2 MB
  _Float16* vpre       = (_Float16*)take((size_t)BN * Di * 2);    // 2 MB
  float* gpart         = (float*)take((size_t)KSPL * BN * 32 * 4); // 2 MB
  float* Mc            = (float*)take((size_t)NSEQ * CHUNK * 4);
  float* Dc            = (float*)take((size_t)NSEQ * CHUNK * 4);
  float* Wc            = (float*)take((size_t)NSEQ * CHUNK * 4);
  _Float16* wqT        = (_Float16*)take((size_t)Di * Dim * 2);   // 1 MB
  _Float16* wkT        = (_Float16*)take((size_t)Di * Dim * 2);   // 1 MB
  _Float16* wvT        = (_Float16*)take((size_t)Di * Dim * 2);   // 1 MB
  _Float16* woT        = (_Float16*)take((size_t)Dim * Di * 2);   // 1 MB
  _Float16* WgT        = (_Float16*)take((size_t)64 * Dim * 2);   // 128 KB
  _Float16* wcq        = (_Float16*)take((size_t)Dim * 4 * 2);
  _Float16* wck        = (_Float16*)take((size_t)Dim * 4 * 2);
  _Float16* wcv        = (_Float16*)take((size_t)Dim * 4 * 2);
  float* gqf           = (float*)take(Di * 4);
  float* gkf           = (float*)take(Di * 4);
  float* gbf           = (float*)take(32 * 4);
  // Aliases: qc/kc/vc are dead after k_mid
  _Float16* ZS_Z       = qc;
  _Float16* ZS_S       = kc;
  _Float16* yb         = vc;

  k_prep_all<<<1105, 256, 0, stream>>>(ip, flags, wqT, wkT, wvT, woT, WgT,
                                       wcq, wck, wcv, gqf, gkf, gbf);

  k_rmsconv<<<dim3(Seq / NT2, Bb), 256, 0, stream>>>(
      d_in[0], d_in[1], flags, wcq, wck, wcv, xaf, qc, kc, vc);

  k_mid<<<640, 256, 0, stream>>>(qc, kc, vc, wqT, wkT, wvT, xaf, WgT,
                                 qpre, kpre, vpre, gpart);

  k_phaseA<<<dim3(CHUNK, NSEQ), 256, 0, stream>>>(kpre, vpre, gkf,
                                                  gpart, gbf,
                                                  ZS_Z, ZS_S, Mc, Dc, Wc);
  k_phaseB<<<dim3(NSEQ, 16), 256, 0, stream>>>(ZS_Z, ZS_S, Mc, Dc, Wc);
  k_phaseC<<<dim3(CHUNK, NSEQ), 256, 0, stream>>>(qpre, kpre, vpre, gqf, gkf,
                                                  gpart, gbf,
                                                  ZS_Z, ZS_S, yb);

  k_gemm_fin<<<dim3(Dim / 64, BN / 128), 256, 0, stream>>>(
      yb, woT, d_out, flags, Dim, Di);
}